// Round 2
// baseline (5029.077 us; speedup 1.0000x reference)
//
#include <hip/hip_runtime.h>
#include <hip/hip_bf16.h>

typedef __hip_bfloat16 bf16;

#define DEV __device__ __forceinline__
DEV float b2f(bf16 v){ return __bfloat162float(v); }
DEV bf16 f2b(float v){ return __float2bfloat16(v); }
DEV float sigm(float x){ return 1.f/(1.f + expf(-x)); }

// ---- problem constants ----
#define BB 4
#define CIN 256
#define MID 128
#define COUT 64
#define HH 128
#define WW 128
#define WS 8
#define HEADS 8
#define HD 16
#define NTOK 64         // WS*WS
#define NWIN 1024       // B * 16 * 16

// ---- workspace layout (bytes) ----
static const size_t OFF_H     = 0;                       // fp32 8388608  (33554432 B)
static const size_t OFF_LOCAL = 33554432;                // fp32 8388608
static const size_t OFF_Q     = 67108864;                // bf16 8388608  (16777216 B)
static const size_t OFF_K     = 83886080;                // bf16 8388608
static const size_t OFF_V     = 100663296;               // bf16 8388608
static const size_t OFF_DOTS  = 117440512;               // bf16 33554432 (67108864 B)
static const size_t OFF_Z1    = 184549376;               // bf16 1048576  (2097152 B)
static const size_t OFF_Z2    = 186646528;               // bf16 1048576
static const size_t OFF_Z3    = 188743680;               // bf16 8388608  (16777216 B)
static const size_t OFF_G1    = 205520896;               // fp32 524288   (2097152 B)
static const size_t OFF_G2    = 207618048;               // fp32 524288
static const size_t OFF_G3    = 209715200;               // fp32 4194304  (16777216 B)
// total 226492416 B.  Reuse: o_img->OFF_Q (q+k), Fh/Fw->OFF_DOTS, comb->OFF_H,
// proj1->OFF_LOCAL, out_mid->OFF_Q.

// ============ K1: conv3x3 256->128 + bn + relu ============
__global__ __launch_bounds__(256) void k_conv1(const float* __restrict__ x, const float* __restrict__ w,
      const float* __restrict__ gg, const float* __restrict__ bb, float* __restrict__ h){
  const int tx = threadIdx.x, ty = threadIdx.y, t = ty*16+tx;
  const int bz = blockIdx.z; const int b = bz >> 6; const int co0 = (bz & 63)*2;
  const int ox = blockIdx.x*16, oy = blockIdx.y*16;
  __shared__ float wsm[2*256*9];
  __shared__ float xs[8][18][18];
  for (int i = t; i < 2*256*9; i += 256){
    int c = i / 2304, r = i % 2304;
    wsm[i] = w[(co0+c)*2304 + r];
  }
  float a0 = 0.f, a1 = 0.f;
  for (int cc = 0; cc < 32; ++cc){
    __syncthreads();
    for (int i = t; i < 8*324; i += 256){
      int ci = i / 324, r = i % 324; int iy = r / 18, ix = r % 18;
      int gy = oy + iy - 1, gx = ox + ix - 1;
      float v = 0.f;
      if ((unsigned)gy < 128u && (unsigned)gx < 128u)
        v = x[((size_t)(b*256 + cc*8+ci)*128 + gy)*128 + gx];
      xs[ci][iy][ix] = v;
    }
    __syncthreads();
    #pragma unroll
    for (int ci = 0; ci < 8; ++ci){
      const float* wp = &wsm[(cc*8+ci)*9];
      const float* wq = wp + 2304;
      #pragma unroll
      for (int ky = 0; ky < 3; ++ky)
        #pragma unroll
        for (int kx = 0; kx < 3; ++kx){
          float xv = xs[ci][ty+ky][tx+kx];
          a0 += xv * wp[ky*3+kx];
          a1 += xv * wq[ky*3+kx];
        }
    }
  }
  float g0 = gg[co0], g1 = gg[co0+1], c0 = bb[co0], c1 = bb[co0+1];
  size_t oidx = ((size_t)(b*128 + co0)*128 + oy+ty)*128 + ox+tx;
  h[oidx]           = fmaxf(a0*g0 + c0, 0.f);
  h[oidx + 128*128] = fmaxf(a1*g1 + c1, 0.f);
}

// ============ K2: local = bn(1x1) + bn(3x3) ============
__global__ __launch_bounds__(256) void k_local(const float* __restrict__ h,
      const float* __restrict__ w1, const float* __restrict__ g1, const float* __restrict__ b1,
      const float* __restrict__ w2, const float* __restrict__ g2, const float* __restrict__ b2,
      float* __restrict__ out){
  const int tx = threadIdx.x, ty = threadIdx.y, t = ty*16+tx;
  const int bz = blockIdx.z; const int b = bz >> 6; const int co0 = (bz & 63)*2;
  const int ox = blockIdx.x*16, oy = blockIdx.y*16;
  __shared__ float wsm1[2*128*9];
  __shared__ float wsm2[2*128];
  __shared__ float xs[8][18][18];
  for (int i = t; i < 2*128*9; i += 256){
    int c = i / 1152, r = i % 1152;
    wsm1[i] = w1[(co0+c)*1152 + r];
  }
  if (t < 256) wsm2[t] = w2[(co0 + (t>>7))*128 + (t&127)];
  float a3[2] = {0.f,0.f}; float a1x[2] = {0.f,0.f};
  for (int cc = 0; cc < 16; ++cc){
    __syncthreads();
    for (int i = t; i < 8*324; i += 256){
      int ci = i / 324, r = i % 324; int iy = r / 18, ix = r % 18;
      int gy = oy + iy - 1, gx = ox + ix - 1;
      float v = 0.f;
      if ((unsigned)gy < 128u && (unsigned)gx < 128u)
        v = h[((size_t)(b*128 + cc*8+ci)*128 + gy)*128 + gx];
      xs[ci][iy][ix] = v;
    }
    __syncthreads();
    #pragma unroll
    for (int ci = 0; ci < 8; ++ci){
      const float* wp = &wsm1[(cc*8+ci)*9];
      const float* wq = wp + 1152;
      float ctr = xs[ci][ty+1][tx+1];
      a1x[0] += ctr * wsm2[cc*8+ci];
      a1x[1] += ctr * wsm2[128 + cc*8+ci];
      #pragma unroll
      for (int ky = 0; ky < 3; ++ky)
        #pragma unroll
        for (int kx = 0; kx < 3; ++kx){
          float xv = xs[ci][ty+ky][tx+kx];
          a3[0] += xv * wp[ky*3+kx];
          a3[1] += xv * wq[ky*3+kx];
        }
    }
  }
  size_t oidx = ((size_t)(b*128 + co0)*128 + oy+ty)*128 + ox+tx;
  #pragma unroll
  for (int c = 0; c < 2; ++c){
    float r = a3[c]*g1[co0+c] + b1[co0+c] + a1x[c]*g2[co0+c] + b2[co0+c];
    out[oidx + (size_t)c*128*128] = r;
  }
}

// ============ K3: 1x1 qkv conv -> windowed q,k,v (bf16) ============
__global__ __launch_bounds__(256) void k_qkv(const float* __restrict__ h, const float* __restrict__ w,
     bf16* __restrict__ q, bf16* __restrict__ k, bf16* __restrict__ v){
  const int bw = blockIdx.x, ocb = blockIdx.y;   // oc in [ocb*64, +64)
  const int b = bw >> 8, wy = (bw >> 4) & 15, wx = bw & 15;
  __shared__ float hs[128][64];
  __shared__ float wsm[64][129];
  const int tx = threadIdx.x, ty = threadIdx.y, t = ty*16+tx;
  for (int i = t; i < 128*64; i += 256){
    int ci = i >> 6, n = i & 63; int yy = wy*8 + (n>>3), xx = wx*8 + (n&7);
    hs[ci][n] = h[((size_t)(b*128+ci)*128 + yy)*128 + xx];
  }
  for (int i = t; i < 64*128; i += 256){
    int oc = i >> 7, ci = i & 127;
    wsm[oc][ci] = w[(ocb*64+oc)*128 + ci];
  }
  __syncthreads();
  float acc[4][4] = {};
  for (int ci = 0; ci < 128; ++ci){
    float hv[4], wv[4];
    #pragma unroll
    for (int jj = 0; jj < 4; ++jj) hv[jj] = hs[ci][jj*16+tx];
    #pragma unroll
    for (int ii = 0; ii < 4; ++ii) wv[ii] = wsm[ii*16+ty][ci];
    #pragma unroll
    for (int ii = 0; ii < 4; ++ii)
      #pragma unroll
      for (int jj = 0; jj < 4; ++jj) acc[ii][jj] += wv[ii]*hv[jj];
  }
  #pragma unroll
  for (int ii = 0; ii < 4; ++ii){
    int oc = ocb*64 + ii*16 + ty;
    int s = oc >> 7, rem = oc & 127, head = rem >> 4, d = rem & 15;
    bf16* dst = (s==0) ? q : (s==1) ? k : v;
    #pragma unroll
    for (int jj = 0; jj < 4; ++jj){
      int n = jj*16 + tx;
      dst[((size_t)(bw*8+head)*64 + n)*16 + d] = f2b(acc[ii][jj]);
    }
  }
}

// ============ K4: dots = q.k^T * 0.25 + relpos bias ============
__global__ __launch_bounds__(256) void k_dots(const bf16* __restrict__ q, const bf16* __restrict__ kk,
      const float* __restrict__ rel, bf16* __restrict__ dots){
  const int bw = blockIdx.x, hd = blockIdx.y;
  __shared__ bf16 qs[64][16], ks[64][16];
  const int t = threadIdx.x;
  const size_t base = (size_t)(bw*8+hd)*1024;
  for (int i = t; i < 1024; i += 256){ qs[i>>4][i&15] = q[base + i]; ks[i>>4][i&15] = kk[base + i]; }
  __syncthreads();
  const int n = t >> 2, jm = t & 3;
  float qr[16];
  #pragma unroll
  for (int d = 0; d < 16; ++d) qr[d] = b2f(qs[n][d]);
  const int ny = n >> 3, nx = n & 7;
  for (int mm = 0; mm < 16; ++mm){
    int m = jm*16 + mm;
    float a = 0.f;
    #pragma unroll
    for (int d = 0; d < 16; ++d) a += qr[d]*b2f(ks[m][d]);
    int my = m >> 3, mx = m & 7;
    int ridx = (ny - my + 7)*15 + (nx - mx + 7);
    float bias = rel[ridx*8 + hd];
    dots[base*4 + (size_t)n*64 + m] = f2b(a*0.25f + bias);
  }
}

// ============ K5: axis reductions (max, mean) ============
__global__ void k_z1(const bf16* __restrict__ dots, bf16* __restrict__ z){ // over n -> (bw,2,8,64)
  int t = blockIdx.x*256 + threadIdx.x;
  int bw = t >> 9, r = t & 511; int hd = r >> 6, m = r & 63;
  const bf16* p = dots + (size_t)(bw*8+hd)*4096 + m;
  float mx = -1e30f, sm = 0.f;
  for (int n = 0; n < 64; ++n){ float v = b2f(p[n*64]); mx = fmaxf(mx,v); sm += v; }
  z[(size_t)bw*1024 + hd*64 + m]       = f2b(mx);
  z[(size_t)bw*1024 + 512 + hd*64 + m] = f2b(sm*(1.f/64.f));
}
__global__ void k_z2(const bf16* __restrict__ dots, bf16* __restrict__ z){ // over m -> (bw,2,64,8)
  int t = blockIdx.x*256 + threadIdx.x;
  int bw = t >> 9, r = t & 511; int n = r >> 3, hd = r & 7;
  const bf16* p = dots + ((size_t)(bw*8+hd)*64 + n)*64;
  float mx = -1e30f, sm = 0.f;
  for (int m = 0; m < 64; ++m){ float v = b2f(p[m]); mx = fmaxf(mx,v); sm += v; }
  z[(size_t)bw*1024 + n*8 + hd]       = f2b(mx);
  z[(size_t)bw*1024 + 512 + n*8 + hd] = f2b(sm*(1.f/64.f));
}
__global__ void k_z3(const bf16* __restrict__ dots, bf16* __restrict__ z){ // over h -> (bw,2,64,64)
  int t = blockIdx.x*256 + threadIdx.x;
  int bw = t >> 12, r = t & 4095;
  const bf16* p = dots + (size_t)bw*32768 + r;
  float mx = -1e30f, sm = 0.f;
  for (int hd = 0; hd < 8; ++hd){ float v = b2f(p[hd*4096]); mx = fmaxf(mx,v); sm += v; }
  z[(size_t)bw*8192 + r]        = f2b(mx);
  z[(size_t)bw*8192 + 4096 + r] = f2b(sm*0.125f);
}

// ============ K6: 7x7 2->1 conv + bn + sigmoid ============
__global__ __launch_bounds__(256) void k_gate(const bf16* __restrict__ z, const float* __restrict__ w,
      const float* __restrict__ gg, const float* __restrict__ bb, float* __restrict__ G, int R, int C){
  __shared__ float wsm[98];
  const int t = threadIdx.x;
  if (t < 98) wsm[t] = w[t];
  __syncthreads();
  const int bw = blockIdx.x;
  int p = blockIdx.y*256 + t; if (p >= R*C) return;
  int y = p / C, x = p - y*C;
  float acc = 0.f;
  for (int c = 0; c < 2; ++c)
    for (int ky = 0; ky < 7; ++ky){
      int iy = y + ky - 3; if ((unsigned)iy >= (unsigned)R) continue;
      for (int kx = 0; kx < 7; ++kx){
        int ix = x + kx - 3; if ((unsigned)ix >= (unsigned)C) continue;
        acc += b2f(z[((size_t)(bw*2+c)*R + iy)*C + ix]) * wsm[c*49 + ky*7 + kx];
      }
    }
  G[(size_t)bw*R*C + p] = sigm(acc*gg[0] + bb[0]);
}

// ============ K7: gated softmax + attn@v -> o (image layout, fp32) ============
__global__ __launch_bounds__(256) void k_attn(const bf16* __restrict__ dots, const float* __restrict__ G1,
      const float* __restrict__ G2, const float* __restrict__ G3, const bf16* __restrict__ v,
      float* __restrict__ o){
  const int bw = blockIdx.x, hd = blockIdx.y;
  const int b = bw >> 8, wy = (bw >> 4) & 15, wx = bw & 15;
  __shared__ float attn[64][65];
  __shared__ bf16 vs[64][16];
  __shared__ float invTot[64];
  const int t = threadIdx.x;
  for (int i = t; i < 1024; i += 256) vs[i>>4][i&15] = v[(size_t)(bw*8+hd)*1024 + i];
  const int n = t >> 2, j = t & 3;
  float g2v = G2[(size_t)bw*512 + n*8 + hd];
  const bf16* dp = dots + ((size_t)(bw*8+hd)*64 + n)*64 + j*16;
  const float* g1p = G1 + (size_t)bw*512 + hd*64 + j*16;
  const float* g3p = G3 + (size_t)bw*4096 + n*64 + j*16;
  float e[16]; float mx = -1e30f;
  #pragma unroll
  for (int m = 0; m < 16; ++m){
    float dv = b2f(dp[m]) * ((g1p[m] + g2v + g3p[m]) * (1.f/3.f));
    e[m] = dv; mx = fmaxf(mx, dv);
  }
  mx = fmaxf(mx, __shfl_xor(mx, 1, 4));
  mx = fmaxf(mx, __shfl_xor(mx, 2, 4));
  float s = 0.f;
  #pragma unroll
  for (int m = 0; m < 16; ++m){ float ev = expf(e[m]-mx); e[m] = ev; s += ev; }
  s += __shfl_xor(s, 1, 4);
  s += __shfl_xor(s, 2, 4);
  #pragma unroll
  for (int m = 0; m < 16; ++m) attn[n][j*16+m] = e[m];
  if (j == 0) invTot[n] = 1.f/s;
  __syncthreads();
  const int dg = j;
  float acc[4] = {0.f,0.f,0.f,0.f};
  for (int m = 0; m < 64; ++m){
    float a = attn[n][m];
    #pragma unroll
    for (int dd = 0; dd < 4; ++dd) acc[dd] += a * b2f(vs[m][dg*4+dd]);
  }
  float it = invTot[n];
  int y = wy*8 + (n>>3), x = wx*8 + (n&7);
  #pragma unroll
  for (int dd = 0; dd < 4; ++dd){
    int c = hd*16 + dg*4 + dd;
    o[((size_t)(b*128+c)*128 + y)*128 + x] = acc[dd]*it;
  }
}

// ============ K8: Fh / Fw axial gates ============
__global__ void k_fw(const float* __restrict__ o, float* __restrict__ Fw){
  int t = blockIdx.x*256 + threadIdx.x; if (t >= 4*128*32*128) return;
  int x = t & 127, kk = (t>>7) & 31, bc = t >> 12;
  const float* p = o + ((size_t)bc*128 + kk*4)*128 + x;
  float mx = -1e30f, sm = 0.f;
  #pragma unroll
  for (int r = 0; r < 4; ++r){ float v = p[r*128]; mx = fmaxf(mx,v); sm += v; }
  Fw[t] = sigm(sm*0.25f + mx);
}
__global__ void k_fh(const float* __restrict__ o, float* __restrict__ Fh){
  int t = blockIdx.x*256 + threadIdx.x; if (t >= 4*128*128*32) return;
  int kk = t & 31, y = (t>>5) & 127, bc = t >> 12;
  const float* p = o + ((size_t)bc*128 + y)*128 + kk*4;
  float mx = -1e30f, sm = 0.f;
  #pragma unroll
  for (int r = 0; r < 4; ++r){ float v = p[r]; mx = fmaxf(mx,v); sm += v; }
  Fh[t] = sigm(sm*0.25f + mx);
}

// ============ K9: comb = o * (Fh@Fw) + local ============
__global__ __launch_bounds__(256) void k_comb(const float* __restrict__ o, const float* __restrict__ Fh,
      const float* __restrict__ Fw, const float* __restrict__ local, float* __restrict__ comb){
  const int bc = blockIdx.x;
  __shared__ float fh[128][33];
  __shared__ float fw[32][129];
  const int t = threadIdx.x;
  for (int i = t; i < 4096; i += 256) fh[i>>5][i&31]  = Fh[(size_t)bc*4096 + i];
  for (int i = t; i < 4096; i += 256) fw[i>>7][i&127] = Fw[(size_t)bc*4096 + i];
  __syncthreads();
  for (int i = t; i < 16384; i += 256){
    int y = i >> 7, x = i & 127;
    float g = 0.f;
    #pragma unroll
    for (int kk = 0; kk < 32; ++kk) g += fh[y][kk]*fw[kk][x];
    size_t idx = (size_t)bc*16384 + i;
    comb[idx] = o[idx]*g + local[idx];
  }
}

// ============ K10: reflect-pad + depthwise 8x8 (pad 3) + bn ============
__global__ __launch_bounds__(256) void k_dw(const float* __restrict__ comb, const float* __restrict__ dw,
      const float* __restrict__ gg, const float* __restrict__ bb, float* __restrict__ out){
  const int tx = threadIdx.x, ty = threadIdx.y, t = ty*16+tx;
  const int bz = blockIdx.z; const int c = bz & 127;
  const int oy0 = blockIdx.y*16, ox0 = blockIdx.x*16;
  __shared__ float xs[23][23];
  __shared__ float wsm[64];
  if (t < 64) wsm[t] = dw[c*64 + t];
  for (int i = t; i < 529; i += 256){
    int iy = i/23, ix = i - iy*23;
    int y = oy0 + iy - 3, x = ox0 + ix - 3;
    float v = 0.f;
    if (y >= 0 && y <= 128 && x >= 0 && x <= 128){
      int yy = (y==128)?126:y, xx = (x==128)?126:x;
      v = comb[((size_t)bz*128 + yy)*128 + xx];
    }
    xs[iy][ix] = v;
  }
  __syncthreads();
  float acc = 0.f;
  #pragma unroll
  for (int ky = 0; ky < 8; ++ky)
    #pragma unroll
    for (int kx = 0; kx < 8; ++kx)
      acc += xs[ty+ky][tx+kx]*wsm[ky*8+kx];
  out[((size_t)bz*128 + oy0+ty)*128 + ox0+tx] = acc*gg[c] + bb[c];
}

// ============ K11: 1x1 proj conv 128->128 ============
__global__ __launch_bounds__(256) void k_pw(const float* __restrict__ p1, const float* __restrict__ w,
      float* __restrict__ om){
  const int pt = blockIdx.x, cb = blockIdx.y;
  const int P0 = pt*64; const int b = P0 >> 14; const int rem0 = P0 & 16383;
  __shared__ float xsm[128][65];
  __shared__ float wsm[64][129];
  const int tx = threadIdx.x, ty = threadIdx.y, t = ty*16+tx;
  for (int i = t; i < 128*64; i += 256){
    int ci = i >> 6, p = i & 63;
    xsm[ci][p] = p1[(size_t)(b*128+ci)*16384 + rem0 + p];
  }
  for (int i = t; i < 64*128; i += 256){
    int co = i >> 7, ci = i & 127;
    wsm[co][ci] = w[(cb*64+co)*128 + ci];
  }
  __syncthreads();
  float acc[4][4] = {};
  for (int ci = 0; ci < 128; ++ci){
    float hv[4], wv[4];
    #pragma unroll
    for (int jj = 0; jj < 4; ++jj) hv[jj] = xsm[ci][jj*16+tx];
    #pragma unroll
    for (int ii = 0; ii < 4; ++ii) wv[ii] = wsm[ii*16+ty][ci];
    #pragma unroll
    for (int ii = 0; ii < 4; ++ii)
      #pragma unroll
      for (int jj = 0; jj < 4; ++jj) acc[ii][jj] += wv[ii]*hv[jj];
  }
  #pragma unroll
  for (int ii = 0; ii < 4; ++ii){
    int co = cb*64 + ii*16 + ty;
    #pragma unroll
    for (int jj = 0; jj < 4; ++jj)
      om[(size_t)(b*128+co)*16384 + rem0 + jj*16+tx] = acc[ii][jj];
  }
}

// ============ K12: stride-2 transposed 3x3 conv 128->64 ============
__global__ __launch_bounds__(256) void k_up(const float* __restrict__ om, const float* __restrict__ w,
      float* __restrict__ out){
  const int tx = threadIdx.x, ty = threadIdx.y, t = ty*16+tx;
  const int bz = blockIdx.z; const int b = bz >> 6, co = bz & 63;
  const int y0 = blockIdx.y*16, x0 = blockIdx.x*16;   // input tile origin
  __shared__ float wsm[128*9];
  __shared__ float xs[8][17][18];
  for (int i = t; i < 1152; i += 256) wsm[i] = w[co*1152 + i];
  float a00=0.f, a01=0.f, a10=0.f, a11=0.f;
  for (int cc = 0; cc < 16; ++cc){
    __syncthreads();
    for (int i = t; i < 8*289; i += 256){
      int ci = i / 289, r = i % 289, iy = r/17, ix = r - iy*17;
      int y = y0+iy, x = x0+ix;
      float v = 0.f;
      if (y < 128 && x < 128) v = om[((size_t)(b*128 + cc*8+ci)*128 + y)*128 + x];
      xs[ci][iy][ix] = v;
    }
    __syncthreads();
    #pragma unroll
    for (int ci = 0; ci < 8; ++ci){
      const float* wp = &wsm[(cc*8+ci)*9];
      float xa = xs[ci][ty][tx],   xb = xs[ci][ty][tx+1];
      float xc = xs[ci][ty+1][tx], xd = xs[ci][ty+1][tx+1];
      a00 += wp[4]*xa;
      a01 += wp[3]*xa + wp[5]*xb;
      a10 += wp[1]*xa + wp[7]*xc;
      a11 += wp[0]*xa + wp[2]*xb + wp[6]*xc + wp[8]*xd;
    }
  }
  int Y = 2*(y0+ty), X = 2*(x0+tx);
  size_t base = ((size_t)bz*256 + Y)*256 + X;
  out[base]     = a00; out[base+1]   = a01;
  out[base+256] = a10; out[base+257] = a11;
}

extern "C" void kernel_launch(void* const* d_in, const int* in_sizes, int n_in,
                              void* d_out, int out_size, void* d_ws, size_t ws_size,
                              hipStream_t stream) {
  const float* x       = (const float*)d_in[0];
  const float* conv_w  = (const float*)d_in[1];
  const float* bn1_g   = (const float*)d_in[2];
  const float* bn1_b   = (const float*)d_in[3];
  const float* qkv_w   = (const float*)d_in[4];
  const float* loc1_w  = (const float*)d_in[5];
  const float* loc1_g  = (const float*)d_in[6];
  const float* loc1_b  = (const float*)d_in[7];
  const float* loc2_w  = (const float*)d_in[8];
  const float* loc2_g  = (const float*)d_in[9];
  const float* loc2_b  = (const float*)d_in[10];
  const float* rel_t   = (const float*)d_in[11];
  const float* cw_w    = (const float*)d_in[12];
  const float* cw_g    = (const float*)d_in[13];
  const float* cw_b    = (const float*)d_in[14];
  const float* hc_w    = (const float*)d_in[15];
  const float* hc_g    = (const float*)d_in[16];
  const float* hc_b    = (const float*)d_in[17];
  const float* hw_w    = (const float*)d_in[18];
  const float* hw_g    = (const float*)d_in[19];
  const float* hw_b    = (const float*)d_in[20];
  const float* proj_dw = (const float*)d_in[21];
  const float* proj_g  = (const float*)d_in[22];
  const float* proj_b  = (const float*)d_in[23];
  const float* proj_pw = (const float*)d_in[24];
  const float* up_w    = (const float*)d_in[25];

  char* ws = (char*)d_ws;
  float* h      = (float*)(ws + OFF_H);
  float* local  = (float*)(ws + OFF_LOCAL);
  bf16*  q      = (bf16*)(ws + OFF_Q);
  bf16*  k      = (bf16*)(ws + OFF_K);
  bf16*  v      = (bf16*)(ws + OFF_V);
  bf16*  dots   = (bf16*)(ws + OFF_DOTS);
  bf16*  z1     = (bf16*)(ws + OFF_Z1);
  bf16*  z2     = (bf16*)(ws + OFF_Z2);
  bf16*  z3     = (bf16*)(ws + OFF_Z3);
  float* G1     = (float*)(ws + OFF_G1);
  float* G2     = (float*)(ws + OFF_G2);
  float* G3     = (float*)(ws + OFF_G3);
  float* o_img  = (float*)(ws + OFF_Q);                 // reuse q+k
  float* Fh     = (float*)(ws + OFF_DOTS);              // reuse dots
  float* Fw     = (float*)(ws + OFF_DOTS + 8388608);
  float* comb   = (float*)(ws + OFF_H);                 // reuse h
  float* proj1  = (float*)(ws + OFF_LOCAL);             // reuse local
  float* om     = (float*)(ws + OFF_Q);                 // reuse q+k (o dead)
  float* outp   = (float*)d_out;

  dim3 blk2(16,16);
  k_conv1<<<dim3(8,8,BB*64), blk2, 0, stream>>>(x, conv_w, bn1_g, bn1_b, h);
  k_local<<<dim3(8,8,BB*64), blk2, 0, stream>>>(h, loc1_w, loc1_g, loc1_b, loc2_w, loc2_g, loc2_b, local);
  k_qkv  <<<dim3(NWIN,6), blk2, 0, stream>>>(h, qkv_w, q, k, v);
  k_dots <<<dim3(NWIN,8), 256, 0, stream>>>(q, k, rel_t, dots);
  k_z1   <<<2048, 256, 0, stream>>>(dots, z1);
  k_z2   <<<2048, 256, 0, stream>>>(dots, z2);
  k_z3   <<<16384, 256, 0, stream>>>(dots, z3);
  k_gate <<<dim3(NWIN,2),  256, 0, stream>>>(z1, cw_w, cw_g, cw_b, G1, 8, 64);
  k_gate <<<dim3(NWIN,2),  256, 0, stream>>>(z2, hc_w, hc_g, hc_b, G2, 64, 8);
  k_gate <<<dim3(NWIN,16), 256, 0, stream>>>(z3, hw_w, hw_g, hw_b, G3, 64, 64);
  k_attn <<<dim3(NWIN,8), 256, 0, stream>>>(dots, G1, G2, G3, v, o_img);
  k_fw   <<<8192, 256, 0, stream>>>(o_img, Fw);
  k_fh   <<<8192, 256, 0, stream>>>(o_img, Fh);
  k_comb <<<512, 256, 0, stream>>>(o_img, Fh, Fw, local, comb);
  k_dw   <<<dim3(8,8,BB*128), blk2, 0, stream>>>(comb, proj_dw, proj_g, proj_b, proj1);
  k_pw   <<<dim3(1024,2), blk2, 0, stream>>>(proj1, proj_pw, om);
  k_up   <<<dim3(8,8,BB*64), blk2, 0, stream>>>(om, up_w, outp);
}

// Round 3
// 2946.908 us; speedup vs baseline: 1.7066x; 1.7066x over previous
//
#include <hip/hip_runtime.h>
#include <hip/hip_bf16.h>

typedef __hip_bfloat16 bf16;
typedef __attribute__((ext_vector_type(8))) short short8;
typedef __attribute__((ext_vector_type(4))) float f32x4;

#define DEV __device__ __forceinline__
DEV float b2f(bf16 v){ return __bfloat162float(v); }
DEV bf16 f2b(float v){ return __float2bfloat16(v); }
DEV short f2bs(float v){ union{ bf16 b; short s; } u; u.b = __float2bfloat16(v); return u.s; }
DEV float sigm(float x){ return 1.f/(1.f + expf(-x)); }

// ---- problem constants ----
#define BB 4
#define CIN 256
#define MID 128
#define COUT 64
#define HH 128
#define WW 128
#define WS 8
#define HEADS 8
#define HD 16
#define NTOK 64
#define NWIN 1024

// ---- workspace layout (bytes) ----
static const size_t OFF_H     = 0;                       // fp32 8388608  (33554432 B)
static const size_t OFF_LOCAL = 33554432;                // fp32 8388608
static const size_t OFF_Q     = 67108864;                // bf16 8388608  (16777216 B)
static const size_t OFF_K     = 83886080;                // bf16 8388608
static const size_t OFF_V     = 100663296;               // bf16 8388608
static const size_t OFF_DOTS  = 117440512;               // bf16 33554432 (67108864 B)
static const size_t OFF_Z1    = 184549376;               // bf16 1048576  (2097152 B)
static const size_t OFF_Z2    = 186646528;               // bf16 1048576
static const size_t OFF_Z3    = 188743680;               // bf16 8388608  (16777216 B)
static const size_t OFF_G1    = 205520896;               // fp32 524288   (2097152 B)
static const size_t OFF_G2    = 207618048;               // fp32 524288
static const size_t OFF_G3    = 209715200;               // fp32 4194304  (16777216 B)
// total 226492416 B.
// Transient reuse: xT (bf16, 34MB) -> OFF_DOTS (dead before k_dots writes dots)
//                  w2 (bf16, 590KB) -> OFF_Z1  (dead before k_z1 writes z1)
// o_img->OFF_Q, Fh/Fw->OFF_DOTS, comb->OFF_H, proj1->OFF_LOCAL, om->OFF_Q.

// ============ P1: repack conv_w (128,256,3,3) fp32 -> w2[kk][co][ci] bf16 ============
__global__ __launch_bounds__(256) void k_wrep(const float* __restrict__ w, short* __restrict__ w2){
  int i = blockIdx.x*256 + threadIdx.x;      // 294912 total
  int ci = i & 255, co = (i >> 8) & 127, kk = i >> 15;
  w2[i] = f2bs(w[(co*256 + ci)*9 + kk]);
}

// ============ P2: zero pad columns of xT ============
__global__ void k_xzero(short* __restrict__ xT){
  int t = blockIdx.x*256 + threadIdx.x;      // 262144 total
  int ci = t & 255, side = (t >> 8) & 1, row = t >> 9;   // row = b*128 + r
  int cpad = side ? 129 : 0;
  xT[((size_t)row*130 + cpad)*256 + ci] = 0;
}

// ============ P3: x NCHW fp32 -> xT[b][r][c+1][ci] bf16 (NHWC w/ halo cols) ============
__global__ __launch_bounds__(256) void k_xrep(const float* __restrict__ x, short* __restrict__ xT){
  const int blk = blockIdx.x;                // 8192 blocks
  const int cgrp = blk & 1, cig = (blk >> 1) & 7, r = (blk >> 4) & 127, b = blk >> 11;
  const int c0 = cgrp*64, ci0 = cig*32;
  __shared__ float lds[32][65];
  const int t = threadIdx.x;
  for (int i = t; i < 2048; i += 256){
    int lci = i >> 6, c = i & 63;
    lds[lci][c] = x[((size_t)(b*256 + ci0 + lci)*128 + r)*128 + c0 + c];
  }
  __syncthreads();
  for (int i = t; i < 2048; i += 256){
    int lci = i & 31, cc = i >> 5;
    xT[((size_t)(b*128 + r)*130 + c0 + cc + 1)*256 + ci0 + lci] = f2bs(lds[lci][cc]);
  }
}

// ============ K1: conv3x3 256->128 + bn + relu  (MFMA implicit GEMM) ============
// block = (b,y) image row: M=128 pixels, N=128 co, K=2304 as 3ky x 8chunks(32ci) x 3kx
__global__ __launch_bounds__(256) void k_conv1m(const short* __restrict__ xT, const short* __restrict__ w2,
      const float* __restrict__ gg, const float* __restrict__ bb, float* __restrict__ h){
  const int blk = blockIdx.x;
  const int b = blk >> 7, y = blk & 127;
  const int t = threadIdx.x, lane = t & 63, wave = t >> 6;
  const int quad = lane >> 4, l15 = lane & 15;
  const int m0 = (wave >> 1)*64, n0 = (wave & 1)*64;
  __shared__ short as[130][32];    // as[col][ci]  (col = x+1, halo baked in xT)
  __shared__ short bs[384][32];    // bs[kx*128+co][ci]
  f32x4 acc[4][4];
  #pragma unroll
  for (int i = 0; i < 4; ++i)
    #pragma unroll
    for (int j = 0; j < 4; ++j) acc[i][j] = (f32x4){0.f,0.f,0.f,0.f};
  for (int ky = 0; ky < 3; ++ky){
    int r = y + ky - 1;
    if ((unsigned)r >= 128u) continue;           // block-uniform
    const short* xrow = xT + (size_t)(b*128 + r)*130*256;
    const short* wk   = w2 + (size_t)ky*384*256;
    for (int ch = 0; ch < 8; ++ch){
      const int ci0 = ch*32;
      __syncthreads();
      for (int i = t; i < 520; i += 256){        // A: 130 cols x 32 ci, 16B each
        int col = i >> 2, cg = i & 3;
        *(uint4*)&as[col][cg*8] = *(const uint4*)&xrow[col*256 + ci0 + cg*8];
      }
      for (int i = t; i < 1536; i += 256){       // B: 384 rows x 32 ci
        int rr = i >> 2, cg = i & 3;
        *(uint4*)&bs[rr][cg*8] = *(const uint4*)&wk[rr*256 + ci0 + cg*8];
      }
      __syncthreads();
      #pragma unroll
      for (int kx = 0; kx < 3; ++kx){
        short8 af[4], bf[4];
        #pragma unroll
        for (int mt = 0; mt < 4; ++mt)
          af[mt] = *(const short8*)&as[m0 + mt*16 + l15 + kx][quad*8];
        #pragma unroll
        for (int nt = 0; nt < 4; ++nt)
          bf[nt] = *(const short8*)&bs[kx*128 + n0 + nt*16 + l15][quad*8];
        #pragma unroll
        for (int mt = 0; mt < 4; ++mt)
          #pragma unroll
          for (int nt = 0; nt < 4; ++nt)
            acc[mt][nt] = __builtin_amdgcn_mfma_f32_16x16x32_bf16(af[mt], bf[nt], acc[mt][nt], 0, 0, 0);
      }
    }
  }
  // epilogue: D row m(=pixel x) = quad*4+reg, col n(=co) = l15
  #pragma unroll
  for (int nt = 0; nt < 4; ++nt){
    int co = n0 + nt*16 + l15;
    float g = gg[co], bia = bb[co];
    #pragma unroll
    for (int mt = 0; mt < 4; ++mt){
      int xb = m0 + mt*16 + quad*4;
      float4 o4;
      o4.x = fmaxf(acc[mt][nt][0]*g + bia, 0.f);
      o4.y = fmaxf(acc[mt][nt][1]*g + bia, 0.f);
      o4.z = fmaxf(acc[mt][nt][2]*g + bia, 0.f);
      o4.w = fmaxf(acc[mt][nt][3]*g + bia, 0.f);
      *(float4*)&h[((size_t)(b*128 + co)*128 + y)*128 + xb] = o4;
    }
  }
}

// ============ K2: local = bn(1x1) + bn(3x3) ============
__global__ __launch_bounds__(256) void k_local(const float* __restrict__ h,
      const float* __restrict__ w1, const float* __restrict__ g1, const float* __restrict__ b1,
      const float* __restrict__ w2, const float* __restrict__ g2, const float* __restrict__ b2,
      float* __restrict__ out){
  const int tx = threadIdx.x, ty = threadIdx.y, t = ty*16+tx;
  const int bz = blockIdx.z; const int b = bz >> 6; const int co0 = (bz & 63)*2;
  const int ox = blockIdx.x*16, oy = blockIdx.y*16;
  __shared__ float wsm1[2*128*9];
  __shared__ float wsm2[2*128];
  __shared__ float xs[8][18][18];
  for (int i = t; i < 2*128*9; i += 256){
    int c = i / 1152, r = i % 1152;
    wsm1[i] = w1[(co0+c)*1152 + r];
  }
  if (t < 256) wsm2[t] = w2[(co0 + (t>>7))*128 + (t&127)];
  float a3[2] = {0.f,0.f}; float a1x[2] = {0.f,0.f};
  for (int cc = 0; cc < 16; ++cc){
    __syncthreads();
    for (int i = t; i < 8*324; i += 256){
      int ci = i / 324, r = i % 324; int iy = r / 18, ix = r % 18;
      int gy = oy + iy - 1, gx = ox + ix - 1;
      float v = 0.f;
      if ((unsigned)gy < 128u && (unsigned)gx < 128u)
        v = h[((size_t)(b*128 + cc*8+ci)*128 + gy)*128 + gx];
      xs[ci][iy][ix] = v;
    }
    __syncthreads();
    #pragma unroll
    for (int ci = 0; ci < 8; ++ci){
      const float* wp = &wsm1[(cc*8+ci)*9];
      const float* wq = wp + 1152;
      float ctr = xs[ci][ty+1][tx+1];
      a1x[0] += ctr * wsm2[cc*8+ci];
      a1x[1] += ctr * wsm2[128 + cc*8+ci];
      #pragma unroll
      for (int ky = 0; ky < 3; ++ky)
        #pragma unroll
        for (int kx = 0; kx < 3; ++kx){
          float xv = xs[ci][ty+ky][tx+kx];
          a3[0] += xv * wp[ky*3+kx];
          a3[1] += xv * wq[ky*3+kx];
        }
    }
  }
  size_t oidx = ((size_t)(b*128 + co0)*128 + oy+ty)*128 + ox+tx;
  #pragma unroll
  for (int c = 0; c < 2; ++c){
    float r = a3[c]*g1[co0+c] + b1[co0+c] + a1x[c]*g2[co0+c] + b2[co0+c];
    out[oidx + (size_t)c*128*128] = r;
  }
}

// ============ K3: 1x1 qkv conv -> windowed q,k,v (bf16) ============
__global__ __launch_bounds__(256) void k_qkv(const float* __restrict__ h, const float* __restrict__ w,
     bf16* __restrict__ q, bf16* __restrict__ k, bf16* __restrict__ v){
  const int bw = blockIdx.x, ocb = blockIdx.y;
  const int b = bw >> 8, wy = (bw >> 4) & 15, wx = bw & 15;
  __shared__ float hs[128][64];
  __shared__ float wsm[64][129];
  const int tx = threadIdx.x, ty = threadIdx.y, t = ty*16+tx;
  for (int i = t; i < 128*64; i += 256){
    int ci = i >> 6, n = i & 63; int yy = wy*8 + (n>>3), xx = wx*8 + (n&7);
    hs[ci][n] = h[((size_t)(b*128+ci)*128 + yy)*128 + xx];
  }
  for (int i = t; i < 64*128; i += 256){
    int oc = i >> 7, ci = i & 127;
    wsm[oc][ci] = w[(ocb*64+oc)*128 + ci];
  }
  __syncthreads();
  float acc[4][4] = {};
  for (int ci = 0; ci < 128; ++ci){
    float hv[4], wv[4];
    #pragma unroll
    for (int jj = 0; jj < 4; ++jj) hv[jj] = hs[ci][jj*16+tx];
    #pragma unroll
    for (int ii = 0; ii < 4; ++ii) wv[ii] = wsm[ii*16+ty][ci];
    #pragma unroll
    for (int ii = 0; ii < 4; ++ii)
      #pragma unroll
      for (int jj = 0; jj < 4; ++jj) acc[ii][jj] += wv[ii]*hv[jj];
  }
  #pragma unroll
  for (int ii = 0; ii < 4; ++ii){
    int oc = ocb*64 + ii*16 + ty;
    int s = oc >> 7, rem = oc & 127, head = rem >> 4, d = rem & 15;
    bf16* dst = (s==0) ? q : (s==1) ? k : v;
    #pragma unroll
    for (int jj = 0; jj < 4; ++jj){
      int n = jj*16 + tx;
      dst[((size_t)(bw*8+head)*64 + n)*16 + d] = f2b(acc[ii][jj]);
    }
  }
}

// ============ K4: dots = q.k^T * 0.25 + relpos bias ============
__global__ __launch_bounds__(256) void k_dots(const bf16* __restrict__ q, const bf16* __restrict__ kk,
      const float* __restrict__ rel, bf16* __restrict__ dots){
  const int bw = blockIdx.x, hd = blockIdx.y;
  __shared__ bf16 qs[64][16], ks[64][16];
  const int t = threadIdx.x;
  const size_t base = (size_t)(bw*8+hd)*1024;
  for (int i = t; i < 1024; i += 256){ qs[i>>4][i&15] = q[base + i]; ks[i>>4][i&15] = kk[base + i]; }
  __syncthreads();
  const int n = t >> 2, jm = t & 3;
  float qr[16];
  #pragma unroll
  for (int d = 0; d < 16; ++d) qr[d] = b2f(qs[n][d]);
  const int ny = n >> 3, nx = n & 7;
  for (int mm = 0; mm < 16; ++mm){
    int m = jm*16 + mm;
    float a = 0.f;
    #pragma unroll
    for (int d = 0; d < 16; ++d) a += qr[d]*b2f(ks[m][d]);
    int my = m >> 3, mx = m & 7;
    int ridx = (ny - my + 7)*15 + (nx - mx + 7);
    float bias = rel[ridx*8 + hd];
    dots[base*4 + (size_t)n*64 + m] = f2b(a*0.25f + bias);
  }
}

// ============ K5: axis reductions (max, mean) ============
__global__ void k_z1(const bf16* __restrict__ dots, bf16* __restrict__ z){
  int t = blockIdx.x*256 + threadIdx.x;
  int bw = t >> 9, r = t & 511; int hd = r >> 6, m = r & 63;
  const bf16* p = dots + (size_t)(bw*8+hd)*4096 + m;
  float mx = -1e30f, sm = 0.f;
  for (int n = 0; n < 64; ++n){ float v = b2f(p[n*64]); mx = fmaxf(mx,v); sm += v; }
  z[(size_t)bw*1024 + hd*64 + m]       = f2b(mx);
  z[(size_t)bw*1024 + 512 + hd*64 + m] = f2b(sm*(1.f/64.f));
}
__global__ void k_z2(const bf16* __restrict__ dots, bf16* __restrict__ z){
  int t = blockIdx.x*256 + threadIdx.x;
  int bw = t >> 9, r = t & 511; int n = r >> 3, hd = r & 7;
  const bf16* p = dots + ((size_t)(bw*8+hd)*64 + n)*64;
  float mx = -1e30f, sm = 0.f;
  for (int m = 0; m < 64; ++m){ float v = b2f(p[m]); mx = fmaxf(mx,v); sm += v; }
  z[(size_t)bw*1024 + n*8 + hd]       = f2b(mx);
  z[(size_t)bw*1024 + 512 + n*8 + hd] = f2b(sm*(1.f/64.f));
}
__global__ void k_z3(const bf16* __restrict__ dots, bf16* __restrict__ z){
  int t = blockIdx.x*256 + threadIdx.x;
  int bw = t >> 12, r = t & 4095;
  const bf16* p = dots + (size_t)bw*32768 + r;
  float mx = -1e30f, sm = 0.f;
  for (int hd = 0; hd < 8; ++hd){ float v = b2f(p[hd*4096]); mx = fmaxf(mx,v); sm += v; }
  z[(size_t)bw*8192 + r]        = f2b(mx);
  z[(size_t)bw*8192 + 4096 + r] = f2b(sm*0.125f);
}

// ============ K6: 7x7 2->1 conv + bn + sigmoid ============
__global__ __launch_bounds__(256) void k_gate(const bf16* __restrict__ z, const float* __restrict__ w,
      const float* __restrict__ gg, const float* __restrict__ bb, float* __restrict__ G, int R, int C){
  __shared__ float wsm[98];
  const int t = threadIdx.x;
  if (t < 98) wsm[t] = w[t];
  __syncthreads();
  const int bw = blockIdx.x;
  int p = blockIdx.y*256 + t; if (p >= R*C) return;
  int y = p / C, x = p - y*C;
  float acc = 0.f;
  for (int c = 0; c < 2; ++c)
    for (int ky = 0; ky < 7; ++ky){
      int iy = y + ky - 3; if ((unsigned)iy >= (unsigned)R) continue;
      for (int kx = 0; kx < 7; ++kx){
        int ix = x + kx - 3; if ((unsigned)ix >= (unsigned)C) continue;
        acc += b2f(z[((size_t)(bw*2+c)*R + iy)*C + ix]) * wsm[c*49 + ky*7 + kx];
      }
    }
  G[(size_t)bw*R*C + p] = sigm(acc*gg[0] + bb[0]);
}

// ============ K7: gated softmax + attn@v -> o (image layout, fp32) ============
__global__ __launch_bounds__(256) void k_attn(const bf16* __restrict__ dots, const float* __restrict__ G1,
      const float* __restrict__ G2, const float* __restrict__ G3, const bf16* __restrict__ v,
      float* __restrict__ o){
  const int bw = blockIdx.x, hd = blockIdx.y;
  const int b = bw >> 8, wy = (bw >> 4) & 15, wx = bw & 15;
  __shared__ float attn[64][65];
  __shared__ bf16 vs[64][16];
  __shared__ float invTot[64];
  const int t = threadIdx.x;
  for (int i = t; i < 1024; i += 256) vs[i>>4][i&15] = v[(size_t)(bw*8+hd)*1024 + i];
  const int n = t >> 2, j = t & 3;
  float g2v = G2[(size_t)bw*512 + n*8 + hd];
  const bf16* dp = dots + ((size_t)(bw*8+hd)*64 + n)*64 + j*16;
  const float* g1p = G1 + (size_t)bw*512 + hd*64 + j*16;
  const float* g3p = G3 + (size_t)bw*4096 + n*64 + j*16;
  float e[16]; float mx = -1e30f;
  #pragma unroll
  for (int m = 0; m < 16; ++m){
    float dv = b2f(dp[m]) * ((g1p[m] + g2v + g3p[m]) * (1.f/3.f));
    e[m] = dv; mx = fmaxf(mx, dv);
  }
  mx = fmaxf(mx, __shfl_xor(mx, 1, 4));
  mx = fmaxf(mx, __shfl_xor(mx, 2, 4));
  float s = 0.f;
  #pragma unroll
  for (int m = 0; m < 16; ++m){ float ev = expf(e[m]-mx); e[m] = ev; s += ev; }
  s += __shfl_xor(s, 1, 4);
  s += __shfl_xor(s, 2, 4);
  #pragma unroll
  for (int m = 0; m < 16; ++m) attn[n][j*16+m] = e[m];
  if (j == 0) invTot[n] = 1.f/s;
  __syncthreads();
  const int dg = j;
  float acc[4] = {0.f,0.f,0.f,0.f};
  for (int m = 0; m < 64; ++m){
    float a = attn[n][m];
    #pragma unroll
    for (int dd = 0; dd < 4; ++dd) acc[dd] += a * b2f(vs[m][dg*4+dd]);
  }
  float it = invTot[n];
  int y = wy*8 + (n>>3), x = wx*8 + (n&7);
  #pragma unroll
  for (int dd = 0; dd < 4; ++dd){
    int c = hd*16 + dg*4 + dd;
    o[((size_t)(b*128+c)*128 + y)*128 + x] = acc[dd]*it;
  }
}

// ============ K8: Fh / Fw axial gates ============
__global__ void k_fw(const float* __restrict__ o, float* __restrict__ Fw){
  int t = blockIdx.x*256 + threadIdx.x; if (t >= 4*128*32*128) return;
  int x = t & 127, kk = (t>>7) & 31, bc = t >> 12;
  const float* p = o + ((size_t)bc*128 + kk*4)*128 + x;
  float mx = -1e30f, sm = 0.f;
  #pragma unroll
  for (int r = 0; r < 4; ++r){ float v = p[r*128]; mx = fmaxf(mx,v); sm += v; }
  Fw[t] = sigm(sm*0.25f + mx);
}
__global__ void k_fh(const float* __restrict__ o, float* __restrict__ Fh){
  int t = blockIdx.x*256 + threadIdx.x; if (t >= 4*128*128*32) return;
  int kk = t & 31, y = (t>>5) & 127, bc = t >> 12;
  const float* p = o + ((size_t)bc*128 + y)*128 + kk*4;
  float mx = -1e30f, sm = 0.f;
  #pragma unroll
  for (int r = 0; r < 4; ++r){ float v = p[r]; mx = fmaxf(mx,v); sm += v; }
  Fh[t] = sigm(sm*0.25f + mx);
}

// ============ K9: comb = o * (Fh@Fw) + local ============
__global__ __launch_bounds__(256) void k_comb(const float* __restrict__ o, const float* __restrict__ Fh,
      const float* __restrict__ Fw, const float* __restrict__ local, float* __restrict__ comb){
  const int bc = blockIdx.x;
  __shared__ float fh[128][33];
  __shared__ float fw[32][129];
  const int t = threadIdx.x;
  for (int i = t; i < 4096; i += 256) fh[i>>5][i&31]  = Fh[(size_t)bc*4096 + i];
  for (int i = t; i < 4096; i += 256) fw[i>>7][i&127] = Fw[(size_t)bc*4096 + i];
  __syncthreads();
  for (int i = t; i < 16384; i += 256){
    int y = i >> 7, x = i & 127;
    float g = 0.f;
    #pragma unroll
    for (int kk = 0; kk < 32; ++kk) g += fh[y][kk]*fw[kk][x];
    size_t idx = (size_t)bc*16384 + i;
    comb[idx] = o[idx]*g + local[idx];
  }
}

// ============ K10: reflect-pad + depthwise 8x8 (pad 3) + bn ============
__global__ __launch_bounds__(256) void k_dw(const float* __restrict__ comb, const float* __restrict__ dw,
      const float* __restrict__ gg, const float* __restrict__ bb, float* __restrict__ out){
  const int tx = threadIdx.x, ty = threadIdx.y, t = ty*16+tx;
  const int bz = blockIdx.z; const int c = bz & 127;
  const int oy0 = blockIdx.y*16, ox0 = blockIdx.x*16;
  __shared__ float xs[23][23];
  __shared__ float wsm[64];
  if (t < 64) wsm[t] = dw[c*64 + t];
  for (int i = t; i < 529; i += 256){
    int iy = i/23, ix = i - iy*23;
    int y = oy0 + iy - 3, x = ox0 + ix - 3;
    float v = 0.f;
    if (y >= 0 && y <= 128 && x >= 0 && x <= 128){
      int yy = (y==128)?126:y, xx = (x==128)?126:x;
      v = comb[((size_t)bz*128 + yy)*128 + xx];
    }
    xs[iy][ix] = v;
  }
  __syncthreads();
  float acc = 0.f;
  #pragma unroll
  for (int ky = 0; ky < 8; ++ky)
    #pragma unroll
    for (int kx = 0; kx < 8; ++kx)
      acc += xs[ty+ky][tx+kx]*wsm[ky*8+kx];
  out[((size_t)bz*128 + oy0+ty)*128 + ox0+tx] = acc*gg[c] + bb[c];
}

// ============ K11: 1x1 proj conv 128->128 ============
__global__ __launch_bounds__(256) void k_pw(const float* __restrict__ p1, const float* __restrict__ w,
      float* __restrict__ om){
  const int pt = blockIdx.x, cb = blockIdx.y;
  const int P0 = pt*64; const int b = P0 >> 14; const int rem0 = P0 & 16383;
  __shared__ float xsm[128][65];
  __shared__ float wsm[64][129];
  const int tx = threadIdx.x, ty = threadIdx.y, t = ty*16+tx;
  for (int i = t; i < 128*64; i += 256){
    int ci = i >> 6, p = i & 63;
    xsm[ci][p] = p1[(size_t)(b*128+ci)*16384 + rem0 + p];
  }
  for (int i = t; i < 64*128; i += 256){
    int co = i >> 7, ci = i & 127;
    wsm[co][ci] = w[(cb*64+co)*128 + ci];
  }
  __syncthreads();
  float acc[4][4] = {};
  for (int ci = 0; ci < 128; ++ci){
    float hv[4], wv[4];
    #pragma unroll
    for (int jj = 0; jj < 4; ++jj) hv[jj] = xsm[ci][jj*16+tx];
    #pragma unroll
    for (int ii = 0; ii < 4; ++ii) wv[ii] = wsm[ii*16+ty][ci];
    #pragma unroll
    for (int ii = 0; ii < 4; ++ii)
      #pragma unroll
      for (int jj = 0; jj < 4; ++jj) acc[ii][jj] += wv[ii]*hv[jj];
  }
  #pragma unroll
  for (int ii = 0; ii < 4; ++ii){
    int co = cb*64 + ii*16 + ty;
    #pragma unroll
    for (int jj = 0; jj < 4; ++jj)
      om[(size_t)(b*128+co)*16384 + rem0 + jj*16+tx] = acc[ii][jj];
  }
}

// ============ K12: stride-2 transposed 3x3 conv 128->64 ============
__global__ __launch_bounds__(256) void k_up(const float* __restrict__ om, const float* __restrict__ w,
      float* __restrict__ out){
  const int tx = threadIdx.x, ty = threadIdx.y, t = ty*16+tx;
  const int bz = blockIdx.z; const int b = bz >> 6, co = bz & 63;
  const int y0 = blockIdx.y*16, x0 = blockIdx.x*16;
  __shared__ float wsm[128*9];
  __shared__ float xs[8][17][18];
  for (int i = t; i < 1152; i += 256) wsm[i] = w[co*1152 + i];
  float a00=0.f, a01=0.f, a10=0.f, a11=0.f;
  for (int cc = 0; cc < 16; ++cc){
    __syncthreads();
    for (int i = t; i < 8*289; i += 256){
      int ci = i / 289, r = i % 289, iy = r/17, ix = r - iy*17;
      int y = y0+iy, x = x0+ix;
      float v = 0.f;
      if (y < 128 && x < 128) v = om[((size_t)(b*128 + cc*8+ci)*128 + y)*128 + x];
      xs[ci][iy][ix] = v;
    }
    __syncthreads();
    #pragma unroll
    for (int ci = 0; ci < 8; ++ci){
      const float* wp = &wsm[(cc*8+ci)*9];
      float xa = xs[ci][ty][tx],   xb = xs[ci][ty][tx+1];
      float xc = xs[ci][ty+1][tx], xd = xs[ci][ty+1][tx+1];
      a00 += wp[4]*xa;
      a01 += wp[3]*xa + wp[5]*xb;
      a10 += wp[1]*xa + wp[7]*xc;
      a11 += wp[0]*xa + wp[2]*xb + wp[6]*xc + wp[8]*xd;
    }
  }
  int Y = 2*(y0+ty), X = 2*(x0+tx);
  size_t base = ((size_t)bz*256 + Y)*256 + X;
  out[base]     = a00; out[base+1]   = a01;
  out[base+256] = a10; out[base+257] = a11;
}

extern "C" void kernel_launch(void* const* d_in, const int* in_sizes, int n_in,
                              void* d_out, int out_size, void* d_ws, size_t ws_size,
                              hipStream_t stream) {
  const float* x       = (const float*)d_in[0];
  const float* conv_w  = (const float*)d_in[1];
  const float* bn1_g   = (const float*)d_in[2];
  const float* bn1_b   = (const float*)d_in[3];
  const float* qkv_w   = (const float*)d_in[4];
  const float* loc1_w  = (const float*)d_in[5];
  const float* loc1_g  = (const float*)d_in[6];
  const float* loc1_b  = (const float*)d_in[7];
  const float* loc2_w  = (const float*)d_in[8];
  const float* loc2_g  = (const float*)d_in[9];
  const float* loc2_b  = (const float*)d_in[10];
  const float* rel_t   = (const float*)d_in[11];
  const float* cw_w    = (const float*)d_in[12];
  const float* cw_g    = (const float*)d_in[13];
  const float* cw_b    = (const float*)d_in[14];
  const float* hc_w    = (const float*)d_in[15];
  const float* hc_g    = (const float*)d_in[16];
  const float* hc_b    = (const float*)d_in[17];
  const float* hw_w    = (const float*)d_in[18];
  const float* hw_g    = (const float*)d_in[19];
  const float* hw_b    = (const float*)d_in[20];
  const float* proj_dw = (const float*)d_in[21];
  const float* proj_g  = (const float*)d_in[22];
  const float* proj_b  = (const float*)d_in[23];
  const float* proj_pw = (const float*)d_in[24];
  const float* up_w    = (const float*)d_in[25];

  char* ws = (char*)d_ws;
  float* h      = (float*)(ws + OFF_H);
  float* local  = (float*)(ws + OFF_LOCAL);
  bf16*  q      = (bf16*)(ws + OFF_Q);
  bf16*  k      = (bf16*)(ws + OFF_K);
  bf16*  v      = (bf16*)(ws + OFF_V);
  bf16*  dots   = (bf16*)(ws + OFF_DOTS);
  bf16*  z1     = (bf16*)(ws + OFF_Z1);
  bf16*  z2     = (bf16*)(ws + OFF_Z2);
  bf16*  z3     = (bf16*)(ws + OFF_Z3);
  float* G1     = (float*)(ws + OFF_G1);
  float* G2     = (float*)(ws + OFF_G2);
  float* G3     = (float*)(ws + OFF_G3);
  short* xT     = (short*)(ws + OFF_DOTS);              // transient (dead before dots)
  short* w2bf   = (short*)(ws + OFF_Z1);                // transient (dead before z1)
  float* o_img  = (float*)(ws + OFF_Q);
  float* Fh     = (float*)(ws + OFF_DOTS);
  float* Fw     = (float*)(ws + OFF_DOTS + 8388608);
  float* comb   = (float*)(ws + OFF_H);
  float* proj1  = (float*)(ws + OFF_LOCAL);
  float* om     = (float*)(ws + OFF_Q);
  float* outp   = (float*)d_out;

  dim3 blk2(16,16);
  k_wrep <<<1152, 256, 0, stream>>>(conv_w, w2bf);
  k_xzero<<<1024, 256, 0, stream>>>(xT);
  k_xrep <<<8192, 256, 0, stream>>>(x, xT);
  k_conv1m<<<512, 256, 0, stream>>>(xT, w2bf, bn1_g, bn1_b, h);
  k_local<<<dim3(8,8,BB*64), blk2, 0, stream>>>(h, loc1_w, loc1_g, loc1_b, loc2_w, loc2_g, loc2_b, local);
  k_qkv  <<<dim3(NWIN,6), blk2, 0, stream>>>(h, qkv_w, q, k, v);
  k_dots <<<dim3(NWIN,8), 256, 0, stream>>>(q, k, rel_t, dots);
  k_z1   <<<2048, 256, 0, stream>>>(dots, z1);
  k_z2   <<<2048, 256, 0, stream>>>(dots, z2);
  k_z3   <<<16384, 256, 0, stream>>>(dots, z3);
  k_gate <<<dim3(NWIN,2),  256, 0, stream>>>(z1, cw_w, cw_g, cw_b, G1, 8, 64);
  k_gate <<<dim3(NWIN,2),  256, 0, stream>>>(z2, hc_w, hc_g, hc_b, G2, 64, 8);
  k_gate <<<dim3(NWIN,16), 256, 0, stream>>>(z3, hw_w, hw_g, hw_b, G3, 64, 64);
  k_attn <<<dim3(NWIN,8), 256, 0, stream>>>(dots, G1, G2, G3, v, o_img);
  k_fw   <<<8192, 256, 0, stream>>>(o_img, Fw);
  k_fh   <<<8192, 256, 0, stream>>>(o_img, Fh);
  k_comb <<<512, 256, 0, stream>>>(o_img, Fh, Fw, local, comb);
  k_dw   <<<dim3(8,8,BB*128), blk2, 0, stream>>>(comb, proj_dw, proj_g, proj_b, proj1);
  k_pw   <<<dim3(1024,2), blk2, 0, stream>>>(proj1, proj_pw, om);
  k_up   <<<dim3(8,8,BB*64), blk2, 0, stream>>>(om, up_w, outp);
}

// Round 4
// 1748.713 us; speedup vs baseline: 2.8759x; 1.6852x over previous
//
#include <hip/hip_runtime.h>
#include <hip/hip_bf16.h>

typedef __hip_bfloat16 bf16;
typedef __attribute__((ext_vector_type(8))) short short8;
typedef __attribute__((ext_vector_type(4))) float f32x4;

#define DEV __device__ __forceinline__
DEV float b2f(bf16 v){ return __bfloat162float(v); }
DEV bf16 f2b(float v){ return __float2bfloat16(v); }
DEV short f2bs(float v){ union{ bf16 b; short s; } u; u.b = __float2bfloat16(v); return u.s; }
DEV float sigm(float x){ return 1.f/(1.f + expf(-x)); }

// ---- problem constants ----
#define BB 4
#define CIN 256
#define MID 128
#define COUT 64
#define HH 128
#define WW 128
#define WS 8
#define HEADS 8
#define HD 16
#define NTOK 64
#define NWIN 1024

// ---- workspace layout (bytes) ----
static const size_t OFF_H     = 0;                       // fp32 8388608  (33554432 B)
static const size_t OFF_LOCAL = 33554432;                // fp32 8388608
static const size_t OFF_Q     = 67108864;                // bf16 8388608  (16777216 B)
static const size_t OFF_K     = 83886080;                // bf16 8388608
static const size_t OFF_V     = 100663296;               // bf16 8388608
static const size_t OFF_DOTS  = 117440512;               // bf16 33554432 (67108864 B)
static const size_t OFF_Z1    = 184549376;               // bf16 1048576  (2097152 B)
static const size_t OFF_Z2    = 186646528;               // bf16 1048576
static const size_t OFF_Z3    = 188743680;               // bf16 8388608  (16777216 B)
static const size_t OFF_G1    = 205520896;               // fp32 524288   (2097152 B)
static const size_t OFF_G2    = 207618048;               // fp32 524288
static const size_t OFF_G3    = 209715200;               // fp32 4194304  (16777216 B)
// Transients: xT(34MB)->OFF_DOTS (dead before k_dots); hT(17MB)->OFF_DOTS+34MB
// (dead before k_dots); w2bf(conv1,590KB)->OFF_Z1; wloc(295KB)->OFF_Z2.
static const size_t OFF_HT    = OFF_DOTS + 34078720;     // bf16 [b][y][130][128]

// ============ P1: repack conv_w (128,256,3,3) fp32 -> w2[kk][co][ci] bf16 ============
__global__ __launch_bounds__(256) void k_wrep(const float* __restrict__ w, short* __restrict__ w2){
  int i = blockIdx.x*256 + threadIdx.x;      // 294912 total
  int ci = i & 255, co = (i >> 8) & 127, kk = i >> 15;
  w2[i] = f2bs(w[(co*256 + ci)*9 + kk]);
}

// ============ P2: zero pad columns of xT ============
__global__ void k_xzero(short* __restrict__ xT){
  int t = blockIdx.x*256 + threadIdx.x;      // 262144 total
  int ci = t & 255, side = (t >> 8) & 1, row = t >> 9;
  int cpad = side ? 129 : 0;
  xT[((size_t)row*130 + cpad)*256 + ci] = 0;
}

// ============ P3: x NCHW fp32 -> xT[b][r][c+1][ci] bf16 ============
__global__ __launch_bounds__(256) void k_xrep(const float* __restrict__ x, short* __restrict__ xT){
  const int blk = blockIdx.x;                // 8192 blocks
  const int cgrp = blk & 1, cig = (blk >> 1) & 7, r = (blk >> 4) & 127, b = blk >> 11;
  const int c0 = cgrp*64, ci0 = cig*32;
  __shared__ float lds[32][65];
  const int t = threadIdx.x;
  for (int i = t; i < 2048; i += 256){
    int lci = i >> 6, c = i & 63;
    lds[lci][c] = x[((size_t)(b*256 + ci0 + lci)*128 + r)*128 + c0 + c];
  }
  __syncthreads();
  for (int i = t; i < 2048; i += 256){
    int lci = i & 31, cc = i >> 5;
    xT[((size_t)(b*128 + r)*130 + c0 + cc + 1)*256 + ci0 + lci] = f2bs(lds[lci][cc]);
  }
}

// ============ K1: conv3x3 256->128 + bn + relu  (MFMA implicit GEMM) ============
__global__ __launch_bounds__(256) void k_conv1m(const short* __restrict__ xT, const short* __restrict__ w2,
      const float* __restrict__ gg, const float* __restrict__ bb, float* __restrict__ h){
  const int blk = blockIdx.x;
  const int b = blk >> 7, y = blk & 127;
  const int t = threadIdx.x, lane = t & 63, wave = t >> 6;
  const int quad = lane >> 4, l15 = lane & 15;
  const int m0 = (wave >> 1)*64, n0 = (wave & 1)*64;
  __shared__ short as[130][32];
  __shared__ short bs[384][32];
  f32x4 acc[4][4];
  #pragma unroll
  for (int i = 0; i < 4; ++i)
    #pragma unroll
    for (int j = 0; j < 4; ++j) acc[i][j] = (f32x4){0.f,0.f,0.f,0.f};
  for (int ky = 0; ky < 3; ++ky){
    int r = y + ky - 1;
    if ((unsigned)r >= 128u) continue;
    const short* xrow = xT + (size_t)(b*128 + r)*130*256;
    const short* wk   = w2 + (size_t)ky*384*256;
    for (int ch = 0; ch < 8; ++ch){
      const int ci0 = ch*32;
      __syncthreads();
      for (int i = t; i < 520; i += 256){
        int col = i >> 2, cg = i & 3;
        *(uint4*)&as[col][cg*8] = *(const uint4*)&xrow[col*256 + ci0 + cg*8];
      }
      for (int i = t; i < 1536; i += 256){
        int rr = i >> 2, cg = i & 3;
        *(uint4*)&bs[rr][cg*8] = *(const uint4*)&wk[rr*256 + ci0 + cg*8];
      }
      __syncthreads();
      #pragma unroll
      for (int kx = 0; kx < 3; ++kx){
        short8 af[4], bf[4];
        #pragma unroll
        for (int mt = 0; mt < 4; ++mt)
          af[mt] = *(const short8*)&as[m0 + mt*16 + l15 + kx][quad*8];
        #pragma unroll
        for (int nt = 0; nt < 4; ++nt)
          bf[nt] = *(const short8*)&bs[kx*128 + n0 + nt*16 + l15][quad*8];
        #pragma unroll
        for (int mt = 0; mt < 4; ++mt)
          #pragma unroll
          for (int nt = 0; nt < 4; ++nt)
            acc[mt][nt] = __builtin_amdgcn_mfma_f32_16x16x32_bf16(af[mt], bf[nt], acc[mt][nt], 0, 0, 0);
      }
    }
  }
  #pragma unroll
  for (int nt = 0; nt < 4; ++nt){
    int co = n0 + nt*16 + l15;
    float g = gg[co], bia = bb[co];
    #pragma unroll
    for (int mt = 0; mt < 4; ++mt){
      int xb = m0 + mt*16 + quad*4;
      float4 o4;
      o4.x = fmaxf(acc[mt][nt][0]*g + bia, 0.f);
      o4.y = fmaxf(acc[mt][nt][1]*g + bia, 0.f);
      o4.z = fmaxf(acc[mt][nt][2]*g + bia, 0.f);
      o4.w = fmaxf(acc[mt][nt][3]*g + bia, 0.f);
      *(float4*)&h[((size_t)(b*128 + co)*128 + y)*128 + xb] = o4;
    }
  }
}

// ============ P4: zero pad columns of hT ============
__global__ void k_hzero(short* __restrict__ hT){
  int t = blockIdx.x*256 + threadIdx.x;      // 131072 total
  int ci = t & 127, side = (t >> 7) & 1, row = t >> 8;   // row = b*128 + r
  int cpad = side ? 129 : 0;
  hT[((size_t)row*130 + cpad)*128 + ci] = 0;
}

// ============ P5: h NCHW fp32 -> hT[b][r][c+1][ci] bf16 ============
__global__ __launch_bounds__(256) void k_hrep(const float* __restrict__ h, short* __restrict__ hT){
  const int blk = blockIdx.x;                // 4096 blocks
  const int cgrp = blk & 1, cig = (blk >> 1) & 3, r = (blk >> 3) & 127, b = blk >> 10;
  const int c0 = cgrp*64, ci0 = cig*32;
  __shared__ float lds[32][65];
  const int t = threadIdx.x;
  for (int i = t; i < 2048; i += 256){
    int lci = i >> 6, c = i & 63;
    lds[lci][c] = h[((size_t)(b*128 + ci0 + lci)*128 + r)*128 + c0 + c];
  }
  __syncthreads();
  for (int i = t; i < 2048; i += 256){
    int lci = i & 31, cc = i >> 5;
    hT[((size_t)(b*128 + r)*130 + c0 + cc + 1)*128 + ci0 + lci] = f2bs(lds[lci][cc]);
  }
}

// ============ P6: fold local weights: wloc[ky][kx*128+co][ci] bf16 ============
// W' = loc1_w*g1[co] + center*loc2_w*g2[co]
__global__ __launch_bounds__(256) void k_lwrep(const float* __restrict__ w1, const float* __restrict__ g1,
      const float* __restrict__ w2, const float* __restrict__ g2, short* __restrict__ wloc){
  int i = blockIdx.x*256 + threadIdx.x;      // 147456 total
  int ci = i & 127, row = (i >> 7) % 384, ky = i / 49152;
  int kx = row >> 7, co = row & 127;
  float v = w1[(co*128 + ci)*9 + ky*3 + kx] * g1[co];
  if (ky == 1 && kx == 1) v += w2[co*128 + ci] * g2[co];
  wloc[i] = f2bs(v);
}

// ============ K2: local conv (folded 3x3+1x1)  (MFMA implicit GEMM) ============
__global__ __launch_bounds__(256) void k_localm(const short* __restrict__ hT, const short* __restrict__ wloc,
      const float* __restrict__ b1, const float* __restrict__ b2, float* __restrict__ out){
  const int blk = blockIdx.x;
  const int b = blk >> 7, y = blk & 127;
  const int t = threadIdx.x, lane = t & 63, wave = t >> 6;
  const int quad = lane >> 4, l15 = lane & 15;
  const int m0 = (wave >> 1)*64, n0 = (wave & 1)*64;
  __shared__ short as[130][32];
  __shared__ short bs[384][32];
  f32x4 acc[4][4];
  #pragma unroll
  for (int i = 0; i < 4; ++i)
    #pragma unroll
    for (int j = 0; j < 4; ++j) acc[i][j] = (f32x4){0.f,0.f,0.f,0.f};
  for (int ky = 0; ky < 3; ++ky){
    int r = y + ky - 1;
    if ((unsigned)r >= 128u) continue;
    const short* xrow = hT + (size_t)(b*128 + r)*130*128;
    const short* wk   = wloc + (size_t)ky*384*128;
    for (int ch = 0; ch < 4; ++ch){
      const int ci0 = ch*32;
      __syncthreads();
      for (int i = t; i < 520; i += 256){
        int col = i >> 2, cg = i & 3;
        *(uint4*)&as[col][cg*8] = *(const uint4*)&xrow[col*128 + ci0 + cg*8];
      }
      for (int i = t; i < 1536; i += 256){
        int rr = i >> 2, cg = i & 3;
        *(uint4*)&bs[rr][cg*8] = *(const uint4*)&wk[rr*128 + ci0 + cg*8];
      }
      __syncthreads();
      #pragma unroll
      for (int kx = 0; kx < 3; ++kx){
        short8 af[4], bf[4];
        #pragma unroll
        for (int mt = 0; mt < 4; ++mt)
          af[mt] = *(const short8*)&as[m0 + mt*16 + l15 + kx][quad*8];
        #pragma unroll
        for (int nt = 0; nt < 4; ++nt)
          bf[nt] = *(const short8*)&bs[kx*128 + n0 + nt*16 + l15][quad*8];
        #pragma unroll
        for (int mt = 0; mt < 4; ++mt)
          #pragma unroll
          for (int nt = 0; nt < 4; ++nt)
            acc[mt][nt] = __builtin_amdgcn_mfma_f32_16x16x32_bf16(af[mt], bf[nt], acc[mt][nt], 0, 0, 0);
      }
    }
  }
  #pragma unroll
  for (int nt = 0; nt < 4; ++nt){
    int co = n0 + nt*16 + l15;
    float bia = b1[co] + b2[co];
    #pragma unroll
    for (int mt = 0; mt < 4; ++mt){
      int xb = m0 + mt*16 + quad*4;
      float4 o4;
      o4.x = acc[mt][nt][0] + bia;
      o4.y = acc[mt][nt][1] + bia;
      o4.z = acc[mt][nt][2] + bia;
      o4.w = acc[mt][nt][3] + bia;
      *(float4*)&out[((size_t)(b*128 + co)*128 + y)*128 + xb] = o4;
    }
  }
}

// ============ K3: 1x1 qkv conv -> windowed q,k,v (bf16) ============
__global__ __launch_bounds__(256) void k_qkv(const float* __restrict__ h, const float* __restrict__ w,
     bf16* __restrict__ q, bf16* __restrict__ k, bf16* __restrict__ v){
  const int bw = blockIdx.x, ocb = blockIdx.y;
  const int b = bw >> 8, wy = (bw >> 4) & 15, wx = bw & 15;
  __shared__ float hs[128][64];
  __shared__ float wsm[64][129];
  const int tx = threadIdx.x, ty = threadIdx.y, t = ty*16+tx;
  for (int i = t; i < 128*64; i += 256){
    int ci = i >> 6, n = i & 63; int yy = wy*8 + (n>>3), xx = wx*8 + (n&7);
    hs[ci][n] = h[((size_t)(b*128+ci)*128 + yy)*128 + xx];
  }
  for (int i = t; i < 64*128; i += 256){
    int oc = i >> 7, ci = i & 127;
    wsm[oc][ci] = w[(ocb*64+oc)*128 + ci];
  }
  __syncthreads();
  float acc[4][4] = {};
  for (int ci = 0; ci < 128; ++ci){
    float hv[4], wv[4];
    #pragma unroll
    for (int jj = 0; jj < 4; ++jj) hv[jj] = hs[ci][jj*16+tx];
    #pragma unroll
    for (int ii = 0; ii < 4; ++ii) wv[ii] = wsm[ii*16+ty][ci];
    #pragma unroll
    for (int ii = 0; ii < 4; ++ii)
      #pragma unroll
      for (int jj = 0; jj < 4; ++jj) acc[ii][jj] += wv[ii]*hv[jj];
  }
  #pragma unroll
  for (int ii = 0; ii < 4; ++ii){
    int oc = ocb*64 + ii*16 + ty;
    int s = oc >> 7, rem = oc & 127, head = rem >> 4, d = rem & 15;
    bf16* dst = (s==0) ? q : (s==1) ? k : v;
    #pragma unroll
    for (int jj = 0; jj < 4; ++jj){
      int n = jj*16 + tx;
      dst[((size_t)(bw*8+head)*64 + n)*16 + d] = f2b(acc[ii][jj]);
    }
  }
}

// ============ K4: dots = q.k^T * 0.25 + relpos bias ============
__global__ __launch_bounds__(256) void k_dots(const bf16* __restrict__ q, const bf16* __restrict__ kk,
      const float* __restrict__ rel, bf16* __restrict__ dots){
  const int bw = blockIdx.x, hd = blockIdx.y;
  __shared__ bf16 qs[64][16], ks[64][16];
  const int t = threadIdx.x;
  const size_t base = (size_t)(bw*8+hd)*1024;
  for (int i = t; i < 1024; i += 256){ qs[i>>4][i&15] = q[base + i]; ks[i>>4][i&15] = kk[base + i]; }
  __syncthreads();
  const int n = t >> 2, jm = t & 3;
  float qr[16];
  #pragma unroll
  for (int d = 0; d < 16; ++d) qr[d] = b2f(qs[n][d]);
  const int ny = n >> 3, nx = n & 7;
  for (int mm = 0; mm < 16; ++mm){
    int m = jm*16 + mm;
    float a = 0.f;
    #pragma unroll
    for (int d = 0; d < 16; ++d) a += qr[d]*b2f(ks[m][d]);
    int my = m >> 3, mx = m & 7;
    int ridx = (ny - my + 7)*15 + (nx - mx + 7);
    float bias = rel[ridx*8 + hd];
    dots[base*4 + (size_t)n*64 + m] = f2b(a*0.25f + bias);
  }
}

// ============ K5: axis reductions ============
__global__ void k_z1(const bf16* __restrict__ dots, bf16* __restrict__ z){
  int t = blockIdx.x*256 + threadIdx.x;
  int bw = t >> 9, r = t & 511; int hd = r >> 6, m = r & 63;
  const bf16* p = dots + (size_t)(bw*8+hd)*4096 + m;
  float mx = -1e30f, sm = 0.f;
  for (int n = 0; n < 64; ++n){ float v = b2f(p[n*64]); mx = fmaxf(mx,v); sm += v; }
  z[(size_t)bw*1024 + hd*64 + m]       = f2b(mx);
  z[(size_t)bw*1024 + 512 + hd*64 + m] = f2b(sm*(1.f/64.f));
}
__global__ void k_z2(const bf16* __restrict__ dots, bf16* __restrict__ z){
  int t = blockIdx.x*256 + threadIdx.x;
  int bw = t >> 9, r = t & 511; int n = r >> 3, hd = r & 7;
  const bf16* p = dots + ((size_t)(bw*8+hd)*64 + n)*64;
  float mx = -1e30f, sm = 0.f;
  for (int m = 0; m < 64; ++m){ float v = b2f(p[m]); mx = fmaxf(mx,v); sm += v; }
  z[(size_t)bw*1024 + n*8 + hd]       = f2b(mx);
  z[(size_t)bw*1024 + 512 + n*8 + hd] = f2b(sm*(1.f/64.f));
}
__global__ void k_z3(const bf16* __restrict__ dots, bf16* __restrict__ z){
  int t = blockIdx.x*256 + threadIdx.x;
  int bw = t >> 12, r = t & 4095;
  const bf16* p = dots + (size_t)bw*32768 + r;
  float mx = -1e30f, sm = 0.f;
  for (int hd = 0; hd < 8; ++hd){ float v = b2f(p[hd*4096]); mx = fmaxf(mx,v); sm += v; }
  z[(size_t)bw*8192 + r]        = f2b(mx);
  z[(size_t)bw*8192 + 4096 + r] = f2b(sm*0.125f);
}

// ============ K6: 7x7 2->1 conv + bn + sigmoid ============
__global__ __launch_bounds__(256) void k_gate(const bf16* __restrict__ z, const float* __restrict__ w,
      const float* __restrict__ gg, const float* __restrict__ bb, float* __restrict__ G, int R, int C){
  __shared__ float wsm[98];
  const int t = threadIdx.x;
  if (t < 98) wsm[t] = w[t];
  __syncthreads();
  const int bw = blockIdx.x;
  int p = blockIdx.y*256 + t; if (p >= R*C) return;
  int y = p / C, x = p - y*C;
  float acc = 0.f;
  for (int c = 0; c < 2; ++c)
    for (int ky = 0; ky < 7; ++ky){
      int iy = y + ky - 3; if ((unsigned)iy >= (unsigned)R) continue;
      for (int kx = 0; kx < 7; ++kx){
        int ix = x + kx - 3; if ((unsigned)ix >= (unsigned)C) continue;
        acc += b2f(z[((size_t)(bw*2+c)*R + iy)*C + ix]) * wsm[c*49 + ky*7 + kx];
      }
    }
  G[(size_t)bw*R*C + p] = sigm(acc*gg[0] + bb[0]);
}

// ============ K7: gated softmax + attn@v -> o ============
__global__ __launch_bounds__(256) void k_attn(const bf16* __restrict__ dots, const float* __restrict__ G1,
      const float* __restrict__ G2, const float* __restrict__ G3, const bf16* __restrict__ v,
      float* __restrict__ o){
  const int bw = blockIdx.x, hd = blockIdx.y;
  const int b = bw >> 8, wy = (bw >> 4) & 15, wx = bw & 15;
  __shared__ float attn[64][65];
  __shared__ bf16 vs[64][16];
  __shared__ float invTot[64];
  const int t = threadIdx.x;
  for (int i = t; i < 1024; i += 256) vs[i>>4][i&15] = v[(size_t)(bw*8+hd)*1024 + i];
  const int n = t >> 2, j = t & 3;
  float g2v = G2[(size_t)bw*512 + n*8 + hd];
  const bf16* dp = dots + ((size_t)(bw*8+hd)*64 + n)*64 + j*16;
  const float* g1p = G1 + (size_t)bw*512 + hd*64 + j*16;
  const float* g3p = G3 + (size_t)bw*4096 + n*64 + j*16;
  float e[16]; float mx = -1e30f;
  #pragma unroll
  for (int m = 0; m < 16; ++m){
    float dv = b2f(dp[m]) * ((g1p[m] + g2v + g3p[m]) * (1.f/3.f));
    e[m] = dv; mx = fmaxf(mx, dv);
  }
  mx = fmaxf(mx, __shfl_xor(mx, 1, 4));
  mx = fmaxf(mx, __shfl_xor(mx, 2, 4));
  float s = 0.f;
  #pragma unroll
  for (int m = 0; m < 16; ++m){ float ev = expf(e[m]-mx); e[m] = ev; s += ev; }
  s += __shfl_xor(s, 1, 4);
  s += __shfl_xor(s, 2, 4);
  #pragma unroll
  for (int m = 0; m < 16; ++m) attn[n][j*16+m] = e[m];
  if (j == 0) invTot[n] = 1.f/s;
  __syncthreads();
  const int dg = j;
  float acc[4] = {0.f,0.f,0.f,0.f};
  for (int m = 0; m < 64; ++m){
    float a = attn[n][m];
    #pragma unroll
    for (int dd = 0; dd < 4; ++dd) acc[dd] += a * b2f(vs[m][dg*4+dd]);
  }
  float it = invTot[n];
  int y = wy*8 + (n>>3), x = wx*8 + (n&7);
  #pragma unroll
  for (int dd = 0; dd < 4; ++dd){
    int c = hd*16 + dg*4 + dd;
    o[((size_t)(b*128+c)*128 + y)*128 + x] = acc[dd]*it;
  }
}

// ============ K8: Fh / Fw axial gates ============
__global__ void k_fw(const float* __restrict__ o, float* __restrict__ Fw){
  int t = blockIdx.x*256 + threadIdx.x; if (t >= 4*128*32*128) return;
  int x = t & 127, kk = (t>>7) & 31, bc = t >> 12;
  const float* p = o + ((size_t)bc*128 + kk*4)*128 + x;
  float mx = -1e30f, sm = 0.f;
  #pragma unroll
  for (int r = 0; r < 4; ++r){ float v = p[r*128]; mx = fmaxf(mx,v); sm += v; }
  Fw[t] = sigm(sm*0.25f + mx);
}
__global__ void k_fh(const float* __restrict__ o, float* __restrict__ Fh){
  int t = blockIdx.x*256 + threadIdx.x; if (t >= 4*128*128*32) return;
  int kk = t & 31, y = (t>>5) & 127, bc = t >> 12;
  const float* p = o + ((size_t)bc*128 + y)*128 + kk*4;
  float mx = -1e30f, sm = 0.f;
  #pragma unroll
  for (int r = 0; r < 4; ++r){ float v = p[r]; mx = fmaxf(mx,v); sm += v; }
  Fh[t] = sigm(sm*0.25f + mx);
}

// ============ K9: comb = o * (Fh@Fw) + local ============
__global__ __launch_bounds__(256) void k_comb(const float* __restrict__ o, const float* __restrict__ Fh,
      const float* __restrict__ Fw, const float* __restrict__ local, float* __restrict__ comb){
  const int bc = blockIdx.x;
  __shared__ float fh[128][33];
  __shared__ float fw[32][129];
  const int t = threadIdx.x;
  for (int i = t; i < 4096; i += 256) fh[i>>5][i&31]  = Fh[(size_t)bc*4096 + i];
  for (int i = t; i < 4096; i += 256) fw[i>>7][i&127] = Fw[(size_t)bc*4096 + i];
  __syncthreads();
  for (int i = t; i < 16384; i += 256){
    int y = i >> 7, x = i & 127;
    float g = 0.f;
    #pragma unroll
    for (int kk = 0; kk < 32; ++kk) g += fh[y][kk]*fw[kk][x];
    size_t idx = (size_t)bc*16384 + i;
    comb[idx] = o[idx]*g + local[idx];
  }
}

// ============ K10: reflect-pad + depthwise 8x8 + bn ============
__global__ __launch_bounds__(256) void k_dw(const float* __restrict__ comb, const float* __restrict__ dw,
      const float* __restrict__ gg, const float* __restrict__ bb, float* __restrict__ out){
  const int tx = threadIdx.x, ty = threadIdx.y, t = ty*16+tx;
  const int bz = blockIdx.z; const int c = bz & 127;
  const int oy0 = blockIdx.y*16, ox0 = blockIdx.x*16;
  __shared__ float xs[23][23];
  __shared__ float wsm[64];
  if (t < 64) wsm[t] = dw[c*64 + t];
  for (int i = t; i < 529; i += 256){
    int iy = i/23, ix = i - iy*23;
    int y = oy0 + iy - 3, x = ox0 + ix - 3;
    float v = 0.f;
    if (y >= 0 && y <= 128 && x >= 0 && x <= 128){
      int yy = (y==128)?126:y, xx = (x==128)?126:x;
      v = comb[((size_t)bz*128 + yy)*128 + xx];
    }
    xs[iy][ix] = v;
  }
  __syncthreads();
  float acc = 0.f;
  #pragma unroll
  for (int ky = 0; ky < 8; ++ky)
    #pragma unroll
    for (int kx = 0; kx < 8; ++kx)
      acc += xs[ty+ky][tx+kx]*wsm[ky*8+kx];
  out[((size_t)bz*128 + oy0+ty)*128 + ox0+tx] = acc*gg[c] + bb[c];
}

// ============ K11: 1x1 proj conv 128->128 ============
__global__ __launch_bounds__(256) void k_pw(const float* __restrict__ p1, const float* __restrict__ w,
      float* __restrict__ om){
  const int pt = blockIdx.x, cb = blockIdx.y;
  const int P0 = pt*64; const int b = P0 >> 14; const int rem0 = P0 & 16383;
  __shared__ float xsm[128][65];
  __shared__ float wsm[64][129];
  const int tx = threadIdx.x, ty = threadIdx.y, t = ty*16+tx;
  for (int i = t; i < 128*64; i += 256){
    int ci = i >> 6, p = i & 63;
    xsm[ci][p] = p1[(size_t)(b*128+ci)*16384 + rem0 + p];
  }
  for (int i = t; i < 64*128; i += 256){
    int co = i >> 7, ci = i & 127;
    wsm[co][ci] = w[(cb*64+co)*128 + ci];
  }
  __syncthreads();
  float acc[4][4] = {};
  for (int ci = 0; ci < 128; ++ci){
    float hv[4], wv[4];
    #pragma unroll
    for (int jj = 0; jj < 4; ++jj) hv[jj] = xsm[ci][jj*16+tx];
    #pragma unroll
    for (int ii = 0; ii < 4; ++ii) wv[ii] = wsm[ii*16+ty][ci];
    #pragma unroll
    for (int ii = 0; ii < 4; ++ii)
      #pragma unroll
      for (int jj = 0; jj < 4; ++jj) acc[ii][jj] += wv[ii]*hv[jj];
  }
  #pragma unroll
  for (int ii = 0; ii < 4; ++ii){
    int co = cb*64 + ii*16 + ty;
    #pragma unroll
    for (int jj = 0; jj < 4; ++jj)
      om[(size_t)(b*128+co)*16384 + rem0 + jj*16+tx] = acc[ii][jj];
  }
}

// ============ K12: stride-2 transposed 3x3 conv 128->64 ============
__global__ __launch_bounds__(256) void k_up(const float* __restrict__ om, const float* __restrict__ w,
      float* __restrict__ out){
  const int tx = threadIdx.x, ty = threadIdx.y, t = ty*16+tx;
  const int bz = blockIdx.z; const int b = bz >> 6, co = bz & 63;
  const int y0 = blockIdx.y*16, x0 = blockIdx.x*16;
  __shared__ float wsm[128*9];
  __shared__ float xs[8][17][18];
  for (int i = t; i < 1152; i += 256) wsm[i] = w[co*1152 + i];
  float a00=0.f, a01=0.f, a10=0.f, a11=0.f;
  for (int cc = 0; cc < 16; ++cc){
    __syncthreads();
    for (int i = t; i < 8*289; i += 256){
      int ci = i / 289, r = i % 289, iy = r/17, ix = r - iy*17;
      int y = y0+iy, x = x0+ix;
      float v = 0.f;
      if (y < 128 && x < 128) v = om[((size_t)(b*128 + cc*8+ci)*128 + y)*128 + x];
      xs[ci][iy][ix] = v;
    }
    __syncthreads();
    #pragma unroll
    for (int ci = 0; ci < 8; ++ci){
      const float* wp = &wsm[(cc*8+ci)*9];
      float xa = xs[ci][ty][tx],   xb = xs[ci][ty][tx+1];
      float xc = xs[ci][ty+1][tx], xd = xs[ci][ty+1][tx+1];
      a00 += wp[4]*xa;
      a01 += wp[3]*xa + wp[5]*xb;
      a10 += wp[1]*xa + wp[7]*xc;
      a11 += wp[0]*xa + wp[2]*xb + wp[6]*xc + wp[8]*xd;
    }
  }
  int Y = 2*(y0+ty), X = 2*(x0+tx);
  size_t base = ((size_t)bz*256 + Y)*256 + X;
  out[base]     = a00; out[base+1]   = a01;
  out[base+256] = a10; out[base+257] = a11;
}

extern "C" void kernel_launch(void* const* d_in, const int* in_sizes, int n_in,
                              void* d_out, int out_size, void* d_ws, size_t ws_size,
                              hipStream_t stream) {
  const float* x       = (const float*)d_in[0];
  const float* conv_w  = (const float*)d_in[1];
  const float* bn1_g   = (const float*)d_in[2];
  const float* bn1_b   = (const float*)d_in[3];
  const float* qkv_w   = (const float*)d_in[4];
  const float* loc1_w  = (const float*)d_in[5];
  const float* loc1_g  = (const float*)d_in[6];
  const float* loc1_b  = (const float*)d_in[7];
  const float* loc2_w  = (const float*)d_in[8];
  const float* loc2_g  = (const float*)d_in[9];
  const float* loc2_b  = (const float*)d_in[10];
  const float* rel_t   = (const float*)d_in[11];
  const float* cw_w    = (const float*)d_in[12];
  const float* cw_g    = (const float*)d_in[13];
  const float* cw_b    = (const float*)d_in[14];
  const float* hc_w    = (const float*)d_in[15];
  const float* hc_g    = (const float*)d_in[16];
  const float* hc_b    = (const float*)d_in[17];
  const float* hw_w    = (const float*)d_in[18];
  const float* hw_g    = (const float*)d_in[19];
  const float* hw_b    = (const float*)d_in[20];
  const float* proj_dw = (const float*)d_in[21];
  const float* proj_g  = (const float*)d_in[22];
  const float* proj_b  = (const float*)d_in[23];
  const float* proj_pw = (const float*)d_in[24];
  const float* up_w    = (const float*)d_in[25];

  char* ws = (char*)d_ws;
  float* h      = (float*)(ws + OFF_H);
  float* local  = (float*)(ws + OFF_LOCAL);
  bf16*  q      = (bf16*)(ws + OFF_Q);
  bf16*  k      = (bf16*)(ws + OFF_K);
  bf16*  v      = (bf16*)(ws + OFF_V);
  bf16*  dots   = (bf16*)(ws + OFF_DOTS);
  bf16*  z1     = (bf16*)(ws + OFF_Z1);
  bf16*  z2     = (bf16*)(ws + OFF_Z2);
  bf16*  z3     = (bf16*)(ws + OFF_Z3);
  float* G1     = (float*)(ws + OFF_G1);
  float* G2     = (float*)(ws + OFF_G2);
  float* G3     = (float*)(ws + OFF_G3);
  short* xT     = (short*)(ws + OFF_DOTS);              // transient
  short* hT     = (short*)(ws + OFF_HT);                // transient
  short* w2bf   = (short*)(ws + OFF_Z1);                // transient
  short* wloc   = (short*)(ws + OFF_Z2);                // transient
  float* o_img  = (float*)(ws + OFF_Q);
  float* Fh     = (float*)(ws + OFF_DOTS);
  float* Fw     = (float*)(ws + OFF_DOTS + 8388608);
  float* comb   = (float*)(ws + OFF_H);
  float* proj1  = (float*)(ws + OFF_LOCAL);
  float* om     = (float*)(ws + OFF_Q);
  float* outp   = (float*)d_out;

  dim3 blk2(16,16);
  k_wrep <<<1152, 256, 0, stream>>>(conv_w, w2bf);
  k_xzero<<<1024, 256, 0, stream>>>(xT);
  k_xrep <<<8192, 256, 0, stream>>>(x, xT);
  k_conv1m<<<512, 256, 0, stream>>>(xT, w2bf, bn1_g, bn1_b, h);
  k_lwrep<<<576, 256, 0, stream>>>(loc1_w, loc1_g, loc2_w, loc2_g, wloc);
  k_hzero<<<512, 256, 0, stream>>>(hT);
  k_hrep <<<4096, 256, 0, stream>>>(h, hT);
  k_localm<<<512, 256, 0, stream>>>(hT, wloc, loc1_b, loc2_b, local);
  k_qkv  <<<dim3(NWIN,6), blk2, 0, stream>>>(h, qkv_w, q, k, v);
  k_dots <<<dim3(NWIN,8), 256, 0, stream>>>(q, k, rel_t, dots);
  k_z1   <<<2048, 256, 0, stream>>>(dots, z1);
  k_z2   <<<2048, 256, 0, stream>>>(dots, z2);
  k_z3   <<<16384, 256, 0, stream>>>(dots, z3);
  k_gate <<<dim3(NWIN,2),  256, 0, stream>>>(z1, cw_w, cw_g, cw_b, G1, 8, 64);
  k_gate <<<dim3(NWIN,2),  256, 0, stream>>>(z2, hc_w, hc_g, hc_b, G2, 64, 8);
  k_gate <<<dim3(NWIN,16), 256, 0, stream>>>(z3, hw_w, hw_g, hw_b, G3, 64, 64);
  k_attn <<<dim3(NWIN,8), 256, 0, stream>>>(dots, G1, G2, G3, v, o_img);
  k_fw   <<<8192, 256, 0, stream>>>(o_img, Fw);
  k_fh   <<<8192, 256, 0, stream>>>(o_img, Fh);
  k_comb <<<512, 256, 0, stream>>>(o_img, Fh, Fw, local, comb);
  k_dw   <<<dim3(8,8,BB*128), blk2, 0, stream>>>(comb, proj_dw, proj_g, proj_b, proj1);
  k_pw   <<<dim3(1024,2), blk2, 0, stream>>>(proj1, proj_pw, om);
  k_up   <<<dim3(8,8,BB*64), blk2, 0, stream>>>(om, up_w, outp);
}

// Round 5
// 1006.197 us; speedup vs baseline: 4.9981x; 1.7379x over previous
//
#include <hip/hip_runtime.h>
#include <hip/hip_bf16.h>

typedef __hip_bfloat16 bf16;
typedef __attribute__((ext_vector_type(8))) short short8;
typedef __attribute__((ext_vector_type(4))) float f32x4;

#define DEV __device__ __forceinline__
DEV float b2f(bf16 v){ return __bfloat162float(v); }
DEV bf16 f2b(float v){ return __float2bfloat16(v); }
DEV short f2bs(float v){ union{ bf16 b; short s; } u; u.b = __float2bfloat16(v); return u.s; }
DEV float sigm(float x){ return 1.f/(1.f + expf(-x)); }

// ---- problem constants ----
#define BB 4
#define CIN 256
#define MID 128
#define COUT 64
#define HH 128
#define WW 128
#define WS 8
#define HEADS 8
#define HD 16
#define NTOK 64
#define NWIN 1024

// ---- workspace layout (bytes) ----
static const size_t OFF_H     = 0;                       // fp32 8388608  (33554432 B)
static const size_t OFF_LOCAL = 33554432;                // fp32 8388608
static const size_t OFF_Q     = 67108864;                // bf16 8388608  (16777216 B)
static const size_t OFF_K     = 83886080;                // bf16 8388608
static const size_t OFF_V     = 100663296;               // bf16 8388608
static const size_t OFF_DOTS  = 117440512;               // bf16 33554432 (67108864 B)
static const size_t OFF_Z1    = 184549376;               // bf16 1048576  (2097152 B)
static const size_t OFF_Z2    = 186646528;               // bf16 1048576
static const size_t OFF_Z3    = 188743680;               // bf16 8388608  (16777216 B)
static const size_t OFF_G1    = 205520896;               // fp32 524288   (2097152 B)
static const size_t OFF_G2    = 207618048;               // fp32 524288
static const size_t OFF_G3    = 209715200;               // fp32 4194304  (16777216 B)
// Transients: xT(34MB)->OFF_DOTS (dead before k_dots); hT(17MB)->OFF_DOTS+34MB;
// w2bf(590KB)->OFF_Z1 (dead before z1); wloc(295KB)->OFF_Z2 (dead before z2);
// omT(17MB)->OFF_DOTS (after k_comb; Fh/Fw dead); wup(147KB)->OFF_Z1 (after G1 gate).
static const size_t OFF_HT    = OFF_DOTS + 34078720;

// ============ P1: repack conv_w -> w2[kk][co][ci] bf16 ============
__global__ __launch_bounds__(256) void k_wrep(const float* __restrict__ w, short* __restrict__ w2){
  int i = blockIdx.x*256 + threadIdx.x;
  int ci = i & 255, co = (i >> 8) & 127, kk = i >> 15;
  w2[i] = f2bs(w[(co*256 + ci)*9 + kk]);
}

// ============ P2: zero pad columns of xT ============
__global__ void k_xzero(short* __restrict__ xT){
  int t = blockIdx.x*256 + threadIdx.x;
  int ci = t & 255, side = (t >> 8) & 1, row = t >> 9;
  int cpad = side ? 129 : 0;
  xT[((size_t)row*130 + cpad)*256 + ci] = 0;
}

// ============ P3: x NCHW fp32 -> xT[b][r][c+1][ci] bf16 ============
__global__ __launch_bounds__(256) void k_xrep(const float* __restrict__ x, short* __restrict__ xT){
  const int blk = blockIdx.x;
  const int cgrp = blk & 1, cig = (blk >> 1) & 7, r = (blk >> 4) & 127, b = blk >> 11;
  const int c0 = cgrp*64, ci0 = cig*32;
  __shared__ float lds[32][65];
  const int t = threadIdx.x;
  for (int i = t; i < 2048; i += 256){
    int lci = i >> 6, c = i & 63;
    lds[lci][c] = x[((size_t)(b*256 + ci0 + lci)*128 + r)*128 + c0 + c];
  }
  __syncthreads();
  for (int i = t; i < 2048; i += 256){
    int lci = i & 31, cc = i >> 5;
    xT[((size_t)(b*128 + r)*130 + c0 + cc + 1)*256 + ci0 + lci] = f2bs(lds[lci][cc]);
  }
}

// ============ K1: conv3x3 256->128 + bn + relu  (MFMA implicit GEMM) ============
__global__ __launch_bounds__(256) void k_conv1m(const short* __restrict__ xT, const short* __restrict__ w2,
      const float* __restrict__ gg, const float* __restrict__ bb, float* __restrict__ h){
  const int blk = blockIdx.x;
  const int b = blk >> 7, y = blk & 127;
  const int t = threadIdx.x, lane = t & 63, wave = t >> 6;
  const int quad = lane >> 4, l15 = lane & 15;
  const int m0 = (wave >> 1)*64, n0 = (wave & 1)*64;
  __shared__ short as[130][32];
  __shared__ short bs[384][32];
  f32x4 acc[4][4];
  #pragma unroll
  for (int i = 0; i < 4; ++i)
    #pragma unroll
    for (int j = 0; j < 4; ++j) acc[i][j] = (f32x4){0.f,0.f,0.f,0.f};
  for (int ky = 0; ky < 3; ++ky){
    int r = y + ky - 1;
    if ((unsigned)r >= 128u) continue;
    const short* xrow = xT + (size_t)(b*128 + r)*130*256;
    const short* wk   = w2 + (size_t)ky*384*256;
    for (int ch = 0; ch < 8; ++ch){
      const int ci0 = ch*32;
      __syncthreads();
      for (int i = t; i < 520; i += 256){
        int col = i >> 2, cg = i & 3;
        *(uint4*)&as[col][cg*8] = *(const uint4*)&xrow[col*256 + ci0 + cg*8];
      }
      for (int i = t; i < 1536; i += 256){
        int rr = i >> 2, cg = i & 3;
        *(uint4*)&bs[rr][cg*8] = *(const uint4*)&wk[rr*256 + ci0 + cg*8];
      }
      __syncthreads();
      #pragma unroll
      for (int kx = 0; kx < 3; ++kx){
        short8 af[4], bf[4];
        #pragma unroll
        for (int mt = 0; mt < 4; ++mt)
          af[mt] = *(const short8*)&as[m0 + mt*16 + l15 + kx][quad*8];
        #pragma unroll
        for (int nt = 0; nt < 4; ++nt)
          bf[nt] = *(const short8*)&bs[kx*128 + n0 + nt*16 + l15][quad*8];
        #pragma unroll
        for (int mt = 0; mt < 4; ++mt)
          #pragma unroll
          for (int nt = 0; nt < 4; ++nt)
            acc[mt][nt] = __builtin_amdgcn_mfma_f32_16x16x32_bf16(af[mt], bf[nt], acc[mt][nt], 0, 0, 0);
      }
    }
  }
  #pragma unroll
  for (int nt = 0; nt < 4; ++nt){
    int co = n0 + nt*16 + l15;
    float g = gg[co], bia = bb[co];
    #pragma unroll
    for (int mt = 0; mt < 4; ++mt){
      int xb = m0 + mt*16 + quad*4;
      float4 o4;
      o4.x = fmaxf(acc[mt][nt][0]*g + bia, 0.f);
      o4.y = fmaxf(acc[mt][nt][1]*g + bia, 0.f);
      o4.z = fmaxf(acc[mt][nt][2]*g + bia, 0.f);
      o4.w = fmaxf(acc[mt][nt][3]*g + bia, 0.f);
      *(float4*)&h[((size_t)(b*128 + co)*128 + y)*128 + xb] = o4;
    }
  }
}

// ============ P4: zero pad columns of hT ============
__global__ void k_hzero(short* __restrict__ hT){
  int t = blockIdx.x*256 + threadIdx.x;
  int ci = t & 127, side = (t >> 7) & 1, row = t >> 8;
  int cpad = side ? 129 : 0;
  hT[((size_t)row*130 + cpad)*128 + ci] = 0;
}

// ============ P5: h NCHW fp32 -> hT[b][r][c+1][ci] bf16 ============
__global__ __launch_bounds__(256) void k_hrep(const float* __restrict__ h, short* __restrict__ hT){
  const int blk = blockIdx.x;
  const int cgrp = blk & 1, cig = (blk >> 1) & 3, r = (blk >> 3) & 127, b = blk >> 10;
  const int c0 = cgrp*64, ci0 = cig*32;
  __shared__ float lds[32][65];
  const int t = threadIdx.x;
  for (int i = t; i < 2048; i += 256){
    int lci = i >> 6, c = i & 63;
    lds[lci][c] = h[((size_t)(b*128 + ci0 + lci)*128 + r)*128 + c0 + c];
  }
  __syncthreads();
  for (int i = t; i < 2048; i += 256){
    int lci = i & 31, cc = i >> 5;
    hT[((size_t)(b*128 + r)*130 + c0 + cc + 1)*128 + ci0 + lci] = f2bs(lds[lci][cc]);
  }
}

// ============ P6: fold local weights: wloc[ky][kx*128+co][ci] bf16 ============
__global__ __launch_bounds__(256) void k_lwrep(const float* __restrict__ w1, const float* __restrict__ g1,
      const float* __restrict__ w2, const float* __restrict__ g2, short* __restrict__ wloc){
  int i = blockIdx.x*256 + threadIdx.x;
  int ci = i & 127, row = (i >> 7) % 384, ky = i / 49152;
  int kx = row >> 7, co = row & 127;
  float v = w1[(co*128 + ci)*9 + ky*3 + kx] * g1[co];
  if (ky == 1 && kx == 1) v += w2[co*128 + ci] * g2[co];
  wloc[i] = f2bs(v);
}

// ============ K2: local conv (folded 3x3+1x1)  (MFMA implicit GEMM) ============
__global__ __launch_bounds__(256) void k_localm(const short* __restrict__ hT, const short* __restrict__ wloc,
      const float* __restrict__ b1, const float* __restrict__ b2, float* __restrict__ out){
  const int blk = blockIdx.x;
  const int b = blk >> 7, y = blk & 127;
  const int t = threadIdx.x, lane = t & 63, wave = t >> 6;
  const int quad = lane >> 4, l15 = lane & 15;
  const int m0 = (wave >> 1)*64, n0 = (wave & 1)*64;
  __shared__ short as[130][32];
  __shared__ short bs[384][32];
  f32x4 acc[4][4];
  #pragma unroll
  for (int i = 0; i < 4; ++i)
    #pragma unroll
    for (int j = 0; j < 4; ++j) acc[i][j] = (f32x4){0.f,0.f,0.f,0.f};
  for (int ky = 0; ky < 3; ++ky){
    int r = y + ky - 1;
    if ((unsigned)r >= 128u) continue;
    const short* xrow = hT + (size_t)(b*128 + r)*130*128;
    const short* wk   = wloc + (size_t)ky*384*128;
    for (int ch = 0; ch < 4; ++ch){
      const int ci0 = ch*32;
      __syncthreads();
      for (int i = t; i < 520; i += 256){
        int col = i >> 2, cg = i & 3;
        *(uint4*)&as[col][cg*8] = *(const uint4*)&xrow[col*128 + ci0 + cg*8];
      }
      for (int i = t; i < 1536; i += 256){
        int rr = i >> 2, cg = i & 3;
        *(uint4*)&bs[rr][cg*8] = *(const uint4*)&wk[rr*128 + ci0 + cg*8];
      }
      __syncthreads();
      #pragma unroll
      for (int kx = 0; kx < 3; ++kx){
        short8 af[4], bf[4];
        #pragma unroll
        for (int mt = 0; mt < 4; ++mt)
          af[mt] = *(const short8*)&as[m0 + mt*16 + l15 + kx][quad*8];
        #pragma unroll
        for (int nt = 0; nt < 4; ++nt)
          bf[nt] = *(const short8*)&bs[kx*128 + n0 + nt*16 + l15][quad*8];
        #pragma unroll
        for (int mt = 0; mt < 4; ++mt)
          #pragma unroll
          for (int nt = 0; nt < 4; ++nt)
            acc[mt][nt] = __builtin_amdgcn_mfma_f32_16x16x32_bf16(af[mt], bf[nt], acc[mt][nt], 0, 0, 0);
      }
    }
  }
  #pragma unroll
  for (int nt = 0; nt < 4; ++nt){
    int co = n0 + nt*16 + l15;
    float bia = b1[co] + b2[co];
    #pragma unroll
    for (int mt = 0; mt < 4; ++mt){
      int xb = m0 + mt*16 + quad*4;
      float4 o4;
      o4.x = acc[mt][nt][0] + bia;
      o4.y = acc[mt][nt][1] + bia;
      o4.z = acc[mt][nt][2] + bia;
      o4.w = acc[mt][nt][3] + bia;
      *(float4*)&out[((size_t)(b*128 + co)*128 + y)*128 + xb] = o4;
    }
  }
}

// ============ K3: 1x1 qkv conv -> windowed q,k,v (bf16) ============
__global__ __launch_bounds__(256) void k_qkv(const float* __restrict__ h, const float* __restrict__ w,
     bf16* __restrict__ q, bf16* __restrict__ k, bf16* __restrict__ v){
  const int bw = blockIdx.x, ocb = blockIdx.y;
  const int b = bw >> 8, wy = (bw >> 4) & 15, wx = bw & 15;
  __shared__ float hs[128][64];
  __shared__ float wsm[64][129];
  const int tx = threadIdx.x, ty = threadIdx.y, t = ty*16+tx;
  for (int i = t; i < 128*64; i += 256){
    int ci = i >> 6, n = i & 63; int yy = wy*8 + (n>>3), xx = wx*8 + (n&7);
    hs[ci][n] = h[((size_t)(b*128+ci)*128 + yy)*128 + xx];
  }
  for (int i = t; i < 64*128; i += 256){
    int oc = i >> 7, ci = i & 127;
    wsm[oc][ci] = w[(ocb*64+oc)*128 + ci];
  }
  __syncthreads();
  float acc[4][4] = {};
  for (int ci = 0; ci < 128; ++ci){
    float hv[4], wv[4];
    #pragma unroll
    for (int jj = 0; jj < 4; ++jj) hv[jj] = hs[ci][jj*16+tx];
    #pragma unroll
    for (int ii = 0; ii < 4; ++ii) wv[ii] = wsm[ii*16+ty][ci];
    #pragma unroll
    for (int ii = 0; ii < 4; ++ii)
      #pragma unroll
      for (int jj = 0; jj < 4; ++jj) acc[ii][jj] += wv[ii]*hv[jj];
  }
  #pragma unroll
  for (int ii = 0; ii < 4; ++ii){
    int oc = ocb*64 + ii*16 + ty;
    int s = oc >> 7, rem = oc & 127, head = rem >> 4, d = rem & 15;
    bf16* dst = (s==0) ? q : (s==1) ? k : v;
    #pragma unroll
    for (int jj = 0; jj < 4; ++jj){
      int n = jj*16 + tx;
      dst[((size_t)(bw*8+head)*64 + n)*16 + d] = f2b(acc[ii][jj]);
    }
  }
}

// ============ K4: dots = q.k^T * 0.25 + relpos bias ============
__global__ __launch_bounds__(256) void k_dots(const bf16* __restrict__ q, const bf16* __restrict__ kk,
      const float* __restrict__ rel, bf16* __restrict__ dots){
  const int bw = blockIdx.x, hd = blockIdx.y;
  __shared__ bf16 qs[64][16], ks[64][16];
  const int t = threadIdx.x;
  const size_t base = (size_t)(bw*8+hd)*1024;
  for (int i = t; i < 1024; i += 256){ qs[i>>4][i&15] = q[base + i]; ks[i>>4][i&15] = kk[base + i]; }
  __syncthreads();
  const int n = t >> 2, jm = t & 3;
  float qr[16];
  #pragma unroll
  for (int d = 0; d < 16; ++d) qr[d] = b2f(qs[n][d]);
  const int ny = n >> 3, nx = n & 7;
  for (int mm = 0; mm < 16; ++mm){
    int m = jm*16 + mm;
    float a = 0.f;
    #pragma unroll
    for (int d = 0; d < 16; ++d) a += qr[d]*b2f(ks[m][d]);
    int my = m >> 3, mx = m & 7;
    int ridx = (ny - my + 7)*15 + (nx - mx + 7);
    float bias = rel[ridx*8 + hd];
    dots[base*4 + (size_t)n*64 + m] = f2b(a*0.25f + bias);
  }
}

// ============ K5: axis reductions ============
__global__ void k_z1(const bf16* __restrict__ dots, bf16* __restrict__ z){
  int t = blockIdx.x*256 + threadIdx.x;
  int bw = t >> 9, r = t & 511; int hd = r >> 6, m = r & 63;
  const bf16* p = dots + (size_t)(bw*8+hd)*4096 + m;
  float mx = -1e30f, sm = 0.f;
  for (int n = 0; n < 64; ++n){ float v = b2f(p[n*64]); mx = fmaxf(mx,v); sm += v; }
  z[(size_t)bw*1024 + hd*64 + m]       = f2b(mx);
  z[(size_t)bw*1024 + 512 + hd*64 + m] = f2b(sm*(1.f/64.f));
}
__global__ void k_z2(const bf16* __restrict__ dots, bf16* __restrict__ z){
  int t = blockIdx.x*256 + threadIdx.x;
  int bw = t >> 9, r = t & 511; int n = r >> 3, hd = r & 7;
  const bf16* p = dots + ((size_t)(bw*8+hd)*64 + n)*64;
  float mx = -1e30f, sm = 0.f;
  for (int m = 0; m < 64; ++m){ float v = b2f(p[m]); mx = fmaxf(mx,v); sm += v; }
  z[(size_t)bw*1024 + n*8 + hd]       = f2b(mx);
  z[(size_t)bw*1024 + 512 + n*8 + hd] = f2b(sm*(1.f/64.f));
}
__global__ void k_z3(const bf16* __restrict__ dots, bf16* __restrict__ z){
  int t = blockIdx.x*256 + threadIdx.x;
  int bw = t >> 12, r = t & 4095;
  const bf16* p = dots + (size_t)bw*32768 + r;
  float mx = -1e30f, sm = 0.f;
  for (int hd = 0; hd < 8; ++hd){ float v = b2f(p[hd*4096]); mx = fmaxf(mx,v); sm += v; }
  z[(size_t)bw*8192 + r]        = f2b(mx);
  z[(size_t)bw*8192 + 4096 + r] = f2b(sm*0.125f);
}

// ============ K6: 7x7 2->1 conv + bn + sigmoid ============
__global__ __launch_bounds__(256) void k_gate(const bf16* __restrict__ z, const float* __restrict__ w,
      const float* __restrict__ gg, const float* __restrict__ bb, float* __restrict__ G, int R, int C){
  __shared__ float wsm[98];
  const int t = threadIdx.x;
  if (t < 98) wsm[t] = w[t];
  __syncthreads();
  const int bw = blockIdx.x;
  int p = blockIdx.y*256 + t; if (p >= R*C) return;
  int y = p / C, x = p - y*C;
  float acc = 0.f;
  for (int c = 0; c < 2; ++c)
    for (int ky = 0; ky < 7; ++ky){
      int iy = y + ky - 3; if ((unsigned)iy >= (unsigned)R) continue;
      for (int kx = 0; kx < 7; ++kx){
        int ix = x + kx - 3; if ((unsigned)ix >= (unsigned)C) continue;
        acc += b2f(z[((size_t)(bw*2+c)*R + iy)*C + ix]) * wsm[c*49 + ky*7 + kx];
      }
    }
  G[(size_t)bw*R*C + p] = sigm(acc*gg[0] + bb[0]);
}

// ============ K7: gated softmax + attn@v -> o ============
__global__ __launch_bounds__(256) void k_attn(const bf16* __restrict__ dots, const float* __restrict__ G1,
      const float* __restrict__ G2, const float* __restrict__ G3, const bf16* __restrict__ v,
      float* __restrict__ o){
  const int bw = blockIdx.x, hd = blockIdx.y;
  const int b = bw >> 8, wy = (bw >> 4) & 15, wx = bw & 15;
  __shared__ float attn[64][65];
  __shared__ bf16 vs[64][16];
  __shared__ float invTot[64];
  const int t = threadIdx.x;
  for (int i = t; i < 1024; i += 256) vs[i>>4][i&15] = v[(size_t)(bw*8+hd)*1024 + i];
  const int n = t >> 2, j = t & 3;
  float g2v = G2[(size_t)bw*512 + n*8 + hd];
  const bf16* dp = dots + ((size_t)(bw*8+hd)*64 + n)*64 + j*16;
  const float* g1p = G1 + (size_t)bw*512 + hd*64 + j*16;
  const float* g3p = G3 + (size_t)bw*4096 + n*64 + j*16;
  float e[16]; float mx = -1e30f;
  #pragma unroll
  for (int m = 0; m < 16; ++m){
    float dv = b2f(dp[m]) * ((g1p[m] + g2v + g3p[m]) * (1.f/3.f));
    e[m] = dv; mx = fmaxf(mx, dv);
  }
  mx = fmaxf(mx, __shfl_xor(mx, 1, 4));
  mx = fmaxf(mx, __shfl_xor(mx, 2, 4));
  float s = 0.f;
  #pragma unroll
  for (int m = 0; m < 16; ++m){ float ev = expf(e[m]-mx); e[m] = ev; s += ev; }
  s += __shfl_xor(s, 1, 4);
  s += __shfl_xor(s, 2, 4);
  #pragma unroll
  for (int m = 0; m < 16; ++m) attn[n][j*16+m] = e[m];
  if (j == 0) invTot[n] = 1.f/s;
  __syncthreads();
  const int dg = j;
  float acc[4] = {0.f,0.f,0.f,0.f};
  for (int m = 0; m < 64; ++m){
    float a = attn[n][m];
    #pragma unroll
    for (int dd = 0; dd < 4; ++dd) acc[dd] += a * b2f(vs[m][dg*4+dd]);
  }
  float it = invTot[n];
  int y = wy*8 + (n>>3), x = wx*8 + (n&7);
  #pragma unroll
  for (int dd = 0; dd < 4; ++dd){
    int c = hd*16 + dg*4 + dd;
    o[((size_t)(b*128+c)*128 + y)*128 + x] = acc[dd]*it;
  }
}

// ============ K8: Fh / Fw axial gates ============
__global__ void k_fw(const float* __restrict__ o, float* __restrict__ Fw){
  int t = blockIdx.x*256 + threadIdx.x; if (t >= 4*128*32*128) return;
  int x = t & 127, kk = (t>>7) & 31, bc = t >> 12;
  const float* p = o + ((size_t)bc*128 + kk*4)*128 + x;
  float mx = -1e30f, sm = 0.f;
  #pragma unroll
  for (int r = 0; r < 4; ++r){ float v = p[r*128]; mx = fmaxf(mx,v); sm += v; }
  Fw[t] = sigm(sm*0.25f + mx);
}
__global__ void k_fh(const float* __restrict__ o, float* __restrict__ Fh){
  int t = blockIdx.x*256 + threadIdx.x; if (t >= 4*128*128*32) return;
  int kk = t & 31, y = (t>>5) & 127, bc = t >> 12;
  const float* p = o + ((size_t)bc*128 + y)*128 + kk*4;
  float mx = -1e30f, sm = 0.f;
  #pragma unroll
  for (int r = 0; r < 4; ++r){ float v = p[r]; mx = fmaxf(mx,v); sm += v; }
  Fh[t] = sigm(sm*0.25f + mx);
}

// ============ K9: comb = o * (Fh@Fw) + local ============
__global__ __launch_bounds__(256) void k_comb(const float* __restrict__ o, const float* __restrict__ Fh,
      const float* __restrict__ Fw, const float* __restrict__ local, float* __restrict__ comb){
  const int bc = blockIdx.x;
  __shared__ float fh[128][33];
  __shared__ float fw[32][129];
  const int t = threadIdx.x;
  for (int i = t; i < 4096; i += 256) fh[i>>5][i&31]  = Fh[(size_t)bc*4096 + i];
  for (int i = t; i < 4096; i += 256) fw[i>>7][i&127] = Fw[(size_t)bc*4096 + i];
  __syncthreads();
  for (int i = t; i < 16384; i += 256){
    int y = i >> 7, x = i & 127;
    float g = 0.f;
    #pragma unroll
    for (int kk = 0; kk < 32; ++kk) g += fh[y][kk]*fw[kk][x];
    size_t idx = (size_t)bc*16384 + i;
    comb[idx] = o[idx]*g + local[idx];
  }
}

// ============ K10: reflect-pad + depthwise 8x8 + bn ============
__global__ __launch_bounds__(256) void k_dw(const float* __restrict__ comb, const float* __restrict__ dw,
      const float* __restrict__ gg, const float* __restrict__ bb, float* __restrict__ out){
  const int tx = threadIdx.x, ty = threadIdx.y, t = ty*16+tx;
  const int bz = blockIdx.z; const int c = bz & 127;
  const int oy0 = blockIdx.y*16, ox0 = blockIdx.x*16;
  __shared__ float xs[23][23];
  __shared__ float wsm[64];
  if (t < 64) wsm[t] = dw[c*64 + t];
  for (int i = t; i < 529; i += 256){
    int iy = i/23, ix = i - iy*23;
    int y = oy0 + iy - 3, x = ox0 + ix - 3;
    float v = 0.f;
    if (y >= 0 && y <= 128 && x >= 0 && x <= 128){
      int yy = (y==128)?126:y, xx = (x==128)?126:x;
      v = comb[((size_t)bz*128 + yy)*128 + xx];
    }
    xs[iy][ix] = v;
  }
  __syncthreads();
  float acc = 0.f;
  #pragma unroll
  for (int ky = 0; ky < 8; ++ky)
    #pragma unroll
    for (int kx = 0; kx < 8; ++kx)
      acc += xs[ty+ky][tx+kx]*wsm[ky*8+kx];
  out[((size_t)bz*128 + oy0+ty)*128 + ox0+tx] = acc*gg[c] + bb[c];
}

// ============ P7: zero omT halo cols ============
__global__ void k_omzero(short* __restrict__ omT){
  int t = blockIdx.x*256 + threadIdx.x;      // 131072 total
  int ci = t & 127, side = (t >> 7) & 1, row = t >> 8;
  int cpad = side ? 129 : 0;
  omT[((size_t)row*130 + cpad)*128 + ci] = 0;
}

// ============ P8: repack up_w -> wup[tap][co][ci] bf16 ============
__global__ __launch_bounds__(256) void k_uwrep(const float* __restrict__ w, short* __restrict__ wup){
  int i = blockIdx.x*256 + threadIdx.x;      // 73728 total
  int ci = i & 127, co = (i >> 7) & 63, tap = i >> 13;
  wup[i] = f2bs(w[(co*128 + ci)*9 + tap]);
}

// ============ K11: 1x1 proj conv 128->128 -> omT bf16 NHWC+halo ============
__global__ __launch_bounds__(256) void k_pw(const float* __restrict__ p1, const float* __restrict__ w,
      short* __restrict__ omT){
  const int pt = blockIdx.x, cb = blockIdx.y;
  const int P0 = pt*64; const int b = P0 >> 14; const int rem0 = P0 & 16383;
  const int y = rem0 >> 7, x0 = rem0 & 127;
  __shared__ float xsm[128][65];
  __shared__ float wsm[64][129];
  const int tx = threadIdx.x, ty = threadIdx.y, t = ty*16+tx;
  for (int i = t; i < 128*64; i += 256){
    int ci = i >> 6, p = i & 63;
    xsm[ci][p] = p1[(size_t)(b*128+ci)*16384 + rem0 + p];
  }
  for (int i = t; i < 64*128; i += 256){
    int co = i >> 7, ci = i & 127;
    wsm[co][ci] = w[(cb*64+co)*128 + ci];
  }
  __syncthreads();
  float acc[4][4] = {};
  for (int ci = 0; ci < 128; ++ci){
    float hv[4], wv[4];
    #pragma unroll
    for (int jj = 0; jj < 4; ++jj) hv[jj] = xsm[ci][jj*16+tx];
    #pragma unroll
    for (int ii = 0; ii < 4; ++ii) wv[ii] = wsm[ii*16+ty][ci];
    #pragma unroll
    for (int ii = 0; ii < 4; ++ii)
      #pragma unroll
      for (int jj = 0; jj < 4; ++jj) acc[ii][jj] += wv[ii]*hv[jj];
  }
  // transpose through LDS -> coalesced bf16 NHWC store
  __syncthreads();
  float* pt_t = &xsm[0][0];              // reuse: [64 px][65]
  #pragma unroll
  for (int ii = 0; ii < 4; ++ii)
    #pragma unroll
    for (int jj = 0; jj < 4; ++jj)
      pt_t[(jj*16+tx)*65 + ii*16+ty] = acc[ii][jj];
  __syncthreads();
  for (int i = t; i < 4096; i += 256){
    int px = i >> 6, co_l = i & 63;
    omT[((size_t)(b*128 + y)*130 + x0 + px + 1)*128 + cb*64 + co_l] = f2bs(pt_t[px*65 + co_l]);
  }
}

// ============ K12: transposed 3x3 stride-2 conv 128->64 (MFMA, parity decomp) ============
// taps k=ky*3+kx: parity/row/shift tables (from verified scalar decomposition)
__global__ __launch_bounds__(256) void k_upm(const short* __restrict__ omT, const short* __restrict__ wup,
      float* __restrict__ out){
  const int blk = blockIdx.x;                 // 512 = (b, y)
  const int b = blk >> 7, y = blk & 127;
  const int t = threadIdx.x, lane = t & 63, wave = t >> 6;
  const int quad = lane >> 4, l15 = lane & 15;
  const int m0w = wave*32;                    // 32 x-positions per wave
  __shared__ __align__(16) char smem[53504];
  short* asp = (short*)smem;                  // [2][130][32]
  short* bsp = (short*)(smem + 16640);        // [576][32]
  float* ptile = (float*)smem;                // [64][132] (reused after compute)
  const int PAR[9] = {3,2,3, 1,0,1, 3,2,3};
  const int ROW[9] = {0,0,0, 0,0,0, 1,1,1};
  const int SHF[9] = {0,0,1, 0,0,1, 0,0,1};
  f32x4 acc[4][2][4];
  #pragma unroll
  for (int p = 0; p < 4; ++p)
    #pragma unroll
    for (int mt = 0; mt < 2; ++mt)
      #pragma unroll
      for (int nt = 0; nt < 4; ++nt) acc[p][mt][nt] = (f32x4){0.f,0.f,0.f,0.f};
  for (int ch = 0; ch < 4; ++ch){
    const int ci0 = ch*32;
    __syncthreads();
    for (int i = t; i < 1040; i += 256){       // A: 2 rows x 130 cols x 4 cg
      int rw = (i >= 520), j = i - rw*520;
      int col = j >> 2, cg = j & 3;
      uint4 val = {0,0,0,0};
      if (y + rw < 128)
        val = *(const uint4*)&omT[((size_t)(b*128 + y + rw)*130 + col)*128 + ci0 + cg*8];
      *(uint4*)&asp[((rw*130 + col)*32) + cg*8] = val;
    }
    for (int i = t; i < 2304; i += 256){       // B: 576 rows x 4 cg
      int rr = i >> 2, cg = i & 3;
      *(uint4*)&bsp[rr*32 + cg*8] = *(const uint4*)&wup[rr*128 + ci0 + cg*8];
    }
    __syncthreads();
    #pragma unroll
    for (int k = 0; k < 9; ++k){
      const int pr = PAR[k], rw = ROW[k], sh = SHF[k];
      if (rw && y == 127) continue;            // block-uniform
      short8 af[2], bf[4];
      #pragma unroll
      for (int mt = 0; mt < 2; ++mt)
        af[mt] = *(const short8*)&asp[((rw*130 + m0w + mt*16 + l15 + 1 + sh))*32 + quad*8];
      #pragma unroll
      for (int nt = 0; nt < 4; ++nt)
        bf[nt] = *(const short8*)&bsp[(k*64 + nt*16 + l15)*32 + quad*8];
      #pragma unroll
      for (int mt = 0; mt < 2; ++mt)
        #pragma unroll
        for (int nt = 0; nt < 4; ++nt)
          acc[pr][mt][nt] = __builtin_amdgcn_mfma_f32_16x16x32_bf16(af[mt], bf[nt], acc[pr][mt][nt], 0, 0, 0);
    }
  }
  // epilogue: per parity, transpose through LDS, coalesced-ish store
  #pragma unroll
  for (int p = 0; p < 4; ++p){
    __syncthreads();
    #pragma unroll
    for (int mt = 0; mt < 2; ++mt)
      #pragma unroll
      for (int nt = 0; nt < 4; ++nt){
        int co = nt*16 + l15;
        int xb = m0w + mt*16 + quad*4;
        #pragma unroll
        for (int r = 0; r < 4; ++r)
          ptile[co*132 + xb + r] = acc[p][mt][nt][r];
      }
    __syncthreads();
    int py = p >> 1, px = p & 1;
    int Y = 2*y + py;
    for (int i = t; i < 8192; i += 256){
      int co = i >> 7, xx = i & 127;
      out[((size_t)(b*64 + co)*256 + Y)*256 + 2*xx + px] = ptile[co*132 + xx];
    }
  }
}

extern "C" void kernel_launch(void* const* d_in, const int* in_sizes, int n_in,
                              void* d_out, int out_size, void* d_ws, size_t ws_size,
                              hipStream_t stream) {
  const float* x       = (const float*)d_in[0];
  const float* conv_w  = (const float*)d_in[1];
  const float* bn1_g   = (const float*)d_in[2];
  const float* bn1_b   = (const float*)d_in[3];
  const float* qkv_w   = (const float*)d_in[4];
  const float* loc1_w  = (const float*)d_in[5];
  const float* loc1_g  = (const float*)d_in[6];
  const float* loc1_b  = (const float*)d_in[7];
  const float* loc2_w  = (const float*)d_in[8];
  const float* loc2_g  = (const float*)d_in[9];
  const float* loc2_b  = (const float*)d_in[10];
  const float* rel_t   = (const float*)d_in[11];
  const float* cw_w    = (const float*)d_in[12];
  const float* cw_g    = (const float*)d_in[13];
  const float* cw_b    = (const float*)d_in[14];
  const float* hc_w    = (const float*)d_in[15];
  const float* hc_g    = (const float*)d_in[16];
  const float* hc_b    = (const float*)d_in[17];
  const float* hw_w    = (const float*)d_in[18];
  const float* hw_g    = (const float*)d_in[19];
  const float* hw_b    = (const float*)d_in[20];
  const float* proj_dw = (const float*)d_in[21];
  const float* proj_g  = (const float*)d_in[22];
  const float* proj_b  = (const float*)d_in[23];
  const float* proj_pw = (const float*)d_in[24];
  const float* up_w    = (const float*)d_in[25];

  char* ws = (char*)d_ws;
  float* h      = (float*)(ws + OFF_H);
  float* local  = (float*)(ws + OFF_LOCAL);
  bf16*  q      = (bf16*)(ws + OFF_Q);
  bf16*  k      = (bf16*)(ws + OFF_K);
  bf16*  v      = (bf16*)(ws + OFF_V);
  bf16*  dots   = (bf16*)(ws + OFF_DOTS);
  bf16*  z1     = (bf16*)(ws + OFF_Z1);
  bf16*  z2     = (bf16*)(ws + OFF_Z2);
  bf16*  z3     = (bf16*)(ws + OFF_Z3);
  float* G1     = (float*)(ws + OFF_G1);
  float* G2     = (float*)(ws + OFF_G2);
  float* G3     = (float*)(ws + OFF_G3);
  short* xT     = (short*)(ws + OFF_DOTS);              // transient
  short* hT     = (short*)(ws + OFF_HT);                // transient
  short* w2bf   = (short*)(ws + OFF_Z1);                // transient
  short* wloc   = (short*)(ws + OFF_Z2);                // transient
  short* omT    = (short*)(ws + OFF_DOTS);              // transient (after k_comb)
  short* wup    = (short*)(ws + OFF_Z1);                // transient (after G1 gate)
  float* o_img  = (float*)(ws + OFF_Q);
  float* Fh     = (float*)(ws + OFF_DOTS);
  float* Fw     = (float*)(ws + OFF_DOTS + 8388608);
  float* comb   = (float*)(ws + OFF_H);
  float* proj1  = (float*)(ws + OFF_LOCAL);
  float* outp   = (float*)d_out;

  dim3 blk2(16,16);
  k_wrep <<<1152, 256, 0, stream>>>(conv_w, w2bf);
  k_xzero<<<1024, 256, 0, stream>>>(xT);
  k_xrep <<<8192, 256, 0, stream>>>(x, xT);
  k_conv1m<<<512, 256, 0, stream>>>(xT, w2bf, bn1_g, bn1_b, h);
  k_lwrep<<<576, 256, 0, stream>>>(loc1_w, loc1_g, loc2_w, loc2_g, wloc);
  k_hzero<<<512, 256, 0, stream>>>(hT);
  k_hrep <<<4096, 256, 0, stream>>>(h, hT);
  k_localm<<<512, 256, 0, stream>>>(hT, wloc, loc1_b, loc2_b, local);
  k_qkv  <<<dim3(NWIN,6), blk2, 0, stream>>>(h, qkv_w, q, k, v);
  k_dots <<<dim3(NWIN,8), 256, 0, stream>>>(q, k, rel_t, dots);
  k_z1   <<<2048, 256, 0, stream>>>(dots, z1);
  k_z2   <<<2048, 256, 0, stream>>>(dots, z2);
  k_z3   <<<16384, 256, 0, stream>>>(dots, z3);
  k_gate <<<dim3(NWIN,2),  256, 0, stream>>>(z1, cw_w, cw_g, cw_b, G1, 8, 64);
  k_gate <<<dim3(NWIN,2),  256, 0, stream>>>(z2, hc_w, hc_g, hc_b, G2, 64, 8);
  k_gate <<<dim3(NWIN,16), 256, 0, stream>>>(z3, hw_w, hw_g, hw_b, G3, 64, 64);
  k_attn <<<dim3(NWIN,8), 256, 0, stream>>>(dots, G1, G2, G3, v, o_img);
  k_fw   <<<8192, 256, 0, stream>>>(o_img, Fw);
  k_fh   <<<8192, 256, 0, stream>>>(o_img, Fh);
  k_comb <<<512, 256, 0, stream>>>(o_img, Fh, Fw, local, comb);
  k_dw   <<<dim3(8,8,BB*128), blk2, 0, stream>>>(comb, proj_dw, proj_g, proj_b, proj1);
  k_omzero<<<512, 256, 0, stream>>>(omT);
  k_uwrep<<<288, 256, 0, stream>>>(up_w, wup);
  k_pw   <<<dim3(1024,2), blk2, 0, stream>>>(proj1, proj_pw, omT);
  k_upm  <<<512, 256, 0, stream>>>(omT, wup, outp);
}

// Round 6
// 826.596 us; speedup vs baseline: 6.0841x; 1.2173x over previous
//
#include <hip/hip_runtime.h>
#include <hip/hip_bf16.h>

typedef __hip_bfloat16 bf16;
typedef __attribute__((ext_vector_type(8))) short short8;
typedef __attribute__((ext_vector_type(4))) float f32x4;

#define DEV __device__ __forceinline__
DEV float b2f(bf16 v){ return __bfloat162float(v); }
DEV bf16 f2b(float v){ return __float2bfloat16(v); }
DEV short f2bs(float v){ union{ bf16 b; short s; } u; u.b = __float2bfloat16(v); return u.s; }
DEV float sigm(float x){ return 1.f/(1.f + expf(-x)); }

// ---- problem constants ----
#define BB 4
#define CIN 256
#define MID 128
#define COUT 64
#define HH 128
#define WW 128
#define WS 8
#define HEADS 8
#define HD 16
#define NTOK 64
#define NWIN 1024

// ---- workspace layout (bytes) ----
static const size_t OFF_H     = 0;                       // fp32 8388608  (33554432 B)
static const size_t OFF_LOCAL = 33554432;                // fp32 8388608
static const size_t OFF_Q     = 67108864;                // bf16 8388608  (16777216 B)
static const size_t OFF_K     = 83886080;                // bf16 8388608
static const size_t OFF_V     = 100663296;               // bf16 8388608
static const size_t OFF_DOTS  = 117440512;               // bf16 33554432 (67108864 B)
static const size_t OFF_Z1    = 184549376;               // bf16 1048576  (2097152 B)
static const size_t OFF_Z2    = 186646528;               // bf16 1048576
static const size_t OFF_Z3    = 188743680;               // bf16 8388608  (16777216 B)
static const size_t OFF_G1    = 205520896;               // fp32 524288   (2097152 B)
static const size_t OFF_G2    = 207618048;               // fp32 524288
static const size_t OFF_G3    = 209715200;               // fp32 4194304  (16777216 B)
// Transients: xT(34MB)->OFF_DOTS (dead before k_dots); hT(17MB)->OFF_DOTS+34MB
// (dead before k_dots; qkvm reads it pre-dots); w2bf->OFF_Z1; wloc->OFF_Z2;
// wqkv(98KB)->OFF_Z3 (dead before k_z3); omT(17MB)->OFF_DOTS (after k_comb);
// wup(147KB)->OFF_Z1 (after G1 gate).
static const size_t OFF_HT    = OFF_DOTS + 34078720;

// ============ P1: repack conv_w -> w2[kk][co][ci] bf16 ============
__global__ __launch_bounds__(256) void k_wrep(const float* __restrict__ w, short* __restrict__ w2){
  int i = blockIdx.x*256 + threadIdx.x;
  int ci = i & 255, co = (i >> 8) & 127, kk = i >> 15;
  w2[i] = f2bs(w[(co*256 + ci)*9 + kk]);
}

// ============ P2: zero pad columns of xT ============
__global__ void k_xzero(short* __restrict__ xT){
  int t = blockIdx.x*256 + threadIdx.x;
  int ci = t & 255, side = (t >> 8) & 1, row = t >> 9;
  int cpad = side ? 129 : 0;
  xT[((size_t)row*130 + cpad)*256 + ci] = 0;
}

// ============ P3: x NCHW fp32 -> xT[b][r][c+1][ci] bf16 ============
__global__ __launch_bounds__(256) void k_xrep(const float* __restrict__ x, short* __restrict__ xT){
  const int blk = blockIdx.x;
  const int cgrp = blk & 1, cig = (blk >> 1) & 7, r = (blk >> 4) & 127, b = blk >> 11;
  const int c0 = cgrp*64, ci0 = cig*32;
  __shared__ float lds[32][65];
  const int t = threadIdx.x;
  for (int i = t; i < 2048; i += 256){
    int lci = i >> 6, c = i & 63;
    lds[lci][c] = x[((size_t)(b*256 + ci0 + lci)*128 + r)*128 + c0 + c];
  }
  __syncthreads();
  for (int i = t; i < 2048; i += 256){
    int lci = i & 31, cc = i >> 5;
    xT[((size_t)(b*128 + r)*130 + c0 + cc + 1)*256 + ci0 + lci] = f2bs(lds[lci][cc]);
  }
}

// ============ K1: conv3x3 256->128 + bn + relu  (MFMA implicit GEMM) ============
__global__ __launch_bounds__(256) void k_conv1m(const short* __restrict__ xT, const short* __restrict__ w2,
      const float* __restrict__ gg, const float* __restrict__ bb, float* __restrict__ h){
  const int blk = blockIdx.x;
  const int b = blk >> 7, y = blk & 127;
  const int t = threadIdx.x, lane = t & 63, wave = t >> 6;
  const int quad = lane >> 4, l15 = lane & 15;
  const int m0 = (wave >> 1)*64, n0 = (wave & 1)*64;
  __shared__ short as[130][32];
  __shared__ short bs[384][32];
  f32x4 acc[4][4];
  #pragma unroll
  for (int i = 0; i < 4; ++i)
    #pragma unroll
    for (int j = 0; j < 4; ++j) acc[i][j] = (f32x4){0.f,0.f,0.f,0.f};
  for (int ky = 0; ky < 3; ++ky){
    int r = y + ky - 1;
    if ((unsigned)r >= 128u) continue;
    const short* xrow = xT + (size_t)(b*128 + r)*130*256;
    const short* wk   = w2 + (size_t)ky*384*256;
    for (int ch = 0; ch < 8; ++ch){
      const int ci0 = ch*32;
      __syncthreads();
      for (int i = t; i < 520; i += 256){
        int col = i >> 2, cg = i & 3;
        *(uint4*)&as[col][cg*8] = *(const uint4*)&xrow[col*256 + ci0 + cg*8];
      }
      for (int i = t; i < 1536; i += 256){
        int rr = i >> 2, cg = i & 3;
        *(uint4*)&bs[rr][cg*8] = *(const uint4*)&wk[rr*256 + ci0 + cg*8];
      }
      __syncthreads();
      #pragma unroll
      for (int kx = 0; kx < 3; ++kx){
        short8 af[4], bf[4];
        #pragma unroll
        for (int mt = 0; mt < 4; ++mt)
          af[mt] = *(const short8*)&as[m0 + mt*16 + l15 + kx][quad*8];
        #pragma unroll
        for (int nt = 0; nt < 4; ++nt)
          bf[nt] = *(const short8*)&bs[kx*128 + n0 + nt*16 + l15][quad*8];
        #pragma unroll
        for (int mt = 0; mt < 4; ++mt)
          #pragma unroll
          for (int nt = 0; nt < 4; ++nt)
            acc[mt][nt] = __builtin_amdgcn_mfma_f32_16x16x32_bf16(af[mt], bf[nt], acc[mt][nt], 0, 0, 0);
      }
    }
  }
  #pragma unroll
  for (int nt = 0; nt < 4; ++nt){
    int co = n0 + nt*16 + l15;
    float g = gg[co], bia = bb[co];
    #pragma unroll
    for (int mt = 0; mt < 4; ++mt){
      int xb = m0 + mt*16 + quad*4;
      float4 o4;
      o4.x = fmaxf(acc[mt][nt][0]*g + bia, 0.f);
      o4.y = fmaxf(acc[mt][nt][1]*g + bia, 0.f);
      o4.z = fmaxf(acc[mt][nt][2]*g + bia, 0.f);
      o4.w = fmaxf(acc[mt][nt][3]*g + bia, 0.f);
      *(float4*)&h[((size_t)(b*128 + co)*128 + y)*128 + xb] = o4;
    }
  }
}

// ============ P4: zero pad columns of hT ============
__global__ void k_hzero(short* __restrict__ hT){
  int t = blockIdx.x*256 + threadIdx.x;
  int ci = t & 127, side = (t >> 7) & 1, row = t >> 8;
  int cpad = side ? 129 : 0;
  hT[((size_t)row*130 + cpad)*128 + ci] = 0;
}

// ============ P5: h NCHW fp32 -> hT[b][r][c+1][ci] bf16 ============
__global__ __launch_bounds__(256) void k_hrep(const float* __restrict__ h, short* __restrict__ hT){
  const int blk = blockIdx.x;
  const int cgrp = blk & 1, cig = (blk >> 1) & 3, r = (blk >> 3) & 127, b = blk >> 10;
  const int c0 = cgrp*64, ci0 = cig*32;
  __shared__ float lds[32][65];
  const int t = threadIdx.x;
  for (int i = t; i < 2048; i += 256){
    int lci = i >> 6, c = i & 63;
    lds[lci][c] = h[((size_t)(b*128 + ci0 + lci)*128 + r)*128 + c0 + c];
  }
  __syncthreads();
  for (int i = t; i < 2048; i += 256){
    int lci = i & 31, cc = i >> 5;
    hT[((size_t)(b*128 + r)*130 + c0 + cc + 1)*128 + ci0 + lci] = f2bs(lds[lci][cc]);
  }
}

// ============ P6: fold local weights: wloc[ky][kx*128+co][ci] bf16 ============
__global__ __launch_bounds__(256) void k_lwrep(const float* __restrict__ w1, const float* __restrict__ g1,
      const float* __restrict__ w2, const float* __restrict__ g2, short* __restrict__ wloc){
  int i = blockIdx.x*256 + threadIdx.x;
  int ci = i & 127, row = (i >> 7) % 384, ky = i / 49152;
  int kx = row >> 7, co = row & 127;
  float v = w1[(co*128 + ci)*9 + ky*3 + kx] * g1[co];
  if (ky == 1 && kx == 1) v += w2[co*128 + ci] * g2[co];
  wloc[i] = f2bs(v);
}

// ============ K2: local conv (folded 3x3+1x1)  (MFMA implicit GEMM) ============
__global__ __launch_bounds__(256) void k_localm(const short* __restrict__ hT, const short* __restrict__ wloc,
      const float* __restrict__ b1, const float* __restrict__ b2, float* __restrict__ out){
  const int blk = blockIdx.x;
  const int b = blk >> 7, y = blk & 127;
  const int t = threadIdx.x, lane = t & 63, wave = t >> 6;
  const int quad = lane >> 4, l15 = lane & 15;
  const int m0 = (wave >> 1)*64, n0 = (wave & 1)*64;
  __shared__ short as[130][32];
  __shared__ short bs[384][32];
  f32x4 acc[4][4];
  #pragma unroll
  for (int i = 0; i < 4; ++i)
    #pragma unroll
    for (int j = 0; j < 4; ++j) acc[i][j] = (f32x4){0.f,0.f,0.f,0.f};
  for (int ky = 0; ky < 3; ++ky){
    int r = y + ky - 1;
    if ((unsigned)r >= 128u) continue;
    const short* xrow = hT + (size_t)(b*128 + r)*130*128;
    const short* wk   = wloc + (size_t)ky*384*128;
    for (int ch = 0; ch < 4; ++ch){
      const int ci0 = ch*32;
      __syncthreads();
      for (int i = t; i < 520; i += 256){
        int col = i >> 2, cg = i & 3;
        *(uint4*)&as[col][cg*8] = *(const uint4*)&xrow[col*128 + ci0 + cg*8];
      }
      for (int i = t; i < 1536; i += 256){
        int rr = i >> 2, cg = i & 3;
        *(uint4*)&bs[rr][cg*8] = *(const uint4*)&wk[rr*128 + ci0 + cg*8];
      }
      __syncthreads();
      #pragma unroll
      for (int kx = 0; kx < 3; ++kx){
        short8 af[4], bf[4];
        #pragma unroll
        for (int mt = 0; mt < 4; ++mt)
          af[mt] = *(const short8*)&as[m0 + mt*16 + l15 + kx][quad*8];
        #pragma unroll
        for (int nt = 0; nt < 4; ++nt)
          bf[nt] = *(const short8*)&bs[kx*128 + n0 + nt*16 + l15][quad*8];
        #pragma unroll
        for (int mt = 0; mt < 4; ++mt)
          #pragma unroll
          for (int nt = 0; nt < 4; ++nt)
            acc[mt][nt] = __builtin_amdgcn_mfma_f32_16x16x32_bf16(af[mt], bf[nt], acc[mt][nt], 0, 0, 0);
      }
    }
  }
  #pragma unroll
  for (int nt = 0; nt < 4; ++nt){
    int co = n0 + nt*16 + l15;
    float bia = b1[co] + b2[co];
    #pragma unroll
    for (int mt = 0; mt < 4; ++mt){
      int xb = m0 + mt*16 + quad*4;
      float4 o4;
      o4.x = acc[mt][nt][0] + bia;
      o4.y = acc[mt][nt][1] + bia;
      o4.z = acc[mt][nt][2] + bia;
      o4.w = acc[mt][nt][3] + bia;
      *(float4*)&out[((size_t)(b*128 + co)*128 + y)*128 + xb] = o4;
    }
  }
}

// ============ P9: qkv_w fp32 -> bf16 [oc][ci] (already k-contiguous) ============
__global__ __launch_bounds__(256) void k_wqkvrep(const float* __restrict__ w, short* __restrict__ wqkv){
  int i = blockIdx.x*256 + threadIdx.x;      // 49152 total
  wqkv[i] = f2bs(w[i]);
}

// ============ K3: qkv 1x1 conv (MFMA GEMM over hT) -> windowed q,k,v ============
// grid: (512 = b*128+y, 3 = q/k/v). M=128 px, N=128 oc, K=128 ci.
__global__ __launch_bounds__(256) void k_qkvm(const short* __restrict__ hT, const short* __restrict__ wqkv,
      bf16* __restrict__ q, bf16* __restrict__ k, bf16* __restrict__ v){
  const int blk = blockIdx.x, ocg = blockIdx.y;
  const int b = blk >> 7, y = blk & 127;
  const int t = threadIdx.x, lane = t & 63, wave = t >> 6;
  const int quad = lane >> 4, l15 = lane & 15;
  const int m0 = (wave >> 1)*64, n0 = (wave & 1)*64;
  __shared__ short as[128][32];
  __shared__ short bs[128][32];
  const short* xrow = hT + ((size_t)(b*128 + y)*130 + 1)*128;   // skip halo col
  const short* wk   = wqkv + (size_t)ocg*128*128;
  f32x4 acc[4][4];
  #pragma unroll
  for (int i = 0; i < 4; ++i)
    #pragma unroll
    for (int j = 0; j < 4; ++j) acc[i][j] = (f32x4){0.f,0.f,0.f,0.f};
  for (int ch = 0; ch < 4; ++ch){
    const int ci0 = ch*32;
    __syncthreads();
    for (int i = t; i < 512; i += 256){
      int col = i >> 2, cg = i & 3;
      *(uint4*)&as[col][cg*8] = *(const uint4*)&xrow[col*128 + ci0 + cg*8];
    }
    for (int i = t; i < 512; i += 256){
      int rr = i >> 2, cg = i & 3;
      *(uint4*)&bs[rr][cg*8] = *(const uint4*)&wk[rr*128 + ci0 + cg*8];
    }
    __syncthreads();
    short8 af[4], bf[4];
    #pragma unroll
    for (int mt = 0; mt < 4; ++mt)
      af[mt] = *(const short8*)&as[m0 + mt*16 + l15][quad*8];
    #pragma unroll
    for (int nt = 0; nt < 4; ++nt)
      bf[nt] = *(const short8*)&bs[n0 + nt*16 + l15][quad*8];
    #pragma unroll
    for (int mt = 0; mt < 4; ++mt)
      #pragma unroll
      for (int nt = 0; nt < 4; ++nt)
        acc[mt][nt] = __builtin_amdgcn_mfma_f32_16x16x32_bf16(af[mt], bf[nt], acc[mt][nt], 0, 0, 0);
  }
  bf16* dst = (ocg == 0) ? q : (ocg == 1) ? k : v;
  const int iy = y & 7, hy = y >> 3;
  #pragma unroll
  for (int nt = 0; nt < 4; ++nt){
    int co = n0 + nt*16 + l15;          // oc within this 128-group
    int head = co >> 4, d = co & 15;
    #pragma unroll
    for (int mt = 0; mt < 4; ++mt){
      int xb = m0 + mt*16 + quad*4;
      #pragma unroll
      for (int r = 0; r < 4; ++r){
        int x = xb + r;
        int bw = b*256 + hy*16 + (x >> 3);
        int n = iy*8 + (x & 7);
        dst[((size_t)(bw*8+head)*64 + n)*16 + d] = f2b(acc[mt][nt][r]);
      }
    }
  }
}

// ============ K4: dots = q.k^T * 0.25 + relpos bias ============
__global__ __launch_bounds__(256) void k_dots(const bf16* __restrict__ q, const bf16* __restrict__ kk,
      const float* __restrict__ rel, bf16* __restrict__ dots){
  const int bw = blockIdx.x, hd = blockIdx.y;
  __shared__ bf16 qs[64][16], ks[64][16];
  const int t = threadIdx.x;
  const size_t base = (size_t)(bw*8+hd)*1024;
  for (int i = t; i < 1024; i += 256){ qs[i>>4][i&15] = q[base + i]; ks[i>>4][i&15] = kk[base + i]; }
  __syncthreads();
  const int n = t >> 2, jm = t & 3;
  float qr[16];
  #pragma unroll
  for (int d = 0; d < 16; ++d) qr[d] = b2f(qs[n][d]);
  const int ny = n >> 3, nx = n & 7;
  for (int mm = 0; mm < 16; ++mm){
    int m = jm*16 + mm;
    float a = 0.f;
    #pragma unroll
    for (int d = 0; d < 16; ++d) a += qr[d]*b2f(ks[m][d]);
    int my = m >> 3, mx = m & 7;
    int ridx = (ny - my + 7)*15 + (nx - mx + 7);
    float bias = rel[ridx*8 + hd];
    dots[base*4 + (size_t)n*64 + m] = f2b(a*0.25f + bias);
  }
}

// ============ K5: axis reductions ============
__global__ void k_z1(const bf16* __restrict__ dots, bf16* __restrict__ z){
  int t = blockIdx.x*256 + threadIdx.x;
  int bw = t >> 9, r = t & 511; int hd = r >> 6, m = r & 63;
  const bf16* p = dots + (size_t)(bw*8+hd)*4096 + m;
  float mx = -1e30f, sm = 0.f;
  for (int n = 0; n < 64; ++n){ float v = b2f(p[n*64]); mx = fmaxf(mx,v); sm += v; }
  z[(size_t)bw*1024 + hd*64 + m]       = f2b(mx);
  z[(size_t)bw*1024 + 512 + hd*64 + m] = f2b(sm*(1.f/64.f));
}
__global__ void k_z2(const bf16* __restrict__ dots, bf16* __restrict__ z){
  int t = blockIdx.x*256 + threadIdx.x;
  int bw = t >> 9, r = t & 511; int n = r >> 3, hd = r & 7;
  const bf16* p = dots + ((size_t)(bw*8+hd)*64 + n)*64;
  float mx = -1e30f, sm = 0.f;
  for (int m = 0; m < 64; ++m){ float v = b2f(p[m]); mx = fmaxf(mx,v); sm += v; }
  z[(size_t)bw*1024 + n*8 + hd]       = f2b(mx);
  z[(size_t)bw*1024 + 512 + n*8 + hd] = f2b(sm*(1.f/64.f));
}
__global__ void k_z3(const bf16* __restrict__ dots, bf16* __restrict__ z){
  int t = blockIdx.x*256 + threadIdx.x;
  int bw = t >> 12, r = t & 4095;
  const bf16* p = dots + (size_t)bw*32768 + r;
  float mx = -1e30f, sm = 0.f;
  for (int hd = 0; hd < 8; ++hd){ float v = b2f(p[hd*4096]); mx = fmaxf(mx,v); sm += v; }
  z[(size_t)bw*8192 + r]        = f2b(mx);
  z[(size_t)bw*8192 + 4096 + r] = f2b(sm*0.125f);
}

// ============ K6: 7x7 2->1 conv + bn + sigmoid ============
__global__ __launch_bounds__(256) void k_gate(const bf16* __restrict__ z, const float* __restrict__ w,
      const float* __restrict__ gg, const float* __restrict__ bb, float* __restrict__ G, int R, int C){
  __shared__ float wsm[98];
  const int t = threadIdx.x;
  if (t < 98) wsm[t] = w[t];
  __syncthreads();
  const int bw = blockIdx.x;
  int p = blockIdx.y*256 + t; if (p >= R*C) return;
  int y = p / C, x = p - y*C;
  float acc = 0.f;
  for (int c = 0; c < 2; ++c)
    for (int ky = 0; ky < 7; ++ky){
      int iy = y + ky - 3; if ((unsigned)iy >= (unsigned)R) continue;
      for (int kx = 0; kx < 7; ++kx){
        int ix = x + kx - 3; if ((unsigned)ix >= (unsigned)C) continue;
        acc += b2f(z[((size_t)(bw*2+c)*R + iy)*C + ix]) * wsm[c*49 + ky*7 + kx];
      }
    }
  G[(size_t)bw*R*C + p] = sigm(acc*gg[0] + bb[0]);
}

// ============ K7: gated softmax + attn@v -> o ============
__global__ __launch_bounds__(256) void k_attn(const bf16* __restrict__ dots, const float* __restrict__ G1,
      const float* __restrict__ G2, const float* __restrict__ G3, const bf16* __restrict__ v,
      float* __restrict__ o){
  const int bw = blockIdx.x, hd = blockIdx.y;
  const int b = bw >> 8, wy = (bw >> 4) & 15, wx = bw & 15;
  __shared__ float attn[64][65];
  __shared__ bf16 vs[64][16];
  __shared__ float invTot[64];
  const int t = threadIdx.x;
  for (int i = t; i < 1024; i += 256) vs[i>>4][i&15] = v[(size_t)(bw*8+hd)*1024 + i];
  const int n = t >> 2, j = t & 3;
  float g2v = G2[(size_t)bw*512 + n*8 + hd];
  const bf16* dp = dots + ((size_t)(bw*8+hd)*64 + n)*64 + j*16;
  const float* g1p = G1 + (size_t)bw*512 + hd*64 + j*16;
  const float* g3p = G3 + (size_t)bw*4096 + n*64 + j*16;
  float e[16]; float mx = -1e30f;
  #pragma unroll
  for (int m = 0; m < 16; ++m){
    float dv = b2f(dp[m]) * ((g1p[m] + g2v + g3p[m]) * (1.f/3.f));
    e[m] = dv; mx = fmaxf(mx, dv);
  }
  mx = fmaxf(mx, __shfl_xor(mx, 1, 4));
  mx = fmaxf(mx, __shfl_xor(mx, 2, 4));
  float s = 0.f;
  #pragma unroll
  for (int m = 0; m < 16; ++m){ float ev = expf(e[m]-mx); e[m] = ev; s += ev; }
  s += __shfl_xor(s, 1, 4);
  s += __shfl_xor(s, 2, 4);
  #pragma unroll
  for (int m = 0; m < 16; ++m) attn[n][j*16+m] = e[m];
  if (j == 0) invTot[n] = 1.f/s;
  __syncthreads();
  const int dg = j;
  float acc[4] = {0.f,0.f,0.f,0.f};
  for (int m = 0; m < 64; ++m){
    float a = attn[n][m];
    #pragma unroll
    for (int dd = 0; dd < 4; ++dd) acc[dd] += a * b2f(vs[m][dg*4+dd]);
  }
  float it = invTot[n];
  int y = wy*8 + (n>>3), x = wx*8 + (n&7);
  #pragma unroll
  for (int dd = 0; dd < 4; ++dd){
    int c = hd*16 + dg*4 + dd;
    o[((size_t)(b*128+c)*128 + y)*128 + x] = acc[dd]*it;
  }
}

// ============ K8: Fh / Fw axial gates ============
__global__ void k_fw(const float* __restrict__ o, float* __restrict__ Fw){
  int t = blockIdx.x*256 + threadIdx.x; if (t >= 4*128*32*128) return;
  int x = t & 127, kk = (t>>7) & 31, bc = t >> 12;
  const float* p = o + ((size_t)bc*128 + kk*4)*128 + x;
  float mx = -1e30f, sm = 0.f;
  #pragma unroll
  for (int r = 0; r < 4; ++r){ float v = p[r*128]; mx = fmaxf(mx,v); sm += v; }
  Fw[t] = sigm(sm*0.25f + mx);
}
__global__ void k_fh(const float* __restrict__ o, float* __restrict__ Fh){
  int t = blockIdx.x*256 + threadIdx.x; if (t >= 4*128*128*32) return;
  int kk = t & 31, y = (t>>5) & 127, bc = t >> 12;
  const float* p = o + ((size_t)bc*128 + y)*128 + kk*4;
  float mx = -1e30f, sm = 0.f;
  #pragma unroll
  for (int r = 0; r < 4; ++r){ float v = p[r]; mx = fmaxf(mx,v); sm += v; }
  Fh[t] = sigm(sm*0.25f + mx);
}

// ============ K9: comb = o * (Fh@Fw) + local ============
__global__ __launch_bounds__(256) void k_comb(const float* __restrict__ o, const float* __restrict__ Fh,
      const float* __restrict__ Fw, const float* __restrict__ local, float* __restrict__ comb){
  const int bc = blockIdx.x;
  __shared__ float fh[128][33];
  __shared__ float fw[32][129];
  const int t = threadIdx.x;
  for (int i = t; i < 4096; i += 256) fh[i>>5][i&31]  = Fh[(size_t)bc*4096 + i];
  for (int i = t; i < 4096; i += 256) fw[i>>7][i&127] = Fw[(size_t)bc*4096 + i];
  __syncthreads();
  for (int i = t; i < 16384; i += 256){
    int y = i >> 7, x = i & 127;
    float g = 0.f;
    #pragma unroll
    for (int kk = 0; kk < 32; ++kk) g += fh[y][kk]*fw[kk][x];
    size_t idx = (size_t)bc*16384 + i;
    comb[idx] = o[idx]*g + local[idx];
  }
}

// ============ K10: reflect-pad + depthwise 8x8 + bn ============
__global__ __launch_bounds__(256) void k_dw(const float* __restrict__ comb, const float* __restrict__ dw,
      const float* __restrict__ gg, const float* __restrict__ bb, float* __restrict__ out){
  const int tx = threadIdx.x, ty = threadIdx.y, t = ty*16+tx;
  const int bz = blockIdx.z; const int c = bz & 127;
  const int oy0 = blockIdx.y*16, ox0 = blockIdx.x*16;
  __shared__ float xs[23][23];
  __shared__ float wsm[64];
  if (t < 64) wsm[t] = dw[c*64 + t];
  for (int i = t; i < 529; i += 256){
    int iy = i/23, ix = i - iy*23;
    int y = oy0 + iy - 3, x = ox0 + ix - 3;
    float v = 0.f;
    if (y >= 0 && y <= 128 && x >= 0 && x <= 128){
      int yy = (y==128)?126:y, xx = (x==128)?126:x;
      v = comb[((size_t)bz*128 + yy)*128 + xx];
    }
    xs[iy][ix] = v;
  }
  __syncthreads();
  float acc = 0.f;
  #pragma unroll
  for (int ky = 0; ky < 8; ++ky)
    #pragma unroll
    for (int kx = 0; kx < 8; ++kx)
      acc += xs[ty+ky][tx+kx]*wsm[ky*8+kx];
  out[((size_t)bz*128 + oy0+ty)*128 + ox0+tx] = acc*gg[c] + bb[c];
}

// ============ P7: zero omT halo cols ============
__global__ void k_omzero(short* __restrict__ omT){
  int t = blockIdx.x*256 + threadIdx.x;
  int ci = t & 127, side = (t >> 7) & 1, row = t >> 8;
  int cpad = side ? 129 : 0;
  omT[((size_t)row*130 + cpad)*128 + ci] = 0;
}

// ============ P8: repack up_w -> wup[tap][co][ci] bf16 ============
__global__ __launch_bounds__(256) void k_uwrep(const float* __restrict__ w, short* __restrict__ wup){
  int i = blockIdx.x*256 + threadIdx.x;
  int ci = i & 127, co = (i >> 7) & 63, tap = i >> 13;
  wup[i] = f2bs(w[(co*128 + ci)*9 + tap]);
}

// ============ K11: 1x1 proj conv 128->128 -> omT bf16 NHWC+halo ============
__global__ __launch_bounds__(256) void k_pw(const float* __restrict__ p1, const float* __restrict__ w,
      short* __restrict__ omT){
  const int pt = blockIdx.x, cb = blockIdx.y;
  const int P0 = pt*64; const int b = P0 >> 14; const int rem0 = P0 & 16383;
  const int y = rem0 >> 7, x0 = rem0 & 127;
  __shared__ float xsm[128][65];
  __shared__ float wsm[64][129];
  const int tx = threadIdx.x, ty = threadIdx.y, t = ty*16+tx;
  for (int i = t; i < 128*64; i += 256){
    int ci = i >> 6, p = i & 63;
    xsm[ci][p] = p1[(size_t)(b*128+ci)*16384 + rem0 + p];
  }
  for (int i = t; i < 64*128; i += 256){
    int co = i >> 7, ci = i & 127;
    wsm[co][ci] = w[(cb*64+co)*128 + ci];
  }
  __syncthreads();
  float acc[4][4] = {};
  for (int ci = 0; ci < 128; ++ci){
    float hv[4], wv[4];
    #pragma unroll
    for (int jj = 0; jj < 4; ++jj) hv[jj] = xsm[ci][jj*16+tx];
    #pragma unroll
    for (int ii = 0; ii < 4; ++ii) wv[ii] = wsm[ii*16+ty][ci];
    #pragma unroll
    for (int ii = 0; ii < 4; ++ii)
      #pragma unroll
      for (int jj = 0; jj < 4; ++jj) acc[ii][jj] += wv[ii]*hv[jj];
  }
  __syncthreads();
  float* pt_t = &xsm[0][0];
  #pragma unroll
  for (int ii = 0; ii < 4; ++ii)
    #pragma unroll
    for (int jj = 0; jj < 4; ++jj)
      pt_t[(jj*16+tx)*65 + ii*16+ty] = acc[ii][jj];
  __syncthreads();
  for (int i = t; i < 4096; i += 256){
    int px = i >> 6, co_l = i & 63;
    omT[((size_t)(b*128 + y)*130 + x0 + px + 1)*128 + cb*64 + co_l] = f2bs(pt_t[px*65 + co_l]);
  }
}

// ============ K12: transposed 3x3 stride-2 conv 128->64 (MFMA, parity decomp) ============
__global__ __launch_bounds__(256) void k_upm(const short* __restrict__ omT, const short* __restrict__ wup,
      float* __restrict__ out){
  const int blk = blockIdx.x;
  const int b = blk >> 7, y = blk & 127;
  const int t = threadIdx.x, lane = t & 63, wave = t >> 6;
  const int quad = lane >> 4, l15 = lane & 15;
  const int m0w = wave*32;
  __shared__ __align__(16) char smem[53504];
  short* asp = (short*)smem;
  short* bsp = (short*)(smem + 16640);
  float* ptile = (float*)smem;
  const int PAR[9] = {3,2,3, 1,0,1, 3,2,3};
  const int ROW[9] = {0,0,0, 0,0,0, 1,1,1};
  const int SHF[9] = {0,0,1, 0,0,1, 0,0,1};
  f32x4 acc[4][2][4];
  #pragma unroll
  for (int p = 0; p < 4; ++p)
    #pragma unroll
    for (int mt = 0; mt < 2; ++mt)
      #pragma unroll
      for (int nt = 0; nt < 4; ++nt) acc[p][mt][nt] = (f32x4){0.f,0.f,0.f,0.f};
  for (int ch = 0; ch < 4; ++ch){
    const int ci0 = ch*32;
    __syncthreads();
    for (int i = t; i < 1040; i += 256){
      int rw = (i >= 520), j = i - rw*520;
      int col = j >> 2, cg = j & 3;
      uint4 val = {0,0,0,0};
      if (y + rw < 128)
        val = *(const uint4*)&omT[((size_t)(b*128 + y + rw)*130 + col)*128 + ci0 + cg*8];
      *(uint4*)&asp[((rw*130 + col)*32) + cg*8] = val;
    }
    for (int i = t; i < 2304; i += 256){
      int rr = i >> 2, cg = i & 3;
      *(uint4*)&bsp[rr*32 + cg*8] = *(const uint4*)&wup[rr*128 + ci0 + cg*8];
    }
    __syncthreads();
    #pragma unroll
    for (int k = 0; k < 9; ++k){
      const int pr = PAR[k], rw = ROW[k], sh = SHF[k];
      if (rw && y == 127) continue;
      short8 af[2], bf[4];
      #pragma unroll
      for (int mt = 0; mt < 2; ++mt)
        af[mt] = *(const short8*)&asp[((rw*130 + m0w + mt*16 + l15 + 1 + sh))*32 + quad*8];
      #pragma unroll
      for (int nt = 0; nt < 4; ++nt)
        bf[nt] = *(const short8*)&bsp[(k*64 + nt*16 + l15)*32 + quad*8];
      #pragma unroll
      for (int mt = 0; mt < 2; ++mt)
        #pragma unroll
        for (int nt = 0; nt < 4; ++nt)
          acc[pr][mt][nt] = __builtin_amdgcn_mfma_f32_16x16x32_bf16(af[mt], bf[nt], acc[pr][mt][nt], 0, 0, 0);
    }
  }
  #pragma unroll
  for (int p = 0; p < 4; ++p){
    __syncthreads();
    #pragma unroll
    for (int mt = 0; mt < 2; ++mt)
      #pragma unroll
      for (int nt = 0; nt < 4; ++nt){
        int co = nt*16 + l15;
        int xb = m0w + mt*16 + quad*4;
        #pragma unroll
        for (int r = 0; r < 4; ++r)
          ptile[co*132 + xb + r] = acc[p][mt][nt][r];
      }
    __syncthreads();
    int py = p >> 1, px = p & 1;
    int Y = 2*y + py;
    for (int i = t; i < 8192; i += 256){
      int co = i >> 7, xx = i & 127;
      out[((size_t)(b*64 + co)*256 + Y)*256 + 2*xx + px] = ptile[co*132 + xx];
    }
  }
}

extern "C" void kernel_launch(void* const* d_in, const int* in_sizes, int n_in,
                              void* d_out, int out_size, void* d_ws, size_t ws_size,
                              hipStream_t stream) {
  const float* x       = (const float*)d_in[0];
  const float* conv_w  = (const float*)d_in[1];
  const float* bn1_g   = (const float*)d_in[2];
  const float* bn1_b   = (const float*)d_in[3];
  const float* qkv_w   = (const float*)d_in[4];
  const float* loc1_w  = (const float*)d_in[5];
  const float* loc1_g  = (const float*)d_in[6];
  const float* loc1_b  = (const float*)d_in[7];
  const float* loc2_w  = (const float*)d_in[8];
  const float* loc2_g  = (const float*)d_in[9];
  const float* loc2_b  = (const float*)d_in[10];
  const float* rel_t   = (const float*)d_in[11];
  const float* cw_w    = (const float*)d_in[12];
  const float* cw_g    = (const float*)d_in[13];
  const float* cw_b    = (const float*)d_in[14];
  const float* hc_w    = (const float*)d_in[15];
  const float* hc_g    = (const float*)d_in[16];
  const float* hc_b    = (const float*)d_in[17];
  const float* hw_w    = (const float*)d_in[18];
  const float* hw_g    = (const float*)d_in[19];
  const float* hw_b    = (const float*)d_in[20];
  const float* proj_dw = (const float*)d_in[21];
  const float* proj_g  = (const float*)d_in[22];
  const float* proj_b  = (const float*)d_in[23];
  const float* proj_pw = (const float*)d_in[24];
  const float* up_w    = (const float*)d_in[25];

  char* ws = (char*)d_ws;
  float* h      = (float*)(ws + OFF_H);
  float* local  = (float*)(ws + OFF_LOCAL);
  bf16*  q      = (bf16*)(ws + OFF_Q);
  bf16*  k      = (bf16*)(ws + OFF_K);
  bf16*  v      = (bf16*)(ws + OFF_V);
  bf16*  dots   = (bf16*)(ws + OFF_DOTS);
  bf16*  z1     = (bf16*)(ws + OFF_Z1);
  bf16*  z2     = (bf16*)(ws + OFF_Z2);
  bf16*  z3     = (bf16*)(ws + OFF_Z3);
  float* G1     = (float*)(ws + OFF_G1);
  float* G2     = (float*)(ws + OFF_G2);
  float* G3     = (float*)(ws + OFF_G3);
  short* xT     = (short*)(ws + OFF_DOTS);              // transient
  short* hT     = (short*)(ws + OFF_HT);                // transient
  short* w2bf   = (short*)(ws + OFF_Z1);                // transient
  short* wloc   = (short*)(ws + OFF_Z2);                // transient
  short* wqkv   = (short*)(ws + OFF_Z3);                // transient (dead before z3)
  short* omT    = (short*)(ws + OFF_DOTS);              // transient (after k_comb)
  short* wup    = (short*)(ws + OFF_Z1);                // transient (after G1 gate)
  float* o_img  = (float*)(ws + OFF_Q);
  float* Fh     = (float*)(ws + OFF_DOTS);
  float* Fw     = (float*)(ws + OFF_DOTS + 8388608);
  float* comb   = (float*)(ws + OFF_H);
  float* proj1  = (float*)(ws + OFF_LOCAL);
  float* outp   = (float*)d_out;

  dim3 blk2(16,16);
  k_wrep <<<1152, 256, 0, stream>>>(conv_w, w2bf);
  k_xzero<<<1024, 256, 0, stream>>>(xT);
  k_xrep <<<8192, 256, 0, stream>>>(x, xT);
  k_conv1m<<<512, 256, 0, stream>>>(xT, w2bf, bn1_g, bn1_b, h);
  k_lwrep<<<576, 256, 0, stream>>>(loc1_w, loc1_g, loc2_w, loc2_g, wloc);
  k_hzero<<<512, 256, 0, stream>>>(hT);
  k_hrep <<<4096, 256, 0, stream>>>(h, hT);
  k_localm<<<512, 256, 0, stream>>>(hT, wloc, loc1_b, loc2_b, local);
  k_wqkvrep<<<192, 256, 0, stream>>>(qkv_w, wqkv);
  k_qkvm <<<dim3(512,3), 256, 0, stream>>>(hT, wqkv, q, k, v);
  k_dots <<<dim3(NWIN,8), 256, 0, stream>>>(q, k, rel_t, dots);
  k_z1   <<<2048, 256, 0, stream>>>(dots, z1);
  k_z2   <<<2048, 256, 0, stream>>>(dots, z2);
  k_z3   <<<16384, 256, 0, stream>>>(dots, z3);
  k_gate <<<dim3(NWIN,2),  256, 0, stream>>>(z1, cw_w, cw_g, cw_b, G1, 8, 64);
  k_gate <<<dim3(NWIN,2),  256, 0, stream>>>(z2, hc_w, hc_g, hc_b, G2, 64, 8);
  k_gate <<<dim3(NWIN,16), 256, 0, stream>>>(z3, hw_w, hw_g, hw_b, G3, 64, 64);
  k_attn <<<dim3(NWIN,8), 256, 0, stream>>>(dots, G1, G2, G3, v, o_img);
  k_fw   <<<8192, 256, 0, stream>>>(o_img, Fw);
  k_fh   <<<8192, 256, 0, stream>>>(o_img, Fh);
  k_comb <<<512, 256, 0, stream>>>(o_img, Fh, Fw, local, comb);
  k_dw   <<<dim3(8,8,BB*128), blk2, 0, stream>>>(comb, proj_dw, proj_g, proj_b, proj1);
  k_omzero<<<512, 256, 0, stream>>>(omT);
  k_uwrep<<<288, 256, 0, stream>>>(up_w, wup);
  k_pw   <<<dim3(1024,2), blk2, 0, stream>>>(proj1, proj_pw, omT);
  k_upm  <<<512, 256, 0, stream>>>(omT, wup, outp);
}

// Round 7
// 735.735 us; speedup vs baseline: 6.8354x; 1.1235x over previous
//
#include <hip/hip_runtime.h>
#include <hip/hip_bf16.h>

typedef __hip_bfloat16 bf16;
typedef __attribute__((ext_vector_type(8))) short short8;
typedef __attribute__((ext_vector_type(4))) float f32x4;

#define DEV __device__ __forceinline__
DEV float b2f(bf16 v){ return __bfloat162float(v); }
DEV bf16 f2b(float v){ return __float2bfloat16(v); }
DEV short f2bs(float v){ union{ bf16 b; short s; } u; u.b = __float2bfloat16(v); return u.s; }
DEV float sigm(float x){ return 1.f/(1.f + expf(-x)); }

// ---- problem constants ----
#define BB 4
#define CIN 256
#define MID 128
#define COUT 64
#define HH 128
#define WW 128
#define WS 8
#define HEADS 8
#define HD 16
#define NTOK 64
#define NWIN 1024

// ---- workspace layout (bytes) ----
static const size_t OFF_H     = 0;
static const size_t OFF_LOCAL = 33554432;
static const size_t OFF_Q     = 67108864;
static const size_t OFF_K     = 83886080;
static const size_t OFF_V     = 100663296;
static const size_t OFF_DOTS  = 117440512;
static const size_t OFF_Z1    = 184549376;
static const size_t OFF_Z2    = 186646528;
static const size_t OFF_Z3    = 188743680;
static const size_t OFF_G1    = 205520896;
static const size_t OFF_G2    = 207618048;
static const size_t OFF_G3    = 209715200;
static const size_t OFF_HT    = OFF_DOTS + 34078720;

// ============ P1: repack conv_w -> w2[kk][co][ci] bf16 ============
__global__ __launch_bounds__(256) void k_wrep(const float* __restrict__ w, short* __restrict__ w2){
  int i = blockIdx.x*256 + threadIdx.x;
  int ci = i & 255, co = (i >> 8) & 127, kk = i >> 15;
  w2[i] = f2bs(w[(co*256 + ci)*9 + kk]);
}

// ============ P2: zero pad columns of xT ============
__global__ void k_xzero(short* __restrict__ xT){
  int t = blockIdx.x*256 + threadIdx.x;
  int ci = t & 255, side = (t >> 8) & 1, row = t >> 9;
  int cpad = side ? 129 : 0;
  xT[((size_t)row*130 + cpad)*256 + ci] = 0;
}

// ============ P3: x NCHW fp32 -> xT[b][r][c+1][ci] bf16 ============
__global__ __launch_bounds__(256) void k_xrep(const float* __restrict__ x, short* __restrict__ xT){
  const int blk = blockIdx.x;
  const int cgrp = blk & 1, cig = (blk >> 1) & 7, r = (blk >> 4) & 127, b = blk >> 11;
  const int c0 = cgrp*64, ci0 = cig*32;
  __shared__ float lds[32][65];
  const int t = threadIdx.x;
  for (int i = t; i < 2048; i += 256){
    int lci = i >> 6, c = i & 63;
    lds[lci][c] = x[((size_t)(b*256 + ci0 + lci)*128 + r)*128 + c0 + c];
  }
  __syncthreads();
  for (int i = t; i < 2048; i += 256){
    int lci = i & 31, cc = i >> 5;
    xT[((size_t)(b*128 + r)*130 + c0 + cc + 1)*256 + ci0 + lci] = f2bs(lds[lci][cc]);
  }
}

// ============ K1: conv3x3 256->128 + bn + relu  (MFMA implicit GEMM) ============
__global__ __launch_bounds__(256) void k_conv1m(const short* __restrict__ xT, const short* __restrict__ w2,
      const float* __restrict__ gg, const float* __restrict__ bb, float* __restrict__ h){
  const int blk = blockIdx.x;
  const int b = blk >> 7, y = blk & 127;
  const int t = threadIdx.x, lane = t & 63, wave = t >> 6;
  const int quad = lane >> 4, l15 = lane & 15;
  const int m0 = (wave >> 1)*64, n0 = (wave & 1)*64;
  __shared__ short as[130][32];
  __shared__ short bs[384][32];
  f32x4 acc[4][4];
  #pragma unroll
  for (int i = 0; i < 4; ++i)
    #pragma unroll
    for (int j = 0; j < 4; ++j) acc[i][j] = (f32x4){0.f,0.f,0.f,0.f};
  for (int ky = 0; ky < 3; ++ky){
    int r = y + ky - 1;
    if ((unsigned)r >= 128u) continue;
    const short* xrow = xT + (size_t)(b*128 + r)*130*256;
    const short* wk   = w2 + (size_t)ky*384*256;
    for (int ch = 0; ch < 8; ++ch){
      const int ci0 = ch*32;
      __syncthreads();
      for (int i = t; i < 520; i += 256){
        int col = i >> 2, cg = i & 3;
        *(uint4*)&as[col][cg*8] = *(const uint4*)&xrow[col*256 + ci0 + cg*8];
      }
      for (int i = t; i < 1536; i += 256){
        int rr = i >> 2, cg = i & 3;
        *(uint4*)&bs[rr][cg*8] = *(const uint4*)&wk[rr*256 + ci0 + cg*8];
      }
      __syncthreads();
      #pragma unroll
      for (int kx = 0; kx < 3; ++kx){
        short8 af[4], bf[4];
        #pragma unroll
        for (int mt = 0; mt < 4; ++mt)
          af[mt] = *(const short8*)&as[m0 + mt*16 + l15 + kx][quad*8];
        #pragma unroll
        for (int nt = 0; nt < 4; ++nt)
          bf[nt] = *(const short8*)&bs[kx*128 + n0 + nt*16 + l15][quad*8];
        #pragma unroll
        for (int mt = 0; mt < 4; ++mt)
          #pragma unroll
          for (int nt = 0; nt < 4; ++nt)
            acc[mt][nt] = __builtin_amdgcn_mfma_f32_16x16x32_bf16(af[mt], bf[nt], acc[mt][nt], 0, 0, 0);
      }
    }
  }
  #pragma unroll
  for (int nt = 0; nt < 4; ++nt){
    int co = n0 + nt*16 + l15;
    float g = gg[co], bia = bb[co];
    #pragma unroll
    for (int mt = 0; mt < 4; ++mt){
      int xb = m0 + mt*16 + quad*4;
      float4 o4;
      o4.x = fmaxf(acc[mt][nt][0]*g + bia, 0.f);
      o4.y = fmaxf(acc[mt][nt][1]*g + bia, 0.f);
      o4.z = fmaxf(acc[mt][nt][2]*g + bia, 0.f);
      o4.w = fmaxf(acc[mt][nt][3]*g + bia, 0.f);
      *(float4*)&h[((size_t)(b*128 + co)*128 + y)*128 + xb] = o4;
    }
  }
}

// ============ P4: zero pad columns of hT ============
__global__ void k_hzero(short* __restrict__ hT){
  int t = blockIdx.x*256 + threadIdx.x;
  int ci = t & 127, side = (t >> 7) & 1, row = t >> 8;
  int cpad = side ? 129 : 0;
  hT[((size_t)row*130 + cpad)*128 + ci] = 0;
}

// ============ P5: h NCHW fp32 -> hT[b][r][c+1][ci] bf16 ============
__global__ __launch_bounds__(256) void k_hrep(const float* __restrict__ h, short* __restrict__ hT){
  const int blk = blockIdx.x;
  const int cgrp = blk & 1, cig = (blk >> 1) & 3, r = (blk >> 3) & 127, b = blk >> 10;
  const int c0 = cgrp*64, ci0 = cig*32;
  __shared__ float lds[32][65];
  const int t = threadIdx.x;
  for (int i = t; i < 2048; i += 256){
    int lci = i >> 6, c = i & 63;
    lds[lci][c] = h[((size_t)(b*128 + ci0 + lci)*128 + r)*128 + c0 + c];
  }
  __syncthreads();
  for (int i = t; i < 2048; i += 256){
    int lci = i & 31, cc = i >> 5;
    hT[((size_t)(b*128 + r)*130 + c0 + cc + 1)*128 + ci0 + lci] = f2bs(lds[lci][cc]);
  }
}

// ============ P6: fold local weights: wloc[ky][kx*128+co][ci] bf16 ============
__global__ __launch_bounds__(256) void k_lwrep(const float* __restrict__ w1, const float* __restrict__ g1,
      const float* __restrict__ w2, const float* __restrict__ g2, short* __restrict__ wloc){
  int i = blockIdx.x*256 + threadIdx.x;
  int ci = i & 127, row = (i >> 7) % 384, ky = i / 49152;
  int kx = row >> 7, co = row & 127;
  float v = w1[(co*128 + ci)*9 + ky*3 + kx] * g1[co];
  if (ky == 1 && kx == 1) v += w2[co*128 + ci] * g2[co];
  wloc[i] = f2bs(v);
}

// ============ K2: local conv (folded 3x3+1x1)  (MFMA implicit GEMM) ============
__global__ __launch_bounds__(256) void k_localm(const short* __restrict__ hT, const short* __restrict__ wloc,
      const float* __restrict__ b1, const float* __restrict__ b2, float* __restrict__ out){
  const int blk = blockIdx.x;
  const int b = blk >> 7, y = blk & 127;
  const int t = threadIdx.x, lane = t & 63, wave = t >> 6;
  const int quad = lane >> 4, l15 = lane & 15;
  const int m0 = (wave >> 1)*64, n0 = (wave & 1)*64;
  __shared__ short as[130][32];
  __shared__ short bs[384][32];
  f32x4 acc[4][4];
  #pragma unroll
  for (int i = 0; i < 4; ++i)
    #pragma unroll
    for (int j = 0; j < 4; ++j) acc[i][j] = (f32x4){0.f,0.f,0.f,0.f};
  for (int ky = 0; ky < 3; ++ky){
    int r = y + ky - 1;
    if ((unsigned)r >= 128u) continue;
    const short* xrow = hT + (size_t)(b*128 + r)*130*128;
    const short* wk   = wloc + (size_t)ky*384*128;
    for (int ch = 0; ch < 4; ++ch){
      const int ci0 = ch*32;
      __syncthreads();
      for (int i = t; i < 520; i += 256){
        int col = i >> 2, cg = i & 3;
        *(uint4*)&as[col][cg*8] = *(const uint4*)&xrow[col*128 + ci0 + cg*8];
      }
      for (int i = t; i < 1536; i += 256){
        int rr = i >> 2, cg = i & 3;
        *(uint4*)&bs[rr][cg*8] = *(const uint4*)&wk[rr*128 + ci0 + cg*8];
      }
      __syncthreads();
      #pragma unroll
      for (int kx = 0; kx < 3; ++kx){
        short8 af[4], bf[4];
        #pragma unroll
        for (int mt = 0; mt < 4; ++mt)
          af[mt] = *(const short8*)&as[m0 + mt*16 + l15 + kx][quad*8];
        #pragma unroll
        for (int nt = 0; nt < 4; ++nt)
          bf[nt] = *(const short8*)&bs[kx*128 + n0 + nt*16 + l15][quad*8];
        #pragma unroll
        for (int mt = 0; mt < 4; ++mt)
          #pragma unroll
          for (int nt = 0; nt < 4; ++nt)
            acc[mt][nt] = __builtin_amdgcn_mfma_f32_16x16x32_bf16(af[mt], bf[nt], acc[mt][nt], 0, 0, 0);
      }
    }
  }
  #pragma unroll
  for (int nt = 0; nt < 4; ++nt){
    int co = n0 + nt*16 + l15;
    float bia = b1[co] + b2[co];
    #pragma unroll
    for (int mt = 0; mt < 4; ++mt){
      int xb = m0 + mt*16 + quad*4;
      float4 o4;
      o4.x = acc[mt][nt][0] + bia;
      o4.y = acc[mt][nt][1] + bia;
      o4.z = acc[mt][nt][2] + bia;
      o4.w = acc[mt][nt][3] + bia;
      *(float4*)&out[((size_t)(b*128 + co)*128 + y)*128 + xb] = o4;
    }
  }
}

// ============ P9: qkv_w fp32 -> bf16 [oc][ci] ============
__global__ __launch_bounds__(256) void k_wqkvrep(const float* __restrict__ w, short* __restrict__ wqkv){
  int i = blockIdx.x*256 + threadIdx.x;
  wqkv[i] = f2bs(w[i]);
}

// ============ K3: qkv 1x1 conv (MFMA GEMM over hT) -> windowed q,k,v ============
__global__ __launch_bounds__(256) void k_qkvm(const short* __restrict__ hT, const short* __restrict__ wqkv,
      bf16* __restrict__ q, bf16* __restrict__ k, bf16* __restrict__ v){
  const int blk = blockIdx.x, ocg = blockIdx.y;
  const int b = blk >> 7, y = blk & 127;
  const int t = threadIdx.x, lane = t & 63, wave = t >> 6;
  const int quad = lane >> 4, l15 = lane & 15;
  const int m0 = (wave >> 1)*64, n0 = (wave & 1)*64;
  __shared__ short as[128][32];
  __shared__ short bs[128][32];
  const short* xrow = hT + ((size_t)(b*128 + y)*130 + 1)*128;
  const short* wk   = wqkv + (size_t)ocg*128*128;
  f32x4 acc[4][4];
  #pragma unroll
  for (int i = 0; i < 4; ++i)
    #pragma unroll
    for (int j = 0; j < 4; ++j) acc[i][j] = (f32x4){0.f,0.f,0.f,0.f};
  for (int ch = 0; ch < 4; ++ch){
    const int ci0 = ch*32;
    __syncthreads();
    for (int i = t; i < 512; i += 256){
      int col = i >> 2, cg = i & 3;
      *(uint4*)&as[col][cg*8] = *(const uint4*)&xrow[col*128 + ci0 + cg*8];
    }
    for (int i = t; i < 512; i += 256){
      int rr = i >> 2, cg = i & 3;
      *(uint4*)&bs[rr][cg*8] = *(const uint4*)&wk[rr*128 + ci0 + cg*8];
    }
    __syncthreads();
    short8 af[4], bf[4];
    #pragma unroll
    for (int mt = 0; mt < 4; ++mt)
      af[mt] = *(const short8*)&as[m0 + mt*16 + l15][quad*8];
    #pragma unroll
    for (int nt = 0; nt < 4; ++nt)
      bf[nt] = *(const short8*)&bs[n0 + nt*16 + l15][quad*8];
    #pragma unroll
    for (int mt = 0; mt < 4; ++mt)
      #pragma unroll
      for (int nt = 0; nt < 4; ++nt)
        acc[mt][nt] = __builtin_amdgcn_mfma_f32_16x16x32_bf16(af[mt], bf[nt], acc[mt][nt], 0, 0, 0);
  }
  bf16* dst = (ocg == 0) ? q : (ocg == 1) ? k : v;
  const int iy = y & 7, hy = y >> 3;
  #pragma unroll
  for (int nt = 0; nt < 4; ++nt){
    int co = n0 + nt*16 + l15;
    int head = co >> 4, d = co & 15;
    #pragma unroll
    for (int mt = 0; mt < 4; ++mt){
      int xb = m0 + mt*16 + quad*4;
      #pragma unroll
      for (int r = 0; r < 4; ++r){
        int x = xb + r;
        int bw = b*256 + hy*16 + (x >> 3);
        int n = iy*8 + (x & 7);
        dst[((size_t)(bw*8+head)*64 + n)*16 + d] = f2b(acc[mt][nt][r]);
      }
    }
  }
}

// ============ K4: dots = q.k^T * 0.25 + relpos bias ============
__global__ __launch_bounds__(256) void k_dots(const bf16* __restrict__ q, const bf16* __restrict__ kk,
      const float* __restrict__ rel, bf16* __restrict__ dots){
  const int bw = blockIdx.x, hd = blockIdx.y;
  __shared__ bf16 qs[64][16], ks[64][16];
  const int t = threadIdx.x;
  const size_t base = (size_t)(bw*8+hd)*1024;
  for (int i = t; i < 1024; i += 256){ qs[i>>4][i&15] = q[base + i]; ks[i>>4][i&15] = kk[base + i]; }
  __syncthreads();
  const int n = t >> 2, jm = t & 3;
  float qr[16];
  #pragma unroll
  for (int d = 0; d < 16; ++d) qr[d] = b2f(qs[n][d]);
  const int ny = n >> 3, nx = n & 7;
  for (int mm = 0; mm < 16; ++mm){
    int m = jm*16 + mm;
    float a = 0.f;
    #pragma unroll
    for (int d = 0; d < 16; ++d) a += qr[d]*b2f(ks[m][d]);
    int my = m >> 3, mx = m & 7;
    int ridx = (ny - my + 7)*15 + (nx - mx + 7);
    float bias = rel[ridx*8 + hd];
    dots[base*4 + (size_t)n*64 + m] = f2b(a*0.25f + bias);
  }
}

// ============ K5: axis reductions ============
__global__ void k_z1(const bf16* __restrict__ dots, bf16* __restrict__ z){
  int t = blockIdx.x*256 + threadIdx.x;
  int bw = t >> 9, r = t & 511; int hd = r >> 6, m = r & 63;
  const bf16* p = dots + (size_t)(bw*8+hd)*4096 + m;
  float mx = -1e30f, sm = 0.f;
  for (int n = 0; n < 64; ++n){ float v = b2f(p[n*64]); mx = fmaxf(mx,v); sm += v; }
  z[(size_t)bw*1024 + hd*64 + m]       = f2b(mx);
  z[(size_t)bw*1024 + 512 + hd*64 + m] = f2b(sm*(1.f/64.f));
}
__global__ void k_z2(const bf16* __restrict__ dots, bf16* __restrict__ z){
  int t = blockIdx.x*256 + threadIdx.x;
  int bw = t >> 9, r = t & 511; int n = r >> 3, hd = r & 7;
  const bf16* p = dots + ((size_t)(bw*8+hd)*64 + n)*64;
  float mx = -1e30f, sm = 0.f;
  for (int m = 0; m < 64; ++m){ float v = b2f(p[m]); mx = fmaxf(mx,v); sm += v; }
  z[(size_t)bw*1024 + n*8 + hd]       = f2b(mx);
  z[(size_t)bw*1024 + 512 + n*8 + hd] = f2b(sm*(1.f/64.f));
}
__global__ void k_z3(const bf16* __restrict__ dots, bf16* __restrict__ z){
  int t = blockIdx.x*256 + threadIdx.x;
  int bw = t >> 12, r = t & 4095;
  const bf16* p = dots + (size_t)bw*32768 + r;
  float mx = -1e30f, sm = 0.f;
  for (int hd = 0; hd < 8; ++hd){ float v = b2f(p[hd*4096]); mx = fmaxf(mx,v); sm += v; }
  z[(size_t)bw*8192 + r]        = f2b(mx);
  z[(size_t)bw*8192 + 4096 + r] = f2b(sm*0.125f);
}

// ============ K6: generic 7x7 2->1 conv + bn + sigmoid (small gates) ============
__global__ __launch_bounds__(256) void k_gate(const bf16* __restrict__ z, const float* __restrict__ w,
      const float* __restrict__ gg, const float* __restrict__ bb, float* __restrict__ G, int R, int C){
  __shared__ float wsm[98];
  const int t = threadIdx.x;
  if (t < 98) wsm[t] = w[t];
  __syncthreads();
  const int bw = blockIdx.x;
  int p = blockIdx.y*256 + t; if (p >= R*C) return;
  int y = p / C, x = p - y*C;
  float acc = 0.f;
  for (int c = 0; c < 2; ++c)
    for (int ky = 0; ky < 7; ++ky){
      int iy = y + ky - 3; if ((unsigned)iy >= (unsigned)R) continue;
      for (int kx = 0; kx < 7; ++kx){
        int ix = x + kx - 3; if ((unsigned)ix >= (unsigned)C) continue;
        acc += b2f(z[((size_t)(bw*2+c)*R + iy)*C + ix]) * wsm[c*49 + ky*7 + kx];
      }
    }
  G[(size_t)bw*R*C + p] = sigm(acc*gg[0] + bb[0]);
}

// ============ K6b: specialized 64x64 gate (G3): LDS tile + 4x4 register patch ============
__global__ __launch_bounds__(256) void k_gate3(const bf16* __restrict__ z, const float* __restrict__ w,
      const float* __restrict__ gg, const float* __restrict__ bb, float* __restrict__ G){
  const int bw = blockIdx.x;
  __shared__ float pad[2][70][72];
  __shared__ float wsm[98];
  const int t = threadIdx.x;
  if (t < 98) wsm[t] = w[t];
  for (int i = t; i < 2*70*70; i += 256){
    int c = i / 4900, r = i % 4900;
    int py = r / 70, px = r % 70;
    int y = py - 3, x = px - 3;
    float v = 0.f;
    if ((unsigned)y < 64u && (unsigned)x < 64u)
      v = b2f(z[(size_t)bw*8192 + c*4096 + y*64 + x]);
    pad[c][py][px] = v;
  }
  __syncthreads();
  const int tx = t & 15, ty = t >> 4;
  const int x0 = tx*4, y0 = ty*4;
  float acc[4][4] = {};
  #pragma unroll
  for (int c = 0; c < 2; ++c){
    float wr[49];
    #pragma unroll
    for (int kk = 0; kk < 49; ++kk) wr[kk] = wsm[c*49 + kk];
    #pragma unroll
    for (int iy = 0; iy < 10; ++iy){
      float row[10];
      #pragma unroll
      for (int j = 0; j < 10; ++j) row[j] = pad[c][y0+iy][x0+j];
      #pragma unroll
      for (int dy = 0; dy < 4; ++dy){
        const int ky = iy - dy;
        if (ky < 0 || ky > 6) continue;     // compile-time (unrolled)
        #pragma unroll
        for (int kx = 0; kx < 7; ++kx){
          float wv = wr[ky*7 + kx];
          #pragma unroll
          for (int dx = 0; dx < 4; ++dx)
            acc[dy][dx] += wv * row[dx + kx];
        }
      }
    }
  }
  float g0 = gg[0], b0 = bb[0];
  #pragma unroll
  for (int dy = 0; dy < 4; ++dy){
    float4 o4;
    o4.x = sigm(acc[dy][0]*g0 + b0);
    o4.y = sigm(acc[dy][1]*g0 + b0);
    o4.z = sigm(acc[dy][2]*g0 + b0);
    o4.w = sigm(acc[dy][3]*g0 + b0);
    *(float4*)&G[(size_t)bw*4096 + (y0+dy)*64 + x0] = o4;
  }
}

// ============ K7: gated softmax + attn@v -> o ============
__global__ __launch_bounds__(256) void k_attn(const bf16* __restrict__ dots, const float* __restrict__ G1,
      const float* __restrict__ G2, const float* __restrict__ G3, const bf16* __restrict__ v,
      float* __restrict__ o){
  const int bw = blockIdx.x, hd = blockIdx.y;
  const int b = bw >> 8, wy = (bw >> 4) & 15, wx = bw & 15;
  __shared__ float attn[64][65];
  __shared__ bf16 vs[64][16];
  __shared__ float invTot[64];
  const int t = threadIdx.x;
  for (int i = t; i < 1024; i += 256) vs[i>>4][i&15] = v[(size_t)(bw*8+hd)*1024 + i];
  const int n = t >> 2, j = t & 3;
  float g2v = G2[(size_t)bw*512 + n*8 + hd];
  const bf16* dp = dots + ((size_t)(bw*8+hd)*64 + n)*64 + j*16;
  const float* g1p = G1 + (size_t)bw*512 + hd*64 + j*16;
  const float* g3p = G3 + (size_t)bw*4096 + n*64 + j*16;
  float e[16]; float mx = -1e30f;
  #pragma unroll
  for (int m = 0; m < 16; ++m){
    float dv = b2f(dp[m]) * ((g1p[m] + g2v + g3p[m]) * (1.f/3.f));
    e[m] = dv; mx = fmaxf(mx, dv);
  }
  mx = fmaxf(mx, __shfl_xor(mx, 1, 4));
  mx = fmaxf(mx, __shfl_xor(mx, 2, 4));
  float s = 0.f;
  #pragma unroll
  for (int m = 0; m < 16; ++m){ float ev = expf(e[m]-mx); e[m] = ev; s += ev; }
  s += __shfl_xor(s, 1, 4);
  s += __shfl_xor(s, 2, 4);
  #pragma unroll
  for (int m = 0; m < 16; ++m) attn[n][j*16+m] = e[m];
  if (j == 0) invTot[n] = 1.f/s;
  __syncthreads();
  const int dg = j;
  float acc[4] = {0.f,0.f,0.f,0.f};
  for (int m = 0; m < 64; ++m){
    float a = attn[n][m];
    #pragma unroll
    for (int dd = 0; dd < 4; ++dd) acc[dd] += a * b2f(vs[m][dg*4+dd]);
  }
  float it = invTot[n];
  int y = wy*8 + (n>>3), x = wx*8 + (n&7);
  #pragma unroll
  for (int dd = 0; dd < 4; ++dd){
    int c = hd*16 + dg*4 + dd;
    o[((size_t)(b*128+c)*128 + y)*128 + x] = acc[dd]*it;
  }
}

// ============ K8: Fh / Fw axial gates ============
__global__ void k_fw(const float* __restrict__ o, float* __restrict__ Fw){
  int t = blockIdx.x*256 + threadIdx.x; if (t >= 4*128*32*128) return;
  int x = t & 127, kk = (t>>7) & 31, bc = t >> 12;
  const float* p = o + ((size_t)bc*128 + kk*4)*128 + x;
  float mx = -1e30f, sm = 0.f;
  #pragma unroll
  for (int r = 0; r < 4; ++r){ float v = p[r*128]; mx = fmaxf(mx,v); sm += v; }
  Fw[t] = sigm(sm*0.25f + mx);
}
__global__ void k_fh(const float* __restrict__ o, float* __restrict__ Fh){
  int t = blockIdx.x*256 + threadIdx.x; if (t >= 4*128*128*32) return;
  int kk = t & 31, y = (t>>5) & 127, bc = t >> 12;
  const float* p = o + ((size_t)bc*128 + y)*128 + kk*4;
  float mx = -1e30f, sm = 0.f;
  #pragma unroll
  for (int r = 0; r < 4; ++r){ float v = p[r]; mx = fmaxf(mx,v); sm += v; }
  Fh[t] = sigm(sm*0.25f + mx);
}

// ============ K9: comb = o * (Fh@Fw) + local ============
__global__ __launch_bounds__(256) void k_comb(const float* __restrict__ o, const float* __restrict__ Fh,
      const float* __restrict__ Fw, const float* __restrict__ local, float* __restrict__ comb){
  const int bc = blockIdx.x;
  __shared__ float fh[128][33];
  __shared__ float fw[32][129];
  const int t = threadIdx.x;
  for (int i = t; i < 4096; i += 256) fh[i>>5][i&31]  = Fh[(size_t)bc*4096 + i];
  for (int i = t; i < 4096; i += 256) fw[i>>7][i&127] = Fw[(size_t)bc*4096 + i];
  __syncthreads();
  for (int i = t; i < 16384; i += 256){
    int y = i >> 7, x = i & 127;
    float g = 0.f;
    #pragma unroll
    for (int kk = 0; kk < 32; ++kk) g += fh[y][kk]*fw[kk][x];
    size_t idx = (size_t)bc*16384 + i;
    comb[idx] = o[idx]*g + local[idx];
  }
}

// ============ K10: reflect-pad + depthwise 8x8 + bn ============
__global__ __launch_bounds__(256) void k_dw(const float* __restrict__ comb, const float* __restrict__ dw,
      const float* __restrict__ gg, const float* __restrict__ bb, float* __restrict__ out){
  const int tx = threadIdx.x, ty = threadIdx.y, t = ty*16+tx;
  const int bz = blockIdx.z; const int c = bz & 127;
  const int oy0 = blockIdx.y*16, ox0 = blockIdx.x*16;
  __shared__ float xs[23][23];
  __shared__ float wsm[64];
  if (t < 64) wsm[t] = dw[c*64 + t];
  for (int i = t; i < 529; i += 256){
    int iy = i/23, ix = i - iy*23;
    int y = oy0 + iy - 3, x = ox0 + ix - 3;
    float v = 0.f;
    if (y >= 0 && y <= 128 && x >= 0 && x <= 128){
      int yy = (y==128)?126:y, xx = (x==128)?126:x;
      v = comb[((size_t)bz*128 + yy)*128 + xx];
    }
    xs[iy][ix] = v;
  }
  __syncthreads();
  float acc = 0.f;
  #pragma unroll
  for (int ky = 0; ky < 8; ++ky)
    #pragma unroll
    for (int kx = 0; kx < 8; ++kx)
      acc += xs[ty+ky][tx+kx]*wsm[ky*8+kx];
  out[((size_t)bz*128 + oy0+ty)*128 + ox0+tx] = acc*gg[c] + bb[c];
}

// ============ P7: zero omT halo cols ============
__global__ void k_omzero(short* __restrict__ omT){
  int t = blockIdx.x*256 + threadIdx.x;
  int ci = t & 127, side = (t >> 7) & 1, row = t >> 8;
  int cpad = side ? 129 : 0;
  omT[((size_t)row*130 + cpad)*128 + ci] = 0;
}

// ============ P8: repack up_w -> wup[tap][co][ci] bf16 ============
__global__ __launch_bounds__(256) void k_uwrep(const float* __restrict__ w, short* __restrict__ wup){
  int i = blockIdx.x*256 + threadIdx.x;
  int ci = i & 127, co = (i >> 7) & 63, tap = i >> 13;
  wup[i] = f2bs(w[(co*128 + ci)*9 + tap]);
}

// ============ K11: 1x1 proj conv 128->128 -> omT bf16 NHWC+halo ============
__global__ __launch_bounds__(256) void k_pw(const float* __restrict__ p1, const float* __restrict__ w,
      short* __restrict__ omT){
  const int pt = blockIdx.x, cb = blockIdx.y;
  const int P0 = pt*64; const int b = P0 >> 14; const int rem0 = P0 & 16383;
  const int y = rem0 >> 7, x0 = rem0 & 127;
  __shared__ float xsm[128][65];
  __shared__ float wsm[64][129];
  const int tx = threadIdx.x, ty = threadIdx.y, t = ty*16+tx;
  for (int i = t; i < 128*64; i += 256){
    int ci = i >> 6, p = i & 63;
    xsm[ci][p] = p1[(size_t)(b*128+ci)*16384 + rem0 + p];
  }
  for (int i = t; i < 64*128; i += 256){
    int co = i >> 7, ci = i & 127;
    wsm[co][ci] = w[(cb*64+co)*128 + ci];
  }
  __syncthreads();
  float acc[4][4] = {};
  for (int ci = 0; ci < 128; ++ci){
    float hv[4], wv[4];
    #pragma unroll
    for (int jj = 0; jj < 4; ++jj) hv[jj] = xsm[ci][jj*16+tx];
    #pragma unroll
    for (int ii = 0; ii < 4; ++ii) wv[ii] = wsm[ii*16+ty][ci];
    #pragma unroll
    for (int ii = 0; ii < 4; ++ii)
      #pragma unroll
      for (int jj = 0; jj < 4; ++jj) acc[ii][jj] += wv[ii]*hv[jj];
  }
  __syncthreads();
  float* pt_t = &xsm[0][0];
  #pragma unroll
  for (int ii = 0; ii < 4; ++ii)
    #pragma unroll
    for (int jj = 0; jj < 4; ++jj)
      pt_t[(jj*16+tx)*65 + ii*16+ty] = acc[ii][jj];
  __syncthreads();
  for (int i = t; i < 4096; i += 256){
    int px = i >> 6, co_l = i & 63;
    omT[((size_t)(b*128 + y)*130 + x0 + px + 1)*128 + cb*64 + co_l] = f2bs(pt_t[px*65 + co_l]);
  }
}

// ============ K12: transposed 3x3 stride-2 conv 128->64 (MFMA, parity decomp) ============
__global__ __launch_bounds__(256) void k_upm(const short* __restrict__ omT, const short* __restrict__ wup,
      float* __restrict__ out){
  const int blk = blockIdx.x;
  const int b = blk >> 7, y = blk & 127;
  const int t = threadIdx.x, lane = t & 63, wave = t >> 6;
  const int quad = lane >> 4, l15 = lane & 15;
  const int m0w = wave*32;
  __shared__ __align__(16) char smem[53504];
  short* asp = (short*)smem;
  short* bsp = (short*)(smem + 16640);
  float* ptile = (float*)smem;
  const int PAR[9] = {3,2,3, 1,0,1, 3,2,3};
  const int ROW[9] = {0,0,0, 0,0,0, 1,1,1};
  const int SHF[9] = {0,0,1, 0,0,1, 0,0,1};
  f32x4 acc[4][2][4];
  #pragma unroll
  for (int p = 0; p < 4; ++p)
    #pragma unroll
    for (int mt = 0; mt < 2; ++mt)
      #pragma unroll
      for (int nt = 0; nt < 4; ++nt) acc[p][mt][nt] = (f32x4){0.f,0.f,0.f,0.f};
  for (int ch = 0; ch < 4; ++ch){
    const int ci0 = ch*32;
    __syncthreads();
    for (int i = t; i < 1040; i += 256){
      int rw = (i >= 520), j = i - rw*520;
      int col = j >> 2, cg = j & 3;
      uint4 val = {0,0,0,0};
      if (y + rw < 128)
        val = *(const uint4*)&omT[((size_t)(b*128 + y + rw)*130 + col)*128 + ci0 + cg*8];
      *(uint4*)&asp[((rw*130 + col)*32) + cg*8] = val;
    }
    for (int i = t; i < 2304; i += 256){
      int rr = i >> 2, cg = i & 3;
      *(uint4*)&bsp[rr*32 + cg*8] = *(const uint4*)&wup[rr*128 + ci0 + cg*8];
    }
    __syncthreads();
    #pragma unroll
    for (int k = 0; k < 9; ++k){
      const int pr = PAR[k], rw = ROW[k], sh = SHF[k];
      if (rw && y == 127) continue;
      short8 af[2], bf[4];
      #pragma unroll
      for (int mt = 0; mt < 2; ++mt)
        af[mt] = *(const short8*)&asp[((rw*130 + m0w + mt*16 + l15 + 1 + sh))*32 + quad*8];
      #pragma unroll
      for (int nt = 0; nt < 4; ++nt)
        bf[nt] = *(const short8*)&bsp[(k*64 + nt*16 + l15)*32 + quad*8];
      #pragma unroll
      for (int mt = 0; mt < 2; ++mt)
        #pragma unroll
        for (int nt = 0; nt < 4; ++nt)
          acc[pr][mt][nt] = __builtin_amdgcn_mfma_f32_16x16x32_bf16(af[mt], bf[nt], acc[pr][mt][nt], 0, 0, 0);
    }
  }
  #pragma unroll
  for (int p = 0; p < 4; ++p){
    __syncthreads();
    #pragma unroll
    for (int mt = 0; mt < 2; ++mt)
      #pragma unroll
      for (int nt = 0; nt < 4; ++nt){
        int co = nt*16 + l15;
        int xb = m0w + mt*16 + quad*4;
        #pragma unroll
        for (int r = 0; r < 4; ++r)
          ptile[co*132 + xb + r] = acc[p][mt][nt][r];
      }
    __syncthreads();
    int py = p >> 1, px = p & 1;
    int Y = 2*y + py;
    for (int i = t; i < 8192; i += 256){
      int co = i >> 7, xx = i & 127;
      out[((size_t)(b*64 + co)*256 + Y)*256 + 2*xx + px] = ptile[co*132 + xx];
    }
  }
}

extern "C" void kernel_launch(void* const* d_in, const int* in_sizes, int n_in,
                              void* d_out, int out_size, void* d_ws, size_t ws_size,
                              hipStream_t stream) {
  const float* x       = (const float*)d_in[0];
  const float* conv_w  = (const float*)d_in[1];
  const float* bn1_g   = (const float*)d_in[2];
  const float* bn1_b   = (const float*)d_in[3];
  const float* qkv_w   = (const float*)d_in[4];
  const float* loc1_w  = (const float*)d_in[5];
  const float* loc1_g  = (const float*)d_in[6];
  const float* loc1_b  = (const float*)d_in[7];
  const float* loc2_w  = (const float*)d_in[8];
  const float* loc2_g  = (const float*)d_in[9];
  const float* loc2_b  = (const float*)d_in[10];
  const float* rel_t   = (const float*)d_in[11];
  const float* cw_w    = (const float*)d_in[12];
  const float* cw_g    = (const float*)d_in[13];
  const float* cw_b    = (const float*)d_in[14];
  const float* hc_w    = (const float*)d_in[15];
  const float* hc_g    = (const float*)d_in[16];
  const float* hc_b    = (const float*)d_in[17];
  const float* hw_w    = (const float*)d_in[18];
  const float* hw_g    = (const float*)d_in[19];
  const float* hw_b    = (const float*)d_in[20];
  const float* proj_dw = (const float*)d_in[21];
  const float* proj_g  = (const float*)d_in[22];
  const float* proj_b  = (const float*)d_in[23];
  const float* proj_pw = (const float*)d_in[24];
  const float* up_w    = (const float*)d_in[25];

  char* ws = (char*)d_ws;
  float* h      = (float*)(ws + OFF_H);
  float* local  = (float*)(ws + OFF_LOCAL);
  bf16*  q      = (bf16*)(ws + OFF_Q);
  bf16*  k      = (bf16*)(ws + OFF_K);
  bf16*  v      = (bf16*)(ws + OFF_V);
  bf16*  dots   = (bf16*)(ws + OFF_DOTS);
  bf16*  z1     = (bf16*)(ws + OFF_Z1);
  bf16*  z2     = (bf16*)(ws + OFF_Z2);
  bf16*  z3     = (bf16*)(ws + OFF_Z3);
  float* G1     = (float*)(ws + OFF_G1);
  float* G2     = (float*)(ws + OFF_G2);
  float* G3     = (float*)(ws + OFF_G3);
  short* xT     = (short*)(ws + OFF_DOTS);
  short* hT     = (short*)(ws + OFF_HT);
  short* w2bf   = (short*)(ws + OFF_Z1);
  short* wloc   = (short*)(ws + OFF_Z2);
  short* wqkv   = (short*)(ws + OFF_Z3);
  short* omT    = (short*)(ws + OFF_DOTS);
  short* wup    = (short*)(ws + OFF_Z1);
  float* o_img  = (float*)(ws + OFF_Q);
  float* Fh     = (float*)(ws + OFF_DOTS);
  float* Fw     = (float*)(ws + OFF_DOTS + 8388608);
  float* comb   = (float*)(ws + OFF_H);
  float* proj1  = (float*)(ws + OFF_LOCAL);
  float* outp   = (float*)d_out;

  dim3 blk2(16,16);
  k_wrep <<<1152, 256, 0, stream>>>(conv_w, w2bf);
  k_xzero<<<1024, 256, 0, stream>>>(xT);
  k_xrep <<<8192, 256, 0, stream>>>(x, xT);
  k_conv1m<<<512, 256, 0, stream>>>(xT, w2bf, bn1_g, bn1_b, h);
  k_lwrep<<<576, 256, 0, stream>>>(loc1_w, loc1_g, loc2_w, loc2_g, wloc);
  k_hzero<<<512, 256, 0, stream>>>(hT);
  k_hrep <<<4096, 256, 0, stream>>>(h, hT);
  k_localm<<<512, 256, 0, stream>>>(hT, wloc, loc1_b, loc2_b, local);
  k_wqkvrep<<<192, 256, 0, stream>>>(qkv_w, wqkv);
  k_qkvm <<<dim3(512,3), 256, 0, stream>>>(hT, wqkv, q, k, v);
  k_dots <<<dim3(NWIN,8), 256, 0, stream>>>(q, k, rel_t, dots);
  k_z1   <<<2048, 256, 0, stream>>>(dots, z1);
  k_z2   <<<2048, 256, 0, stream>>>(dots, z2);
  k_z3   <<<16384, 256, 0, stream>>>(dots, z3);
  k_gate <<<dim3(NWIN,2),  256, 0, stream>>>(z1, cw_w, cw_g, cw_b, G1, 8, 64);
  k_gate <<<dim3(NWIN,2),  256, 0, stream>>>(z2, hc_w, hc_g, hc_b, G2, 64, 8);
  k_gate3<<<NWIN, 256, 0, stream>>>(z3, hw_w, hw_g, hw_b, G3);
  k_attn <<<dim3(NWIN,8), 256, 0, stream>>>(dots, G1, G2, G3, v, o_img);
  k_fw   <<<8192, 256, 0, stream>>>(o_img, Fw);
  k_fh   <<<8192, 256, 0, stream>>>(o_img, Fh);
  k_comb <<<512, 256, 0, stream>>>(o_img, Fh, Fw, local, comb);
  k_dw   <<<dim3(8,8,BB*128), blk2, 0, stream>>>(comb, proj_dw, proj_g, proj_b, proj1);
  k_omzero<<<512, 256, 0, stream>>>(omT);
  k_uwrep<<<288, 256, 0, stream>>>(up_w, wup);
  k_pw   <<<dim3(1024,2), blk2, 0, stream>>>(proj1, proj_pw, omT);
  k_upm  <<<512, 256, 0, stream>>>(omT, wup, outp);
}

// Round 8
// 698.135 us; speedup vs baseline: 7.2036x; 1.0539x over previous
//
#include <hip/hip_runtime.h>
#include <hip/hip_bf16.h>

typedef __hip_bfloat16 bf16;
typedef __attribute__((ext_vector_type(8))) short short8;
typedef __attribute__((ext_vector_type(4))) float f32x4;

#define DEV __device__ __forceinline__
DEV float b2f(bf16 v){ return __bfloat162float(v); }
DEV bf16 f2b(float v){ return __float2bfloat16(v); }
DEV short f2bs(float v){ union{ bf16 b; short s; } u; u.b = __float2bfloat16(v); return u.s; }
DEV float sigm(float x){ return 1.f/(1.f + expf(-x)); }

// ---- problem constants ----
#define BB 4
#define CIN 256
#define MID 128
#define COUT 64
#define HH 128
#define WW 128
#define WS 8
#define HEADS 8
#define HD 16
#define NTOK 64
#define NWIN 1024

// ---- workspace layout (bytes) ----
static const size_t OFF_H     = 0;
static const size_t OFF_LOCAL = 33554432;
static const size_t OFF_Q     = 67108864;
static const size_t OFF_K     = 83886080;
static const size_t OFF_V     = 100663296;
static const size_t OFF_DOTS  = 117440512;
static const size_t OFF_Z1    = 184549376;
static const size_t OFF_Z2    = 186646528;
static const size_t OFF_Z3    = 188743680;
static const size_t OFF_G1    = 205520896;
static const size_t OFF_G2    = 207618048;
static const size_t OFF_G3    = 209715200;
static const size_t OFF_HT    = OFF_DOTS + 34078720;

// ============ P1: repack conv_w -> w2[kk][co][ci] bf16 ============
__global__ __launch_bounds__(256) void k_wrep(const float* __restrict__ w, short* __restrict__ w2){
  int i = blockIdx.x*256 + threadIdx.x;
  int ci = i & 255, co = (i >> 8) & 127, kk = i >> 15;
  w2[i] = f2bs(w[(co*256 + ci)*9 + kk]);
}

// ============ P2: zero pad columns of xT ============
__global__ void k_xzero(short* __restrict__ xT){
  int t = blockIdx.x*256 + threadIdx.x;
  int ci = t & 255, side = (t >> 8) & 1, row = t >> 9;
  int cpad = side ? 129 : 0;
  xT[((size_t)row*130 + cpad)*256 + ci] = 0;
}

// ============ P3: x NCHW fp32 -> xT[b][r][c+1][ci] bf16 ============
__global__ __launch_bounds__(256) void k_xrep(const float* __restrict__ x, short* __restrict__ xT){
  const int blk = blockIdx.x;
  const int cgrp = blk & 1, cig = (blk >> 1) & 7, r = (blk >> 4) & 127, b = blk >> 11;
  const int c0 = cgrp*64, ci0 = cig*32;
  __shared__ float lds[32][65];
  const int t = threadIdx.x;
  for (int i = t; i < 2048; i += 256){
    int lci = i >> 6, c = i & 63;
    lds[lci][c] = x[((size_t)(b*256 + ci0 + lci)*128 + r)*128 + c0 + c];
  }
  __syncthreads();
  for (int i = t; i < 2048; i += 256){
    int lci = i & 31, cc = i >> 5;
    xT[((size_t)(b*128 + r)*130 + c0 + cc + 1)*256 + ci0 + lci] = f2bs(lds[lci][cc]);
  }
}

// ============ K1: conv3x3 256->128 + bn + relu  (MFMA implicit GEMM) ============
__global__ __launch_bounds__(256) void k_conv1m(const short* __restrict__ xT, const short* __restrict__ w2,
      const float* __restrict__ gg, const float* __restrict__ bb, float* __restrict__ h){
  const int blk = blockIdx.x;
  const int b = blk >> 7, y = blk & 127;
  const int t = threadIdx.x, lane = t & 63, wave = t >> 6;
  const int quad = lane >> 4, l15 = lane & 15;
  const int m0 = (wave >> 1)*64, n0 = (wave & 1)*64;
  __shared__ short as[130][32];
  __shared__ short bs[384][32];
  f32x4 acc[4][4];
  #pragma unroll
  for (int i = 0; i < 4; ++i)
    #pragma unroll
    for (int j = 0; j < 4; ++j) acc[i][j] = (f32x4){0.f,0.f,0.f,0.f};
  for (int ky = 0; ky < 3; ++ky){
    int r = y + ky - 1;
    if ((unsigned)r >= 128u) continue;
    const short* xrow = xT + (size_t)(b*128 + r)*130*256;
    const short* wk   = w2 + (size_t)ky*384*256;
    for (int ch = 0; ch < 8; ++ch){
      const int ci0 = ch*32;
      __syncthreads();
      for (int i = t; i < 520; i += 256){
        int col = i >> 2, cg = i & 3;
        *(uint4*)&as[col][cg*8] = *(const uint4*)&xrow[col*256 + ci0 + cg*8];
      }
      for (int i = t; i < 1536; i += 256){
        int rr = i >> 2, cg = i & 3;
        *(uint4*)&bs[rr][cg*8] = *(const uint4*)&wk[rr*256 + ci0 + cg*8];
      }
      __syncthreads();
      #pragma unroll
      for (int kx = 0; kx < 3; ++kx){
        short8 af[4], bf[4];
        #pragma unroll
        for (int mt = 0; mt < 4; ++mt)
          af[mt] = *(const short8*)&as[m0 + mt*16 + l15 + kx][quad*8];
        #pragma unroll
        for (int nt = 0; nt < 4; ++nt)
          bf[nt] = *(const short8*)&bs[kx*128 + n0 + nt*16 + l15][quad*8];
        #pragma unroll
        for (int mt = 0; mt < 4; ++mt)
          #pragma unroll
          for (int nt = 0; nt < 4; ++nt)
            acc[mt][nt] = __builtin_amdgcn_mfma_f32_16x16x32_bf16(af[mt], bf[nt], acc[mt][nt], 0, 0, 0);
      }
    }
  }
  #pragma unroll
  for (int nt = 0; nt < 4; ++nt){
    int co = n0 + nt*16 + l15;
    float g = gg[co], bia = bb[co];
    #pragma unroll
    for (int mt = 0; mt < 4; ++mt){
      int xb = m0 + mt*16 + quad*4;
      float4 o4;
      o4.x = fmaxf(acc[mt][nt][0]*g + bia, 0.f);
      o4.y = fmaxf(acc[mt][nt][1]*g + bia, 0.f);
      o4.z = fmaxf(acc[mt][nt][2]*g + bia, 0.f);
      o4.w = fmaxf(acc[mt][nt][3]*g + bia, 0.f);
      *(float4*)&h[((size_t)(b*128 + co)*128 + y)*128 + xb] = o4;
    }
  }
}

// ============ P4: zero pad columns of hT ============
__global__ void k_hzero(short* __restrict__ hT){
  int t = blockIdx.x*256 + threadIdx.x;
  int ci = t & 127, side = (t >> 7) & 1, row = t >> 8;
  int cpad = side ? 129 : 0;
  hT[((size_t)row*130 + cpad)*128 + ci] = 0;
}

// ============ P5: h NCHW fp32 -> hT[b][r][c+1][ci] bf16 ============
__global__ __launch_bounds__(256) void k_hrep(const float* __restrict__ h, short* __restrict__ hT){
  const int blk = blockIdx.x;
  const int cgrp = blk & 1, cig = (blk >> 1) & 3, r = (blk >> 3) & 127, b = blk >> 10;
  const int c0 = cgrp*64, ci0 = cig*32;
  __shared__ float lds[32][65];
  const int t = threadIdx.x;
  for (int i = t; i < 2048; i += 256){
    int lci = i >> 6, c = i & 63;
    lds[lci][c] = h[((size_t)(b*128 + ci0 + lci)*128 + r)*128 + c0 + c];
  }
  __syncthreads();
  for (int i = t; i < 2048; i += 256){
    int lci = i & 31, cc = i >> 5;
    hT[((size_t)(b*128 + r)*130 + c0 + cc + 1)*128 + ci0 + lci] = f2bs(lds[lci][cc]);
  }
}

// ============ P6: fold local weights: wloc[ky][kx*128+co][ci] bf16 ============
__global__ __launch_bounds__(256) void k_lwrep(const float* __restrict__ w1, const float* __restrict__ g1,
      const float* __restrict__ w2, const float* __restrict__ g2, short* __restrict__ wloc){
  int i = blockIdx.x*256 + threadIdx.x;
  int ci = i & 127, row = (i >> 7) % 384, ky = i / 49152;
  int kx = row >> 7, co = row & 127;
  float v = w1[(co*128 + ci)*9 + ky*3 + kx] * g1[co];
  if (ky == 1 && kx == 1) v += w2[co*128 + ci] * g2[co];
  wloc[i] = f2bs(v);
}

// ============ K2: local conv (folded 3x3+1x1)  (MFMA implicit GEMM) ============
__global__ __launch_bounds__(256) void k_localm(const short* __restrict__ hT, const short* __restrict__ wloc,
      const float* __restrict__ b1, const float* __restrict__ b2, float* __restrict__ out){
  const int blk = blockIdx.x;
  const int b = blk >> 7, y = blk & 127;
  const int t = threadIdx.x, lane = t & 63, wave = t >> 6;
  const int quad = lane >> 4, l15 = lane & 15;
  const int m0 = (wave >> 1)*64, n0 = (wave & 1)*64;
  __shared__ short as[130][32];
  __shared__ short bs[384][32];
  f32x4 acc[4][4];
  #pragma unroll
  for (int i = 0; i < 4; ++i)
    #pragma unroll
    for (int j = 0; j < 4; ++j) acc[i][j] = (f32x4){0.f,0.f,0.f,0.f};
  for (int ky = 0; ky < 3; ++ky){
    int r = y + ky - 1;
    if ((unsigned)r >= 128u) continue;
    const short* xrow = hT + (size_t)(b*128 + r)*130*128;
    const short* wk   = wloc + (size_t)ky*384*128;
    for (int ch = 0; ch < 4; ++ch){
      const int ci0 = ch*32;
      __syncthreads();
      for (int i = t; i < 520; i += 256){
        int col = i >> 2, cg = i & 3;
        *(uint4*)&as[col][cg*8] = *(const uint4*)&xrow[col*128 + ci0 + cg*8];
      }
      for (int i = t; i < 1536; i += 256){
        int rr = i >> 2, cg = i & 3;
        *(uint4*)&bs[rr][cg*8] = *(const uint4*)&wk[rr*128 + ci0 + cg*8];
      }
      __syncthreads();
      #pragma unroll
      for (int kx = 0; kx < 3; ++kx){
        short8 af[4], bf[4];
        #pragma unroll
        for (int mt = 0; mt < 4; ++mt)
          af[mt] = *(const short8*)&as[m0 + mt*16 + l15 + kx][quad*8];
        #pragma unroll
        for (int nt = 0; nt < 4; ++nt)
          bf[nt] = *(const short8*)&bs[kx*128 + n0 + nt*16 + l15][quad*8];
        #pragma unroll
        for (int mt = 0; mt < 4; ++mt)
          #pragma unroll
          for (int nt = 0; nt < 4; ++nt)
            acc[mt][nt] = __builtin_amdgcn_mfma_f32_16x16x32_bf16(af[mt], bf[nt], acc[mt][nt], 0, 0, 0);
      }
    }
  }
  #pragma unroll
  for (int nt = 0; nt < 4; ++nt){
    int co = n0 + nt*16 + l15;
    float bia = b1[co] + b2[co];
    #pragma unroll
    for (int mt = 0; mt < 4; ++mt){
      int xb = m0 + mt*16 + quad*4;
      float4 o4;
      o4.x = acc[mt][nt][0] + bia;
      o4.y = acc[mt][nt][1] + bia;
      o4.z = acc[mt][nt][2] + bia;
      o4.w = acc[mt][nt][3] + bia;
      *(float4*)&out[((size_t)(b*128 + co)*128 + y)*128 + xb] = o4;
    }
  }
}

// ============ P9: qkv_w fp32 -> bf16 [oc][ci] ============
__global__ __launch_bounds__(256) void k_wqkvrep(const float* __restrict__ w, short* __restrict__ wqkv){
  int i = blockIdx.x*256 + threadIdx.x;
  wqkv[i] = f2bs(w[i]);
}

// ============ K3: qkv 1x1 conv (MFMA GEMM over hT) -> windowed q,k,v ============
__global__ __launch_bounds__(256) void k_qkvm(const short* __restrict__ hT, const short* __restrict__ wqkv,
      bf16* __restrict__ q, bf16* __restrict__ k, bf16* __restrict__ v){
  const int blk = blockIdx.x, ocg = blockIdx.y;
  const int b = blk >> 7, y = blk & 127;
  const int t = threadIdx.x, lane = t & 63, wave = t >> 6;
  const int quad = lane >> 4, l15 = lane & 15;
  const int m0 = (wave >> 1)*64, n0 = (wave & 1)*64;
  __shared__ short as[128][32];
  __shared__ short bs[128][32];
  const short* xrow = hT + ((size_t)(b*128 + y)*130 + 1)*128;
  const short* wk   = wqkv + (size_t)ocg*128*128;
  f32x4 acc[4][4];
  #pragma unroll
  for (int i = 0; i < 4; ++i)
    #pragma unroll
    for (int j = 0; j < 4; ++j) acc[i][j] = (f32x4){0.f,0.f,0.f,0.f};
  for (int ch = 0; ch < 4; ++ch){
    const int ci0 = ch*32;
    __syncthreads();
    for (int i = t; i < 512; i += 256){
      int col = i >> 2, cg = i & 3;
      *(uint4*)&as[col][cg*8] = *(const uint4*)&xrow[col*128 + ci0 + cg*8];
    }
    for (int i = t; i < 512; i += 256){
      int rr = i >> 2, cg = i & 3;
      *(uint4*)&bs[rr][cg*8] = *(const uint4*)&wk[rr*128 + ci0 + cg*8];
    }
    __syncthreads();
    short8 af[4], bf[4];
    #pragma unroll
    for (int mt = 0; mt < 4; ++mt)
      af[mt] = *(const short8*)&as[m0 + mt*16 + l15][quad*8];
    #pragma unroll
    for (int nt = 0; nt < 4; ++nt)
      bf[nt] = *(const short8*)&bs[n0 + nt*16 + l15][quad*8];
    #pragma unroll
    for (int mt = 0; mt < 4; ++mt)
      #pragma unroll
      for (int nt = 0; nt < 4; ++nt)
        acc[mt][nt] = __builtin_amdgcn_mfma_f32_16x16x32_bf16(af[mt], bf[nt], acc[mt][nt], 0, 0, 0);
  }
  bf16* dst = (ocg == 0) ? q : (ocg == 1) ? k : v;
  const int iy = y & 7, hy = y >> 3;
  #pragma unroll
  for (int nt = 0; nt < 4; ++nt){
    int co = n0 + nt*16 + l15;
    int head = co >> 4, d = co & 15;
    #pragma unroll
    for (int mt = 0; mt < 4; ++mt){
      int xb = m0 + mt*16 + quad*4;
      #pragma unroll
      for (int r = 0; r < 4; ++r){
        int x = xb + r;
        int bw = b*256 + hy*16 + (x >> 3);
        int n = iy*8 + (x & 7);
        dst[((size_t)(bw*8+head)*64 + n)*16 + d] = f2b(acc[mt][nt][r]);
      }
    }
  }
}

// ============ K4: dots = q.k^T * 0.25 + relpos bias ============
__global__ __launch_bounds__(256) void k_dots(const bf16* __restrict__ q, const bf16* __restrict__ kk,
      const float* __restrict__ rel, bf16* __restrict__ dots){
  const int bw = blockIdx.x, hd = blockIdx.y;
  __shared__ bf16 qs[64][16], ks[64][16];
  const int t = threadIdx.x;
  const size_t base = (size_t)(bw*8+hd)*1024;
  for (int i = t; i < 1024; i += 256){ qs[i>>4][i&15] = q[base + i]; ks[i>>4][i&15] = kk[base + i]; }
  __syncthreads();
  const int n = t >> 2, jm = t & 3;
  float qr[16];
  #pragma unroll
  for (int d = 0; d < 16; ++d) qr[d] = b2f(qs[n][d]);
  const int ny = n >> 3, nx = n & 7;
  for (int mm = 0; mm < 16; ++mm){
    int m = jm*16 + mm;
    float a = 0.f;
    #pragma unroll
    for (int d = 0; d < 16; ++d) a += qr[d]*b2f(ks[m][d]);
    int my = m >> 3, mx = m & 7;
    int ridx = (ny - my + 7)*15 + (nx - mx + 7);
    float bias = rel[ridx*8 + hd];
    dots[base*4 + (size_t)n*64 + m] = f2b(a*0.25f + bias);
  }
}

// ============ K5: axis reductions ============
__global__ void k_z1(const bf16* __restrict__ dots, bf16* __restrict__ z){
  int t = blockIdx.x*256 + threadIdx.x;
  int bw = t >> 9, r = t & 511; int hd = r >> 6, m = r & 63;
  const bf16* p = dots + (size_t)(bw*8+hd)*4096 + m;
  float mx = -1e30f, sm = 0.f;
  for (int n = 0; n < 64; ++n){ float v = b2f(p[n*64]); mx = fmaxf(mx,v); sm += v; }
  z[(size_t)bw*1024 + hd*64 + m]       = f2b(mx);
  z[(size_t)bw*1024 + 512 + hd*64 + m] = f2b(sm*(1.f/64.f));
}
__global__ void k_z2(const bf16* __restrict__ dots, bf16* __restrict__ z){
  int t = blockIdx.x*256 + threadIdx.x;
  int bw = t >> 9, r = t & 511; int n = r >> 3, hd = r & 7;
  const bf16* p = dots + ((size_t)(bw*8+hd)*64 + n)*64;
  float mx = -1e30f, sm = 0.f;
  for (int m = 0; m < 64; ++m){ float v = b2f(p[m]); mx = fmaxf(mx,v); sm += v; }
  z[(size_t)bw*1024 + n*8 + hd]       = f2b(mx);
  z[(size_t)bw*1024 + 512 + n*8 + hd] = f2b(sm*(1.f/64.f));
}
__global__ void k_z3(const bf16* __restrict__ dots, bf16* __restrict__ z){
  int t = blockIdx.x*256 + threadIdx.x;
  int bw = t >> 12, r = t & 4095;
  const bf16* p = dots + (size_t)bw*32768 + r;
  float mx = -1e30f, sm = 0.f;
  for (int hd = 0; hd < 8; ++hd){ float v = b2f(p[hd*4096]); mx = fmaxf(mx,v); sm += v; }
  z[(size_t)bw*8192 + r]        = f2b(mx);
  z[(size_t)bw*8192 + 4096 + r] = f2b(sm*0.125f);
}

// ============ K6: generic 7x7 2->1 conv + bn + sigmoid (small gates) ============
__global__ __launch_bounds__(256) void k_gate(const bf16* __restrict__ z, const float* __restrict__ w,
      const float* __restrict__ gg, const float* __restrict__ bb, float* __restrict__ G, int R, int C){
  __shared__ float wsm[98];
  const int t = threadIdx.x;
  if (t < 98) wsm[t] = w[t];
  __syncthreads();
  const int bw = blockIdx.x;
  int p = blockIdx.y*256 + t; if (p >= R*C) return;
  int y = p / C, x = p - y*C;
  float acc = 0.f;
  for (int c = 0; c < 2; ++c)
    for (int ky = 0; ky < 7; ++ky){
      int iy = y + ky - 3; if ((unsigned)iy >= (unsigned)R) continue;
      for (int kx = 0; kx < 7; ++kx){
        int ix = x + kx - 3; if ((unsigned)ix >= (unsigned)C) continue;
        acc += b2f(z[((size_t)(bw*2+c)*R + iy)*C + ix]) * wsm[c*49 + ky*7 + kx];
      }
    }
  G[(size_t)bw*R*C + p] = sigm(acc*gg[0] + bb[0]);
}

// ============ K6b: specialized 64x64 gate (G3) ============
__global__ __launch_bounds__(256) void k_gate3(const bf16* __restrict__ z, const float* __restrict__ w,
      const float* __restrict__ gg, const float* __restrict__ bb, float* __restrict__ G){
  const int bw = blockIdx.x;
  __shared__ float pad[2][70][72];
  __shared__ float wsm[98];
  const int t = threadIdx.x;
  if (t < 98) wsm[t] = w[t];
  for (int i = t; i < 2*70*70; i += 256){
    int c = i / 4900, r = i % 4900;
    int py = r / 70, px = r % 70;
    int y = py - 3, x = px - 3;
    float v = 0.f;
    if ((unsigned)y < 64u && (unsigned)x < 64u)
      v = b2f(z[(size_t)bw*8192 + c*4096 + y*64 + x]);
    pad[c][py][px] = v;
  }
  __syncthreads();
  const int tx = t & 15, ty = t >> 4;
  const int x0 = tx*4, y0 = ty*4;
  float acc[4][4] = {};
  #pragma unroll
  for (int c = 0; c < 2; ++c){
    float wr[49];
    #pragma unroll
    for (int kk = 0; kk < 49; ++kk) wr[kk] = wsm[c*49 + kk];
    #pragma unroll
    for (int iy = 0; iy < 10; ++iy){
      float row[10];
      #pragma unroll
      for (int j = 0; j < 10; ++j) row[j] = pad[c][y0+iy][x0+j];
      #pragma unroll
      for (int dy = 0; dy < 4; ++dy){
        const int ky = iy - dy;
        if (ky < 0 || ky > 6) continue;
        #pragma unroll
        for (int kx = 0; kx < 7; ++kx){
          float wv = wr[ky*7 + kx];
          #pragma unroll
          for (int dx = 0; dx < 4; ++dx)
            acc[dy][dx] += wv * row[dx + kx];
        }
      }
    }
  }
  float g0 = gg[0], b0 = bb[0];
  #pragma unroll
  for (int dy = 0; dy < 4; ++dy){
    float4 o4;
    o4.x = sigm(acc[dy][0]*g0 + b0);
    o4.y = sigm(acc[dy][1]*g0 + b0);
    o4.z = sigm(acc[dy][2]*g0 + b0);
    o4.w = sigm(acc[dy][3]*g0 + b0);
    *(float4*)&G[(size_t)bw*4096 + (y0+dy)*64 + x0] = o4;
  }
}

// ============ K7: gated softmax + attn@v -> o ============
__global__ __launch_bounds__(256) void k_attn(const bf16* __restrict__ dots, const float* __restrict__ G1,
      const float* __restrict__ G2, const float* __restrict__ G3, const bf16* __restrict__ v,
      float* __restrict__ o){
  const int bw = blockIdx.x, hd = blockIdx.y;
  const int b = bw >> 8, wy = (bw >> 4) & 15, wx = bw & 15;
  __shared__ float attn[64][65];
  __shared__ bf16 vs[64][16];
  __shared__ float invTot[64];
  const int t = threadIdx.x;
  for (int i = t; i < 1024; i += 256) vs[i>>4][i&15] = v[(size_t)(bw*8+hd)*1024 + i];
  const int n = t >> 2, j = t & 3;
  float g2v = G2[(size_t)bw*512 + n*8 + hd];
  const bf16* dp = dots + ((size_t)(bw*8+hd)*64 + n)*64 + j*16;
  const float* g1p = G1 + (size_t)bw*512 + hd*64 + j*16;
  const float* g3p = G3 + (size_t)bw*4096 + n*64 + j*16;
  float e[16]; float mx = -1e30f;
  #pragma unroll
  for (int m = 0; m < 16; ++m){
    float dv = b2f(dp[m]) * ((g1p[m] + g2v + g3p[m]) * (1.f/3.f));
    e[m] = dv; mx = fmaxf(mx, dv);
  }
  mx = fmaxf(mx, __shfl_xor(mx, 1, 4));
  mx = fmaxf(mx, __shfl_xor(mx, 2, 4));
  float s = 0.f;
  #pragma unroll
  for (int m = 0; m < 16; ++m){ float ev = expf(e[m]-mx); e[m] = ev; s += ev; }
  s += __shfl_xor(s, 1, 4);
  s += __shfl_xor(s, 2, 4);
  #pragma unroll
  for (int m = 0; m < 16; ++m) attn[n][j*16+m] = e[m];
  if (j == 0) invTot[n] = 1.f/s;
  __syncthreads();
  const int dg = j;
  float acc[4] = {0.f,0.f,0.f,0.f};
  for (int m = 0; m < 64; ++m){
    float a = attn[n][m];
    #pragma unroll
    for (int dd = 0; dd < 4; ++dd) acc[dd] += a * b2f(vs[m][dg*4+dd]);
  }
  float it = invTot[n];
  int y = wy*8 + (n>>3), x = wx*8 + (n&7);
  #pragma unroll
  for (int dd = 0; dd < 4; ++dd){
    int c = hd*16 + dg*4 + dd;
    o[((size_t)(b*128+c)*128 + y)*128 + x] = acc[dd]*it;
  }
}

// ============ K8: Fh / Fw axial gates ============
__global__ void k_fw(const float* __restrict__ o, float* __restrict__ Fw){
  int t = blockIdx.x*256 + threadIdx.x; if (t >= 4*128*32*128) return;
  int x = t & 127, kk = (t>>7) & 31, bc = t >> 12;
  const float* p = o + ((size_t)bc*128 + kk*4)*128 + x;
  float mx = -1e30f, sm = 0.f;
  #pragma unroll
  for (int r = 0; r < 4; ++r){ float v = p[r*128]; mx = fmaxf(mx,v); sm += v; }
  Fw[t] = sigm(sm*0.25f + mx);
}
__global__ void k_fh(const float* __restrict__ o, float* __restrict__ Fh){
  int t = blockIdx.x*256 + threadIdx.x; if (t >= 4*128*128*32) return;
  int kk = t & 31, y = (t>>5) & 127, bc = t >> 12;
  const float* p = o + ((size_t)bc*128 + y)*128 + kk*4;
  float mx = -1e30f, sm = 0.f;
  #pragma unroll
  for (int r = 0; r < 4; ++r){ float v = p[r]; mx = fmaxf(mx,v); sm += v; }
  Fh[t] = sigm(sm*0.25f + mx);
}

// ============ K9: comb = o * (Fh@Fw) + local ============
__global__ __launch_bounds__(256) void k_comb(const float* __restrict__ o, const float* __restrict__ Fh,
      const float* __restrict__ Fw, const float* __restrict__ local, float* __restrict__ comb){
  const int bc = blockIdx.x;
  __shared__ float fh[128][33];
  __shared__ float fw[32][129];
  const int t = threadIdx.x;
  for (int i = t; i < 4096; i += 256) fh[i>>5][i&31]  = Fh[(size_t)bc*4096 + i];
  for (int i = t; i < 4096; i += 256) fw[i>>7][i&127] = Fw[(size_t)bc*4096 + i];
  __syncthreads();
  for (int i = t; i < 16384; i += 256){
    int y = i >> 7, x = i & 127;
    float g = 0.f;
    #pragma unroll
    for (int kk = 0; kk < 32; ++kk) g += fh[y][kk]*fw[kk][x];
    size_t idx = (size_t)bc*16384 + i;
    comb[idx] = o[idx]*g + local[idx];
  }
}

// ============ K10: reflect-pad + depthwise 8x8 + bn (register-tiled) ============
// block = (ytile, bz): 128x16 output strip of one (b,c). Each thread: 2y x 4x patch.
__global__ __launch_bounds__(256) void k_dw(const float* __restrict__ comb, const float* __restrict__ dw,
      const float* __restrict__ gg, const float* __restrict__ bb, float* __restrict__ out){
  const int bz = blockIdx.y;           // b*128 + c
  const int oy0 = blockIdx.x*16;
  const int c = bz & 127;
  __shared__ float xs[23][136];
  __shared__ float wsm[64];
  const int t = threadIdx.x;
  if (t < 64) wsm[t] = dw[c*64 + t];
  for (int i = t; i < 23*135; i += 256){
    int py = i / 135, px = i - py*135;
    int gy = oy0 + py - 3, gx = px - 3;
    float v = 0.f;
    if (gy >= 0 && gy <= 128 && gx >= 0 && gx <= 128){
      int yy = (gy==128)?126:gy, xx = (gx==128)?126:gx;
      v = comb[((size_t)bz*128 + yy)*128 + xx];
    }
    xs[py][px] = v;
  }
  __syncthreads();
  const int tx = t & 31, ty = t >> 5;  // 32 x-groups(4 wide), 8 y-groups(2 tall)
  const int x0 = tx*4, y0 = ty*2;
  float acc[2][4] = {};
  #pragma unroll
  for (int iy = 0; iy < 9; ++iy){
    float row[12];
    *(float4*)&row[0] = *(const float4*)&xs[y0+iy][x0];
    *(float4*)&row[4] = *(const float4*)&xs[y0+iy][x0+4];
    *(float4*)&row[8] = *(const float4*)&xs[y0+iy][x0+8];
    #pragma unroll
    for (int dy = 0; dy < 2; ++dy){
      const int ky = iy - dy;
      if (ky < 0 || ky > 7) continue;   // compile-time after unroll
      #pragma unroll
      for (int kx = 0; kx < 8; ++kx){
        float wv = wsm[ky*8 + kx];
        #pragma unroll
        for (int dx = 0; dx < 4; ++dx)
          acc[dy][dx] += wv * row[dx + kx];
      }
    }
  }
  float g = gg[c], bi = bb[c];
  #pragma unroll
  for (int dy = 0; dy < 2; ++dy){
    float4 o4;
    o4.x = acc[dy][0]*g + bi;
    o4.y = acc[dy][1]*g + bi;
    o4.z = acc[dy][2]*g + bi;
    o4.w = acc[dy][3]*g + bi;
    *(float4*)&out[((size_t)bz*128 + oy0 + y0 + dy)*128 + x0] = o4;
  }
}

// ============ P7: zero omT halo cols ============
__global__ void k_omzero(short* __restrict__ omT){
  int t = blockIdx.x*256 + threadIdx.x;
  int ci = t & 127, side = (t >> 7) & 1, row = t >> 8;
  int cpad = side ? 129 : 0;
  omT[((size_t)row*130 + cpad)*128 + ci] = 0;
}

// ============ P8: repack up_w -> wup[tap][co][ci] bf16 ============
__global__ __launch_bounds__(256) void k_uwrep(const float* __restrict__ w, short* __restrict__ wup){
  int i = blockIdx.x*256 + threadIdx.x;
  int ci = i & 127, co = (i >> 7) & 63, tap = i >> 13;
  wup[i] = f2bs(w[(co*128 + ci)*9 + tap]);
}

// ============ K11: 1x1 proj conv 128->128 -> omT bf16 NHWC+halo ============
__global__ __launch_bounds__(256) void k_pw(const float* __restrict__ p1, const float* __restrict__ w,
      short* __restrict__ omT){
  const int pt = blockIdx.x, cb = blockIdx.y;
  const int P0 = pt*64; const int b = P0 >> 14; const int rem0 = P0 & 16383;
  const int y = rem0 >> 7, x0 = rem0 & 127;
  __shared__ float xsm[128][65];
  __shared__ float wsm[64][129];
  const int tx = threadIdx.x, ty = threadIdx.y, t = ty*16+tx;
  for (int i = t; i < 128*64; i += 256){
    int ci = i >> 6, p = i & 63;
    xsm[ci][p] = p1[(size_t)(b*128+ci)*16384 + rem0 + p];
  }
  for (int i = t; i < 64*128; i += 256){
    int co = i >> 7, ci = i & 127;
    wsm[co][ci] = w[(cb*64+co)*128 + ci];
  }
  __syncthreads();
  float acc[4][4] = {};
  for (int ci = 0; ci < 128; ++ci){
    float hv[4], wv[4];
    #pragma unroll
    for (int jj = 0; jj < 4; ++jj) hv[jj] = xsm[ci][jj*16+tx];
    #pragma unroll
    for (int ii = 0; ii < 4; ++ii) wv[ii] = wsm[ii*16+ty][ci];
    #pragma unroll
    for (int ii = 0; ii < 4; ++ii)
      #pragma unroll
      for (int jj = 0; jj < 4; ++jj) acc[ii][jj] += wv[ii]*hv[jj];
  }
  __syncthreads();
  float* pt_t = &xsm[0][0];
  #pragma unroll
  for (int ii = 0; ii < 4; ++ii)
    #pragma unroll
    for (int jj = 0; jj < 4; ++jj)
      pt_t[(jj*16+tx)*65 + ii*16+ty] = acc[ii][jj];
  __syncthreads();
  for (int i = t; i < 4096; i += 256){
    int px = i >> 6, co_l = i & 63;
    omT[((size_t)(b*128 + y)*130 + x0 + px + 1)*128 + cb*64 + co_l] = f2bs(pt_t[px*65 + co_l]);
  }
}

// ============ K12: transposed 3x3 stride-2 conv 128->64 (MFMA, parity decomp) ============
__global__ __launch_bounds__(256) void k_upm(const short* __restrict__ omT, const short* __restrict__ wup,
      float* __restrict__ out){
  const int blk = blockIdx.x;
  const int b = blk >> 7, y = blk & 127;
  const int t = threadIdx.x, lane = t & 63, wave = t >> 6;
  const int quad = lane >> 4, l15 = lane & 15;
  const int m0w = wave*32;
  __shared__ __align__(16) char smem[53504];
  short* asp = (short*)smem;
  short* bsp = (short*)(smem + 16640);
  float* ptile = (float*)smem;
  const int PAR[9] = {3,2,3, 1,0,1, 3,2,3};
  const int ROW[9] = {0,0,0, 0,0,0, 1,1,1};
  const int SHF[9] = {0,0,1, 0,0,1, 0,0,1};
  f32x4 acc[4][2][4];
  #pragma unroll
  for (int p = 0; p < 4; ++p)
    #pragma unroll
    for (int mt = 0; mt < 2; ++mt)
      #pragma unroll
      for (int nt = 0; nt < 4; ++nt) acc[p][mt][nt] = (f32x4){0.f,0.f,0.f,0.f};
  for (int ch = 0; ch < 4; ++ch){
    const int ci0 = ch*32;
    __syncthreads();
    for (int i = t; i < 1040; i += 256){
      int rw = (i >= 520), j = i - rw*520;
      int col = j >> 2, cg = j & 3;
      uint4 val = {0,0,0,0};
      if (y + rw < 128)
        val = *(const uint4*)&omT[((size_t)(b*128 + y + rw)*130 + col)*128 + ci0 + cg*8];
      *(uint4*)&asp[((rw*130 + col)*32) + cg*8] = val;
    }
    for (int i = t; i < 2304; i += 256){
      int rr = i >> 2, cg = i & 3;
      *(uint4*)&bsp[rr*32 + cg*8] = *(const uint4*)&wup[rr*128 + ci0 + cg*8];
    }
    __syncthreads();
    #pragma unroll
    for (int k = 0; k < 9; ++k){
      const int pr = PAR[k], rw = ROW[k], sh = SHF[k];
      if (rw && y == 127) continue;
      short8 af[2], bf[4];
      #pragma unroll
      for (int mt = 0; mt < 2; ++mt)
        af[mt] = *(const short8*)&asp[((rw*130 + m0w + mt*16 + l15 + 1 + sh))*32 + quad*8];
      #pragma unroll
      for (int nt = 0; nt < 4; ++nt)
        bf[nt] = *(const short8*)&bsp[(k*64 + nt*16 + l15)*32 + quad*8];
      #pragma unroll
      for (int mt = 0; mt < 2; ++mt)
        #pragma unroll
        for (int nt = 0; nt < 4; ++nt)
          acc[pr][mt][nt] = __builtin_amdgcn_mfma_f32_16x16x32_bf16(af[mt], bf[nt], acc[pr][mt][nt], 0, 0, 0);
    }
  }
  #pragma unroll
  for (int p = 0; p < 4; ++p){
    __syncthreads();
    #pragma unroll
    for (int mt = 0; mt < 2; ++mt)
      #pragma unroll
      for (int nt = 0; nt < 4; ++nt){
        int co = nt*16 + l15;
        int xb = m0w + mt*16 + quad*4;
        #pragma unroll
        for (int r = 0; r < 4; ++r)
          ptile[co*132 + xb + r] = acc[p][mt][nt][r];
      }
    __syncthreads();
    int py = p >> 1, px = p & 1;
    int Y = 2*y + py;
    for (int i = t; i < 8192; i += 256){
      int co = i >> 7, xx = i & 127;
      out[((size_t)(b*64 + co)*256 + Y)*256 + 2*xx + px] = ptile[co*132 + xx];
    }
  }
}

extern "C" void kernel_launch(void* const* d_in, const int* in_sizes, int n_in,
                              void* d_out, int out_size, void* d_ws, size_t ws_size,
                              hipStream_t stream) {
  const float* x       = (const float*)d_in[0];
  const float* conv_w  = (const float*)d_in[1];
  const float* bn1_g   = (const float*)d_in[2];
  const float* bn1_b   = (const float*)d_in[3];
  const float* qkv_w   = (const float*)d_in[4];
  const float* loc1_w  = (const float*)d_in[5];
  const float* loc1_g  = (const float*)d_in[6];
  const float* loc1_b  = (const float*)d_in[7];
  const float* loc2_w  = (const float*)d_in[8];
  const float* loc2_g  = (const float*)d_in[9];
  const float* loc2_b  = (const float*)d_in[10];
  const float* rel_t   = (const float*)d_in[11];
  const float* cw_w    = (const float*)d_in[12];
  const float* cw_g    = (const float*)d_in[13];
  const float* cw_b    = (const float*)d_in[14];
  const float* hc_w    = (const float*)d_in[15];
  const float* hc_g    = (const float*)d_in[16];
  const float* hc_b    = (const float*)d_in[17];
  const float* hw_w    = (const float*)d_in[18];
  const float* hw_g    = (const float*)d_in[19];
  const float* hw_b    = (const float*)d_in[20];
  const float* proj_dw = (const float*)d_in[21];
  const float* proj_g  = (const float*)d_in[22];
  const float* proj_b  = (const float*)d_in[23];
  const float* proj_pw = (const float*)d_in[24];
  const float* up_w    = (const float*)d_in[25];

  char* ws = (char*)d_ws;
  float* h      = (float*)(ws + OFF_H);
  float* local  = (float*)(ws + OFF_LOCAL);
  bf16*  q      = (bf16*)(ws + OFF_Q);
  bf16*  k      = (bf16*)(ws + OFF_K);
  bf16*  v      = (bf16*)(ws + OFF_V);
  bf16*  dots   = (bf16*)(ws + OFF_DOTS);
  bf16*  z1     = (bf16*)(ws + OFF_Z1);
  bf16*  z2     = (bf16*)(ws + OFF_Z2);
  bf16*  z3     = (bf16*)(ws + OFF_Z3);
  float* G1     = (float*)(ws + OFF_G1);
  float* G2     = (float*)(ws + OFF_G2);
  float* G3     = (float*)(ws + OFF_G3);
  short* xT     = (short*)(ws + OFF_DOTS);
  short* hT     = (short*)(ws + OFF_HT);
  short* w2bf   = (short*)(ws + OFF_Z1);
  short* wloc   = (short*)(ws + OFF_Z2);
  short* wqkv   = (short*)(ws + OFF_Z3);
  short* omT    = (short*)(ws + OFF_DOTS);
  short* wup    = (short*)(ws + OFF_Z1);
  float* o_img  = (float*)(ws + OFF_Q);
  float* Fh     = (float*)(ws + OFF_DOTS);
  float* Fw     = (float*)(ws + OFF_DOTS + 8388608);
  float* comb   = (float*)(ws + OFF_H);
  float* proj1  = (float*)(ws + OFF_LOCAL);
  float* outp   = (float*)d_out;

  dim3 blk2(16,16);
  k_wrep <<<1152, 256, 0, stream>>>(conv_w, w2bf);
  k_xzero<<<1024, 256, 0, stream>>>(xT);
  k_xrep <<<8192, 256, 0, stream>>>(x, xT);
  k_conv1m<<<512, 256, 0, stream>>>(xT, w2bf, bn1_g, bn1_b, h);
  k_lwrep<<<576, 256, 0, stream>>>(loc1_w, loc1_g, loc2_w, loc2_g, wloc);
  k_hzero<<<512, 256, 0, stream>>>(hT);
  k_hrep <<<4096, 256, 0, stream>>>(h, hT);
  k_localm<<<512, 256, 0, stream>>>(hT, wloc, loc1_b, loc2_b, local);
  k_wqkvrep<<<192, 256, 0, stream>>>(qkv_w, wqkv);
  k_qkvm <<<dim3(512,3), 256, 0, stream>>>(hT, wqkv, q, k, v);
  k_dots <<<dim3(NWIN,8), 256, 0, stream>>>(q, k, rel_t, dots);
  k_z1   <<<2048, 256, 0, stream>>>(dots, z1);
  k_z2   <<<2048, 256, 0, stream>>>(dots, z2);
  k_z3   <<<16384, 256, 0, stream>>>(dots, z3);
  k_gate <<<dim3(NWIN,2),  256, 0, stream>>>(z1, cw_w, cw_g, cw_b, G1, 8, 64);
  k_gate <<<dim3(NWIN,2),  256, 0, stream>>>(z2, hc_w, hc_g, hc_b, G2, 64, 8);
  k_gate3<<<NWIN, 256, 0, stream>>>(z3, hw_w, hw_g, hw_b, G3);
  k_attn <<<dim3(NWIN,8), 256, 0, stream>>>(dots, G1, G2, G3, v, o_img);
  k_fw   <<<8192, 256, 0, stream>>>(o_img, Fw);
  k_fh   <<<8192, 256, 0, stream>>>(o_img, Fh);
  k_comb <<<512, 256, 0, stream>>>(o_img, Fh, Fw, local, comb);
  k_dw   <<<dim3(8, BB*128), 256, 0, stream>>>(comb, proj_dw, proj_g, proj_b, proj1);
  k_omzero<<<512, 256, 0, stream>>>(omT);
  k_uwrep<<<288, 256, 0, stream>>>(up_w, wup);
  k_pw   <<<dim3(1024,2), blk2, 0, stream>>>(proj1, proj_pw, omT);
  k_upm  <<<512, 256, 0, stream>>>(omT, wup, outp);
}